// Round 4
// baseline (478.915 us; speedup 1.0000x reference)
//
#include <hip/hip_runtime.h>

// ---------------------------------------------------------------------------
// GraphSAGE 2-layer hetero (R=2) + edge dot scorer.  Round 12:
//  * Column-tiled gathers for per-XCD L2 residency. xb/m0/m1 stored as
//    [4][N][32] bf16 tiles (3.2MB per tile < 4MB XCD L2). agg1 runs as
//    grid.y=4 passes; per pass a quarter-wave (16 lanes x 4B = 64B) handles
//    one edge -> 4 edges per load instruction, indices via per-lane
//    csr[j+q] broadcast loads (NO local arrays - round-10 lesson).
//  * score: h2b stored tiled [2][N][32]; grid.y=2 passes over 3.2MB halves,
//    partial dots combined via memset + atomicAdd (2 adds/edge).
//  * gemm1/cvt use tiled addressing (tile == K-step s, MFMA loop unchanged).
//  * agg2 keeps round-9 gather structure; only its h2b write is tiled.
//  * kept: aggregate-first layer 1, fused 3-matmul GEMMs, CSR radix build.
// ---------------------------------------------------------------------------

#define BW 128            // nodes per radix bucket (pow2)
#define NBK_MAX 1024
#define EPB 8192          // edges per block in radix passes

typedef __attribute__((ext_vector_type(8))) short bf16x8;
typedef __attribute__((ext_vector_type(4))) float floatx4;

__device__ __forceinline__ unsigned short f2bf(float f) {
    unsigned u = __float_as_uint(f);
    unsigned r = u + 0x7FFFu + ((u >> 16) & 1u);
    return (unsigned short)(r >> 16);
}
__device__ __forceinline__ unsigned pack2(float a, float b) {
    return (unsigned)f2bf(a) | ((unsigned)f2bf(b) << 16);
}
__device__ __forceinline__ float bflo(unsigned v) { return __uint_as_float(v << 16); }
__device__ __forceinline__ float bfhi(unsigned v) { return __uint_as_float(v & 0xFFFF0000u); }
#define RFL(x) __builtin_amdgcn_readfirstlane(x)

// ---- radix pass A: per-(r,bucket) counts --------------------------------
__global__ __launch_bounds__(256) void
bucket_count_kernel(const int* __restrict__ edges, int* __restrict__ bcnt,
                    int NBK, int E)
{
    __shared__ int cnt[2 * NBK_MAX];
    const int rbT = 2 * NBK;
    const int t = threadIdx.x;
    for (int k = t; k < rbT; k += 256) cnt[k] = 0;
    __syncthreads();
    long long start = (long long)blockIdx.x * EPB;
    long long twoE = 2LL * E;
    for (int u = 0; u < EPB / 256; ++u) {
        long long idx = start + u * 256 + t;
        if (idx < twoE) {
            int r = idx >= E;
            int e = (int)(idx - (long long)r * E);
            int d = edges[(size_t)r * 2 * E + E + e];
            atomicAdd(&cnt[r * NBK + (d >> 7)], 1);
        }
    }
    __syncthreads();
    for (int k = t; k < rbT; k += 256)
        if (cnt[k]) atomicAdd(&bcnt[k], cnt[k]);
}

// ---- radix pass B: exclusive scan of bucket counts ----------------------
__global__ __launch_bounds__(1024) void
bucket_scan_kernel(const int* __restrict__ bcnt, int* __restrict__ bko,
                   int rbT, int twoE)
{
    __shared__ int sm[1024];
    int t = threadIdx.x;
    int v = (t < rbT) ? bcnt[t] : 0;
    sm[t] = v;
    __syncthreads();
    for (int s = 1; s < 1024; s <<= 1) {
        int u = (t >= s) ? sm[t - s] : 0;
        __syncthreads();
        sm[t] += u;
        __syncthreads();
    }
    if (t < rbT) bko[t] = sm[t] - v;
    if (t == 0) bko[rbT] = twoE;
}

// ---- radix pass C: partition into bucket-grouped (src,dst) pairs --------
__global__ __launch_bounds__(256) void
partition_kernel(const int* __restrict__ edges, const int* __restrict__ bko,
                 int* __restrict__ gcur, uint2* __restrict__ staging,
                 int NBK, int E)
{
    __shared__ int cnt[2 * NBK_MAX];
    __shared__ int base[2 * NBK_MAX];
    const int rbT = 2 * NBK;
    const int t = threadIdx.x;
    for (int k = t; k < rbT; k += 256) cnt[k] = 0;
    __syncthreads();
    long long start = (long long)blockIdx.x * EPB;
    long long twoE = 2LL * E;
    for (int u = 0; u < EPB / 256; ++u) {
        long long idx = start + u * 256 + t;
        if (idx < twoE) {
            int r = idx >= E;
            int e = (int)(idx - (long long)r * E);
            int d = edges[(size_t)r * 2 * E + E + e];
            atomicAdd(&cnt[r * NBK + (d >> 7)], 1);
        }
    }
    __syncthreads();
    for (int k = t; k < rbT; k += 256) {
        int c0 = cnt[k];
        if (c0) base[k] = bko[k] + atomicAdd(&gcur[k], c0);
        cnt[k] = 0;
    }
    __syncthreads();
    for (int u = 0; u < EPB / 256; ++u) {
        long long idx = start + u * 256 + t;
        if (idx < twoE) {
            int r = idx >= E;
            int e = (int)(idx - (long long)r * E);
            int s = edges[(size_t)r * 2 * E + e];
            int d = edges[(size_t)r * 2 * E + E + e];
            int rb = r * NBK + (d >> 7);
            int pos = atomicAdd(&cnt[rb], 1);
            staging[(size_t)base[rb] + pos] = make_uint2((unsigned)s, (unsigned)d);
        }
    }
}

// ---- radix pass D: per-bucket node hist/scan -> off[] and csr[] ----------
__global__ __launch_bounds__(256) void
bucket_csr_kernel(const uint2* __restrict__ staging, const int* __restrict__ bko,
                  int* __restrict__ csr, int* __restrict__ off,
                  int NBK, int N)
{
    __shared__ int hist[BW], excl[BW], cur[BW], sc[BW];
    const int rb = blockIdx.x;
    const int r = rb / NBK;
    const int b = rb % NBK;
    const int node0 = b * BW;
    const int nn = min(BW, N - node0);
    const int cbase = bko[rb];
    const int c = bko[rb + 1] - cbase;
    const int t = threadIdx.x;

    if (t < BW) { hist[t] = 0; cur[t] = 0; }
    __syncthreads();
    for (int k = t; k < c; k += 256)
        atomicAdd(&hist[(int)staging[(size_t)cbase + k].y - node0], 1);
    __syncthreads();
    if (t < BW) sc[t] = hist[t];
    __syncthreads();
    for (int s = 1; s < BW; s <<= 1) {
        int v = (t < BW && t >= s) ? sc[t - s] : 0;
        __syncthreads();
        if (t < BW) sc[t] += v;
        __syncthreads();
    }
    if (t < BW) excl[t] = sc[t] - hist[t];
    if (t < nn) off[(size_t)r * N + node0 + t] = cbase + excl[t];
    __syncthreads();
    for (int k = t; k < c; k += 256) {
        uint2 pr = staging[(size_t)cbase + k];
        int l = (int)pr.y - node0;
        int pos = atomicAdd(&cur[l], 1);
        csr[(size_t)cbase + excl[l] + pos] = (int)pr.x;
    }
}

// ---- f32 -> bf16, tiled layout [4][N][32] -------------------------------
__global__ void cvt_kernel(const float* __restrict__ in,
                           unsigned short* __restrict__ xbt, int N)
{
    int t = blockIdx.x * blockDim.x + threadIdx.x;
    if (t >= N * 32) return;
    int row = t >> 5;
    int c4 = (t & 31) * 4;
    float4 v = ((const float4*)in)[t];
    ushort4 r;
    r.x = f2bf(v.x); r.y = f2bf(v.y); r.z = f2bf(v.z); r.w = f2bf(v.w);
    int tile = c4 >> 5;
    int tcol = c4 & 31;
    *(ushort4*)(xbt + ((size_t)tile * N + row) * 32 + tcol) = r;
}

// ---- weight prep: combined-Wself / Wn -> bf16 W^T rows, biases ----------
__global__ void prep_kernel(const float* __restrict__ Ws1, const float* __restrict__ Wn1,
                            const float* __restrict__ b1,
                            const float* __restrict__ Ws2, const float* __restrict__ Wn2,
                            const float* __restrict__ b2,
                            unsigned short* __restrict__ WT1z, unsigned short* __restrict__ WT1a,
                            unsigned short* __restrict__ WT1b, float* __restrict__ bc1,
                            unsigned short* __restrict__ WT2z, unsigned short* __restrict__ WT2a,
                            unsigned short* __restrict__ WT2b, float* __restrict__ bc2)
{
    int t = blockIdx.x * blockDim.x + threadIdx.x;
    if (t < 16384) {                 // layer 1: [n][k] <- [k][n], n,k < 128
        int n = t >> 7, k = t & 127;
        int in = k * 128 + n;
        WT1z[t] = f2bf(Ws1[in] + Ws1[16384 + in]);
        WT1a[t] = f2bf(Wn1[in]);
        WT1b[t] = f2bf(Wn1[16384 + in]);
    }
    if (t < 8192) {                  // layer 2: n < 64, k < 128
        int n = t >> 7, k = t & 127;
        int in = k * 64 + n;
        WT2z[t] = f2bf(Ws2[in] + Ws2[8192 + in]);
        WT2a[t] = f2bf(Wn2[in]);
        WT2b[t] = f2bf(Wn2[8192 + in]);
    }
    if (t < 128) bc1[t] = b1[t] + b1[128 + t];
    if (t < 64)  bc2[t] = b2[t] + b2[64 + t];
}

// ---- agg L1 (tiled): grid.y = tile (0..3), working set 3.2MB/pass -------
// Wave per node; quarter-wave (16 lanes x 4B = 64B) per edge -> 4 edges per
// load instruction. Indices via per-lane csr[j+q] broadcast loads.
__global__ __launch_bounds__(256) void
agg1_kernel(const unsigned short* __restrict__ xbt,   // [4][N][32]
            const int* __restrict__ csr, const int* __restrict__ off,
            unsigned short* __restrict__ m0t, unsigned short* __restrict__ m1t,
            int N, int twoE)
{
    int w = blockIdx.x * 4 + (threadIdx.x >> 6);
    int lane = threadIdx.x & 63;
    if (w >= N) return;
    const int q = lane >> 4;               // edge slot within wave
    const int col = (lane & 15) * 2;       // 2 bf16 cols per lane
    const unsigned short* xc = xbt + (size_t)blockIdx.y * N * 32 + col;

    float sx0 = 0.f, sy0 = 0.f, sx1 = 0.f, sy1 = 0.f;

    // ---- relation 0 ----
    int o0 = RFL(off[w]);
    int o1 = RFL(off[w + 1]);
    int d0 = o1 - o0;
    int j = o0;
    for (; j + 15 < o1; j += 16) {
        int r0 = csr[j + q];
        int r1 = csr[j + 4 + q];
        int r2 = csr[j + 8 + q];
        int r3 = csr[j + 12 + q];
        unsigned a0 = *(const unsigned*)(xc + (size_t)r0 * 32);
        unsigned a1 = *(const unsigned*)(xc + (size_t)r1 * 32);
        unsigned a2 = *(const unsigned*)(xc + (size_t)r2 * 32);
        unsigned a3 = *(const unsigned*)(xc + (size_t)r3 * 32);
        sx0 += (bflo(a0) + bflo(a1)) + (bflo(a2) + bflo(a3));
        sy0 += (bfhi(a0) + bfhi(a1)) + (bfhi(a2) + bfhi(a3));
    }
    for (; j + 3 < o1; j += 4) {
        int r = csr[j + q];
        unsigned a = *(const unsigned*)(xc + (size_t)r * 32);
        sx0 += bflo(a); sy0 += bfhi(a);
    }
    if (j < o1 && q < o1 - j) {
        int r = csr[j + q];
        unsigned a = *(const unsigned*)(xc + (size_t)r * 32);
        sx0 += bflo(a); sy0 += bfhi(a);
    }

    // ---- relation 1 ----
    int p = N + w;
    o0 = RFL(off[p]);
    o1 = (p + 1 < 2 * N) ? RFL(off[p + 1]) : twoE;
    int d1 = o1 - o0;
    j = o0;
    for (; j + 15 < o1; j += 16) {
        int r0 = csr[j + q];
        int r1 = csr[j + 4 + q];
        int r2 = csr[j + 8 + q];
        int r3 = csr[j + 12 + q];
        unsigned a0 = *(const unsigned*)(xc + (size_t)r0 * 32);
        unsigned a1 = *(const unsigned*)(xc + (size_t)r1 * 32);
        unsigned a2 = *(const unsigned*)(xc + (size_t)r2 * 32);
        unsigned a3 = *(const unsigned*)(xc + (size_t)r3 * 32);
        sx1 += (bflo(a0) + bflo(a1)) + (bflo(a2) + bflo(a3));
        sy1 += (bfhi(a0) + bfhi(a1)) + (bfhi(a2) + bfhi(a3));
    }
    for (; j + 3 < o1; j += 4) {
        int r = csr[j + q];
        unsigned a = *(const unsigned*)(xc + (size_t)r * 32);
        sx1 += bflo(a); sy1 += bfhi(a);
    }
    if (j < o1 && q < o1 - j) {
        int r = csr[j + q];
        unsigned a = *(const unsigned*)(xc + (size_t)r * 32);
        sx1 += bflo(a); sy1 += bfhi(a);
    }

    // cross-quarter reduce + write (tile row of 32 cols)
    sx0 += __shfl_xor(sx0, 16); sy0 += __shfl_xor(sy0, 16);
    sx0 += __shfl_xor(sx0, 32); sy0 += __shfl_xor(sy0, 32);
    sx1 += __shfl_xor(sx1, 16); sy1 += __shfl_xor(sy1, 16);
    sx1 += __shfl_xor(sx1, 32); sy1 += __shfl_xor(sy1, 32);
    if (q == 0) {
        float inv0 = 1.0f / fmaxf((float)d0, 1.0f);
        float inv1 = 1.0f / fmaxf((float)d1, 1.0f);
        size_t o = ((size_t)blockIdx.y * N + w) * 32 + col;
        *(unsigned*)(m0t + o) = pack2(sx0 * inv0, sy0 * inv0);
        *(unsigned*)(m1t + o) = pack2(sx1 * inv1, sy1 * inv1);
    }
}

// ---- fused layer-1 GEMM: h1 = relu(x@WTz + m0@WTa + m1@WTb + bias) ------
// A operands read from tiled [4][N][32] layout (tile index == K-step s).
__global__ __launch_bounds__(256) void
gemm1_fused_kernel(const unsigned short* __restrict__ xbt,
                   const unsigned short* __restrict__ m0t,
                   const unsigned short* __restrict__ m1t,
                   const unsigned short* __restrict__ WTz,
                   const unsigned short* __restrict__ WTa,
                   const unsigned short* __restrict__ WTb,
                   const float* __restrict__ bias,
                   unsigned short* __restrict__ h1b, int N)
{
    __shared__ float eb[64][129];

    const int tid = threadIdx.x;
    const int wave = tid >> 6;
    const int lane = tid & 63;
    const int m = lane & 15;
    const int quad = lane >> 4;

    floatx4 acc[8];
    const floatx4 z4 = {0.f, 0.f, 0.f, 0.f};
#pragma unroll
    for (int t = 0; t < 8; ++t) acc[t] = z4;

    int arow = blockIdx.x * 64 + wave * 16 + m;
    if (arow >= N) arow = N - 1;

#pragma unroll
    for (int s = 0; s < 4; ++s) {
        const size_t tb = ((size_t)s * N + arow) * 32 + quad * 8;
        bf16x8 ax = *(const bf16x8*)(xbt + tb);
        bf16x8 a0 = *(const bf16x8*)(m0t + tb);
        bf16x8 a1 = *(const bf16x8*)(m1t + tb);
#pragma unroll
        for (int t = 0; t < 8; ++t) {
            const size_t bo = (size_t)(t * 16 + m) * 128 + s * 32 + quad * 8;
            acc[t] = __builtin_amdgcn_mfma_f32_16x16x32_bf16(
                ax, *(const bf16x8*)(WTz + bo), acc[t], 0, 0, 0);
            acc[t] = __builtin_amdgcn_mfma_f32_16x16x32_bf16(
                a0, *(const bf16x8*)(WTa + bo), acc[t], 0, 0, 0);
            acc[t] = __builtin_amdgcn_mfma_f32_16x16x32_bf16(
                a1, *(const bf16x8*)(WTb + bo), acc[t], 0, 0, 0);
        }
    }

    // C/D: col = lane&15, row = quad*4 + reg -> LDS transpose epilogue
#pragma unroll
    for (int t = 0; t < 8; ++t)
#pragma unroll
        for (int i = 0; i < 4; ++i)
            eb[wave * 16 + quad * 4 + i][t * 16 + m] = acc[t][i];
    __syncthreads();

#pragma unroll
    for (int j = 0; j < 4; ++j) {
        int lr = wave * 16 + j * 4 + quad;
        int grow = blockIdx.x * 64 + lr;
        if (grow < N) {
#pragma unroll
            for (int i = 0; i < 2; ++i) {
                int c0 = (i * 16 + m) * 4;
                float v0 = fmaxf(eb[lr][c0 + 0] + bias[c0 + 0], 0.0f);
                float v1 = fmaxf(eb[lr][c0 + 1] + bias[c0 + 1], 0.0f);
                float v2 = fmaxf(eb[lr][c0 + 2] + bias[c0 + 2], 0.0f);
                float v3 = fmaxf(eb[lr][c0 + 3] + bias[c0 + 3], 0.0f);
                ushort4 u;
                u.x = f2bf(v0); u.y = f2bf(v1); u.z = f2bf(v2); u.w = f2bf(v3);
                *(ushort4*)(h1b + (size_t)grow * 128 + c0) = u;
            }
        }
    }
}

// ---- fused layer-2 GEMM: one pass over h1b -> z2 (f32+bias), t0, t1 -----
__global__ __launch_bounds__(256) void
gemm2_fused_kernel(const unsigned short* __restrict__ Ab,
                   const unsigned short* __restrict__ WTz,
                   const unsigned short* __restrict__ WTa,
                   const unsigned short* __restrict__ WTb,
                   const float* __restrict__ bias,
                   float* __restrict__ zf,
                   unsigned short* __restrict__ ya, unsigned short* __restrict__ yb,
                   int N)
{
    __shared__ float eb[64][65];

    const int tid = threadIdx.x;
    const int wave = tid >> 6;
    const int lane = tid & 63;
    const int m = lane & 15;
    const int quad = lane >> 4;

    floatx4 accz[4], acca[4], accb[4];
    const floatx4 z4 = {0.f, 0.f, 0.f, 0.f};
#pragma unroll
    for (int t = 0; t < 4; ++t) { accz[t] = z4; acca[t] = z4; accb[t] = z4; }

    int arow = blockIdx.x * 64 + wave * 16 + m;
    if (arow >= N) arow = N - 1;
    const unsigned short* aptr = Ab + (size_t)arow * 128 + quad * 8;

#pragma unroll
    for (int s = 0; s < 4; ++s) {
        bf16x8 a = *(const bf16x8*)(aptr + s * 32);
#pragma unroll
        for (int t = 0; t < 4; ++t) {
            const size_t bo = (size_t)(t * 16 + m) * 128 + s * 32 + quad * 8;
            accz[t] = __builtin_amdgcn_mfma_f32_16x16x32_bf16(
                a, *(const bf16x8*)(WTz + bo), accz[t], 0, 0, 0);
            acca[t] = __builtin_amdgcn_mfma_f32_16x16x32_bf16(
                a, *(const bf16x8*)(WTa + bo), acca[t], 0, 0, 0);
            accb[t] = __builtin_amdgcn_mfma_f32_16x16x32_bf16(
                a, *(const bf16x8*)(WTb + bo), accb[t], 0, 0, 0);
        }
    }

    // ---- round z: f32 + bias ----
#pragma unroll
    for (int t = 0; t < 4; ++t)
#pragma unroll
        for (int i = 0; i < 4; ++i)
            eb[wave * 16 + quad * 4 + i][t * 16 + m] = accz[t][i];
    __syncthreads();
#pragma unroll
    for (int j = 0; j < 4; ++j) {
        int lr = wave * 16 + j * 4 + quad;
        int gr = blockIdx.x * 64 + lr;
        if (gr < N) {
            int c0 = m * 4;
            float4 o;
            o.x = eb[lr][c0 + 0] + bias[c0 + 0];
            o.y = eb[lr][c0 + 1] + bias[c0 + 1];
            o.z = eb[lr][c0 + 2] + bias[c0 + 2];
            o.w = eb[lr][c0 + 3] + bias[c0 + 3];
            *(float4*)(zf + (size_t)gr * 64 + c0) = o;
        }
    }
    __syncthreads();

    // ---- round a: bf16 ----
#pragma unroll
    for (int t = 0; t < 4; ++t)
#pragma unroll
        for (int i = 0; i < 4; ++i)
            eb[wave * 16 + quad * 4 + i][t * 16 + m] = acca[t][i];
    __syncthreads();
#pragma unroll
    for (int j = 0; j < 4; ++j) {
        int lr = wave * 16 + j * 4 + quad;
        int gr = blockIdx.x * 64 + lr;
        if (gr < N) {
            int c0 = m * 4;
            ushort4 u;
            u.x = f2bf(eb[lr][c0 + 0]); u.y = f2bf(eb[lr][c0 + 1]);
            u.z = f2bf(eb[lr][c0 + 2]); u.w = f2bf(eb[lr][c0 + 3]);
            *(ushort4*)(ya + (size_t)gr * 64 + c0) = u;
        }
    }
    __syncthreads();

    // ---- round b: bf16 ----
#pragma unroll
    for (int t = 0; t < 4; ++t)
#pragma unroll
        for (int i = 0; i < 4; ++i)
            eb[wave * 16 + quad * 4 + i][t * 16 + m] = accb[t][i];
    __syncthreads();
#pragma unroll
    for (int j = 0; j < 4; ++j) {
        int lr = wave * 16 + j * 4 + quad;
        int gr = blockIdx.x * 64 + lr;
        if (gr < N) {
            int c0 = m * 4;
            ushort4 u;
            u.x = f2bf(eb[lr][c0 + 0]); u.y = f2bf(eb[lr][c0 + 1]);
            u.z = f2bf(eb[lr][c0 + 2]); u.w = f2bf(eb[lr][c0 + 3]);
            *(ushort4*)(yb + (size_t)gr * 64 + c0) = u;
        }
    }
}

// ---- agg L2: wave per node (round-9 gather); OUTPUT write tiled ---------
__global__ __launch_bounds__(256) void
agg2_kernel(const unsigned short* __restrict__ t0,
            const unsigned short* __restrict__ t1,
            const float* __restrict__ z2,
            const int* __restrict__ csr, const int* __restrict__ off,
            unsigned short* __restrict__ h2bt,   // [2][N][32]
            int N, int twoE)
{
    int w = blockIdx.x * 4 + (threadIdx.x >> 6);
    int lane = threadIdx.x & 63;
    if (w >= N) return;
    const int half = lane >> 5;
    const int col = (lane & 31) * 2;

    float sx0 = 0.f, sy0 = 0.f, sx1 = 0.f, sy1 = 0.f;
    int o0 = RFL(off[w]);
    int o1 = RFL(off[w + 1]);
    int d0 = o1 - o0;
    int j = o0 + half;
    for (; j + 6 < o1; j += 8) {
        int s0 = csr[j], s1 = csr[j + 2], s2 = csr[j + 4], s3 = csr[j + 6];
        unsigned a0 = *(const unsigned*)(t0 + (size_t)s0 * 64 + col);
        unsigned a1 = *(const unsigned*)(t0 + (size_t)s1 * 64 + col);
        unsigned a2 = *(const unsigned*)(t0 + (size_t)s2 * 64 + col);
        unsigned a3 = *(const unsigned*)(t0 + (size_t)s3 * 64 + col);
        sx0 += (bflo(a0) + bflo(a1)) + (bflo(a2) + bflo(a3));
        sy0 += (bfhi(a0) + bfhi(a1)) + (bfhi(a2) + bfhi(a3));
    }
    for (; j < o1; j += 2) {
        unsigned a = *(const unsigned*)(t0 + (size_t)csr[j] * 64 + col);
        sx0 += bflo(a); sy0 += bfhi(a);
    }
    int p = N + w;
    o0 = RFL(off[p]);
    o1 = (p + 1 < 2 * N) ? RFL(off[p + 1]) : twoE;
    int d1 = o1 - o0;
    j = o0 + half;
    for (; j + 6 < o1; j += 8) {
        int s0 = csr[j], s1 = csr[j + 2], s2 = csr[j + 4], s3 = csr[j + 6];
        unsigned a0 = *(const unsigned*)(t1 + (size_t)s0 * 64 + col);
        unsigned a1 = *(const unsigned*)(t1 + (size_t)s1 * 64 + col);
        unsigned a2 = *(const unsigned*)(t1 + (size_t)s2 * 64 + col);
        unsigned a3 = *(const unsigned*)(t1 + (size_t)s3 * 64 + col);
        sx1 += (bflo(a0) + bflo(a1)) + (bflo(a2) + bflo(a3));
        sy1 += (bfhi(a0) + bfhi(a1)) + (bfhi(a2) + bfhi(a3));
    }
    for (; j < o1; j += 2) {
        unsigned a = *(const unsigned*)(t1 + (size_t)csr[j] * 64 + col);
        sx1 += bflo(a); sy1 += bfhi(a);
    }
    sx0 += __shfl_xor(sx0, 32);
    sy0 += __shfl_xor(sy0, 32);
    sx1 += __shfl_xor(sx1, 32);
    sy1 += __shfl_xor(sy1, 32);
    if (half == 0) {
        float inv0 = 1.0f / fmaxf((float)d0, 1.0f);
        float inv1 = 1.0f / fmaxf((float)d1, 1.0f);
        float2 z = *(const float2*)(z2 + (size_t)w * 64 + col);
        float hx = z.x + sx0 * inv0 + sx1 * inv1;
        float hy = z.y + sy0 * inv0 + sy1 * inv1;
        int tile = col >> 5;
        *(unsigned*)(h2bt + ((size_t)tile * N + w) * 32 + (col & 31)) =
            pack2(hx, hy);
    }
}

// ---- score (tiled, 2 passes, atomicAdd accumulate) ----------------------
// grid.y = tile (0..1): per pass 3.2MB h2bt half is L2-resident.
__global__ __launch_bounds__(256) void
score_kernel(const unsigned short* __restrict__ h2bt, // [2][N][32]
             const int* __restrict__ edges, const int* __restrict__ neg,
             float* __restrict__ out, int E, int En, int N)
{
    int t = blockIdx.x * blockDim.x + threadIdx.x;
    int e = t >> 3;
    int c = t & 7;
    if (e >= E + En) return;
    int sI, dI, oI;
    if (e < E) { sI = edges[e]; dI = edges[E + e]; oI = e; }
    else { int en = e - E; sI = neg[en]; dI = neg[En + en]; oI = E + en; }
    const unsigned short* hb = h2bt + (size_t)blockIdx.y * N * 32;
    uint2 va = *(const uint2*)(hb + (size_t)sI * 32 + c * 4);
    uint2 vb = *(const uint2*)(hb + (size_t)dI * 32 + c * 4);
    float s = 0.0f;
    s = fmaf(bflo(va.x), bflo(vb.x), s);
    s = fmaf(bfhi(va.x), bfhi(vb.x), s);
    s = fmaf(bflo(va.y), bflo(vb.y), s);
    s = fmaf(bfhi(va.y), bfhi(vb.y), s);
    s += __shfl_xor(s, 1);
    s += __shfl_xor(s, 2);
    s += __shfl_xor(s, 4);
    if (c == 0) atomicAdd(&out[oI], s);
}

extern "C" void kernel_launch(void* const* d_in, const int* in_sizes, int n_in,
                              void* d_out, int out_size, void* d_ws, size_t ws_size,
                              hipStream_t stream)
{
    const float* x     = (const float*)d_in[0];
    const int*   edges = (const int*)d_in[1];
    const int*   neg   = (const int*)d_in[2];
    const float* Wn1   = (const float*)d_in[3];
    const float* Ws1   = (const float*)d_in[4];
    const float* b1    = (const float*)d_in[5];
    const float* Wn2   = (const float*)d_in[6];
    const float* Ws2   = (const float*)d_in[7];
    const float* b2    = (const float*)d_in[8];
    float* out = (float*)d_out;

    const int Fin = 128, R = 2;
    const int N  = in_sizes[0] / Fin;        // 50000
    const int E  = in_sizes[1] / (R * 2);    // 800000
    const int En = in_sizes[2] / 2;          // 800000
    const int twoE = 2 * E;
    const int NBK = (N + BW - 1) / BW;       // 391
    const int rbT = 2 * NBK;

    // ---- workspace layout (aliases noted) ----
    const size_t nb128 = (size_t)N * 128 * sizeof(unsigned short);   // 12.8MB
    char* p = (char*)d_ws;

    uint2* staging = (uint2*)p;                 // [2E] pairs (dead after CSR build)
    float* z2      = (float*)p;                 // [N,64] f32 (layer 2, aliases staging)
    {
        size_t r0 = (size_t)twoE * sizeof(uint2);
        size_t r1 = (size_t)N * 64 * sizeof(float);
        p += (r0 > r1 ? r0 : r1);
    }
    unsigned short* m0t = (unsigned short*)p; p += nb128;  // [4][N][32] (t0/t1 reuse)
    unsigned short* m1t = (unsigned short*)p; p += nb128;  // [4][N][32] (h2bt reuse)
    unsigned short* xbt = (unsigned short*)p; p += nb128;  // [4][N][32] bf16 x
    unsigned short* h1b = (unsigned short*)p; p += nb128;  // [N,128] bf16 h1
    unsigned short* WT1z = (unsigned short*)p; p += 16384 * 2;
    unsigned short* WT1a = (unsigned short*)p; p += 16384 * 2;
    unsigned short* WT1b = (unsigned short*)p; p += 16384 * 2;
    unsigned short* WT2z = (unsigned short*)p; p += 8192 * 2;
    unsigned short* WT2a = (unsigned short*)p; p += 8192 * 2;
    unsigned short* WT2b = (unsigned short*)p; p += 8192 * 2;
    float* bc1 = (float*)p; p += 128 * sizeof(float);
    float* bc2 = (float*)p; p += 64 * sizeof(float);
    int* bcnt = (int*)p; p += (size_t)2 * NBK_MAX * sizeof(int);
    int* gcur = (int*)p; p += (size_t)2 * NBK_MAX * sizeof(int);
    int* bko  = (int*)p; p += ((size_t)2 * NBK_MAX + 1) * sizeof(int);
    int* off  = (int*)p; p += (size_t)2 * N * sizeof(int);
    int* csr  = (int*)p;

    unsigned short* t0   = m0t;                      // [N,64] bf16 (row-major)
    unsigned short* t1   = m0t + (size_t)N * 64;     // [N,64] bf16
    unsigned short* h2bt = m1t;                      // [2][N][32] bf16

    const int BS = 256;
    const int edge_blocks = (twoE + EPB - 1) / EPB;
    const int gx = (N + 63) / 64;

    // ---- CSR build (radix by dst bucket) ----
    hipMemsetAsync(bcnt, 0, (size_t)4 * NBK_MAX * sizeof(int), stream);
    bucket_count_kernel<<<edge_blocks, BS, 0, stream>>>(edges, bcnt, NBK, E);
    bucket_scan_kernel<<<1, 1024, 0, stream>>>(bcnt, bko, rbT, twoE);
    partition_kernel<<<edge_blocks, BS, 0, stream>>>(edges, bko, gcur, staging, NBK, E);
    bucket_csr_kernel<<<rbT, BS, 0, stream>>>(staging, bko, csr, off, NBK, N);

    // ---- prep ----
    cvt_kernel<<<(N * 32 + BS - 1) / BS, BS, 0, stream>>>(x, xbt, N);
    prep_kernel<<<(16384 + BS - 1) / BS, BS, 0, stream>>>(
        Ws1, Wn1, b1, Ws2, Wn2, b2,
        WT1z, WT1a, WT1b, bc1, WT2z, WT2a, WT2b, bc2);

    // ---- Layer 1: tiled aggregate (4 passes), then fused 3-matmul GEMM --
    {
        dim3 g((N + 3) / 4, 4);
        agg1_kernel<<<g, BS, 0, stream>>>(xbt, csr, off, m0t, m1t, N, twoE);
    }
    gemm1_fused_kernel<<<gx, BS, 0, stream>>>(xbt, m0t, m1t, WT1z, WT1a, WT1b,
                                              bc1, h1b, N);

    // ---- Layer 2: one fused transform (3 outputs), then aggregate ----
    gemm2_fused_kernel<<<gx, BS, 0, stream>>>(h1b, WT2z, WT2a, WT2b, bc2,
                                              z2, t0, t1, N);
    agg2_kernel<<<(N + 3) / 4, BS, 0, stream>>>(t0, t1, z2, csr, off, h2bt, N, twoE);

    // ---- Scores (tiled 2 passes, pos + neg merged) ----
    hipMemsetAsync(out, 0, (size_t)(E + En) * sizeof(float), stream);
    {
        dim3 g(((E + En) * 8 + BS - 1) / BS, 2);
        score_kernel<<<g, BS, 0, stream>>>(h2bt, edges, neg, out, E, En, N);
    }
}

// Round 6
// 376.372 us; speedup vs baseline: 1.2725x; 1.2725x over previous
//
#include <hip/hip_runtime.h>

// ---------------------------------------------------------------------------
// GraphSAGE 2-layer hetero (R=2) + edge dot scorer.  Round 14:
//  * Round 13 (fp8 gather arrays) resubmitted after container failure, with
//    one fix: xb8 now ALIASES the staging/z2 region (xb8 live [cvt..agg1];
//    staging dead after bucket_csr; z2 written first at gemm2) -> workspace
//    footprint identical to round 11 (~77MB), removing OOB risk.
//  * agg1 gathers xb8 [N,128] fp8 (128B/row, 6.4MB working set); agg2
//    gathers t0/t1 fp8 [N,64] (64B/row). Dequant via hw v_cvt_pk_f32_fp8.
//    Mean over deg~16 + bf16 GEMM dilution keeps score err ~0.3 << 2.0 tol.
//  * h2b / score stay bf16. Everything else verbatim round 11.
// ---------------------------------------------------------------------------

#define BW 128            // nodes per radix bucket (pow2)
#define NBK_MAX 1024
#define EPB 8192          // edges per block in radix passes

typedef __attribute__((ext_vector_type(8))) short bf16x8;
typedef __attribute__((ext_vector_type(4))) float floatx4;
typedef __attribute__((ext_vector_type(2))) float floatx2;

__device__ __forceinline__ unsigned short f2bf(float f) {
    unsigned u = __float_as_uint(f);
    unsigned r = u + 0x7FFFu + ((u >> 16) & 1u);
    return (unsigned short)(r >> 16);
}
__device__ __forceinline__ unsigned pack2(float a, float b) {
    return (unsigned)f2bf(a) | ((unsigned)f2bf(b) << 16);
}
__device__ __forceinline__ float bflo(unsigned v) { return __uint_as_float(v << 16); }
__device__ __forceinline__ float bfhi(unsigned v) { return __uint_as_float(v & 0xFFFF0000u); }
#define RFL(x) __builtin_amdgcn_readfirstlane(x)

// ---- fp8 e4m3 helpers (hw cvt when available, bit-math fallback) --------
#if defined(__has_builtin) && __has_builtin(__builtin_amdgcn_cvt_pk_f32_fp8)
__device__ __forceinline__ floatx2 fp8x2_f32(unsigned v) {
    return __builtin_amdgcn_cvt_pk_f32_fp8((int)v, false);
}
#else
__device__ __forceinline__ floatx2 fp8x2_f32(unsigned v) {
    floatx2 r;
    unsigned b0 = v & 0xFFu, b1 = (v >> 8) & 0xFFu;
    r.x = __uint_as_float(((b0 & 0x80u) << 24) | ((b0 & 0x7Fu) << 20)) * 0x1.0p+120f;
    r.y = __uint_as_float(((b1 & 0x80u) << 24) | ((b1 & 0x7Fu) << 20)) * 0x1.0p+120f;
    return r;
}
#endif

#if defined(__has_builtin) && __has_builtin(__builtin_amdgcn_cvt_pk_fp8_f32)
__device__ __forceinline__ unsigned f32x4_fp8x4(float a, float b, float c, float d) {
    unsigned lo = __builtin_amdgcn_cvt_pk_fp8_f32(a, b, 0, false);
    return __builtin_amdgcn_cvt_pk_fp8_f32(c, d, lo, true);
}
#else
__device__ __forceinline__ unsigned f2fp8(float x) {
    float m = fminf(fabsf(x), 448.0f);
    unsigned u = __float_as_uint(m * 0x1.0p-120f);
    unsigned r = (u + 0x7FFFFu + ((u >> 20) & 1u)) >> 20;
    if (r > 0x7Eu) r = 0x7Eu;
    return r | ((__float_as_uint(x) >> 24) & 0x80u);
}
__device__ __forceinline__ unsigned f32x4_fp8x4(float a, float b, float c, float d) {
    return f2fp8(a) | (f2fp8(b) << 8) | (f2fp8(c) << 16) | (f2fp8(d) << 24);
}
#endif

// ---- radix pass A: per-(r,bucket) counts --------------------------------
__global__ __launch_bounds__(256) void
bucket_count_kernel(const int* __restrict__ edges, int* __restrict__ bcnt,
                    int NBK, int E)
{
    __shared__ int cnt[2 * NBK_MAX];
    const int rbT = 2 * NBK;
    const int t = threadIdx.x;
    for (int k = t; k < rbT; k += 256) cnt[k] = 0;
    __syncthreads();
    long long start = (long long)blockIdx.x * EPB;
    long long twoE = 2LL * E;
    for (int u = 0; u < EPB / 256; ++u) {
        long long idx = start + u * 256 + t;
        if (idx < twoE) {
            int r = idx >= E;
            int e = (int)(idx - (long long)r * E);
            int d = edges[(size_t)r * 2 * E + E + e];
            atomicAdd(&cnt[r * NBK + (d >> 7)], 1);
        }
    }
    __syncthreads();
    for (int k = t; k < rbT; k += 256)
        if (cnt[k]) atomicAdd(&bcnt[k], cnt[k]);
}

// ---- radix pass B: exclusive scan of bucket counts ----------------------
__global__ __launch_bounds__(1024) void
bucket_scan_kernel(const int* __restrict__ bcnt, int* __restrict__ bko,
                   int rbT, int twoE)
{
    __shared__ int sm[1024];
    int t = threadIdx.x;
    int v = (t < rbT) ? bcnt[t] : 0;
    sm[t] = v;
    __syncthreads();
    for (int s = 1; s < 1024; s <<= 1) {
        int u = (t >= s) ? sm[t - s] : 0;
        __syncthreads();
        sm[t] += u;
        __syncthreads();
    }
    if (t < rbT) bko[t] = sm[t] - v;
    if (t == 0) bko[rbT] = twoE;
}

// ---- radix pass C: partition into bucket-grouped (src,dst) pairs --------
__global__ __launch_bounds__(256) void
partition_kernel(const int* __restrict__ edges, const int* __restrict__ bko,
                 int* __restrict__ gcur, uint2* __restrict__ staging,
                 int NBK, int E)
{
    __shared__ int cnt[2 * NBK_MAX];
    __shared__ int base[2 * NBK_MAX];
    const int rbT = 2 * NBK;
    const int t = threadIdx.x;
    for (int k = t; k < rbT; k += 256) cnt[k] = 0;
    __syncthreads();
    long long start = (long long)blockIdx.x * EPB;
    long long twoE = 2LL * E;
    for (int u = 0; u < EPB / 256; ++u) {
        long long idx = start + u * 256 + t;
        if (idx < twoE) {
            int r = idx >= E;
            int e = (int)(idx - (long long)r * E);
            int d = edges[(size_t)r * 2 * E + E + e];
            atomicAdd(&cnt[r * NBK + (d >> 7)], 1);
        }
    }
    __syncthreads();
    for (int k = t; k < rbT; k += 256) {
        int c0 = cnt[k];
        if (c0) base[k] = bko[k] + atomicAdd(&gcur[k], c0);
        cnt[k] = 0;
    }
    __syncthreads();
    for (int u = 0; u < EPB / 256; ++u) {
        long long idx = start + u * 256 + t;
        if (idx < twoE) {
            int r = idx >= E;
            int e = (int)(idx - (long long)r * E);
            int s = edges[(size_t)r * 2 * E + e];
            int d = edges[(size_t)r * 2 * E + E + e];
            int rb = r * NBK + (d >> 7);
            int pos = atomicAdd(&cnt[rb], 1);
            staging[(size_t)base[rb] + pos] = make_uint2((unsigned)s, (unsigned)d);
        }
    }
}

// ---- radix pass D: per-bucket node hist/scan -> off[] and csr[] ----------
__global__ __launch_bounds__(256) void
bucket_csr_kernel(const uint2* __restrict__ staging, const int* __restrict__ bko,
                  int* __restrict__ csr, int* __restrict__ off,
                  int NBK, int N)
{
    __shared__ int hist[BW], excl[BW], cur[BW], sc[BW];
    const int rb = blockIdx.x;
    const int r = rb / NBK;
    const int b = rb % NBK;
    const int node0 = b * BW;
    const int nn = min(BW, N - node0);
    const int cbase = bko[rb];
    const int c = bko[rb + 1] - cbase;
    const int t = threadIdx.x;

    if (t < BW) { hist[t] = 0; cur[t] = 0; }
    __syncthreads();
    for (int k = t; k < c; k += 256)
        atomicAdd(&hist[(int)staging[(size_t)cbase + k].y - node0], 1);
    __syncthreads();
    if (t < BW) sc[t] = hist[t];
    __syncthreads();
    for (int s = 1; s < BW; s <<= 1) {
        int v = (t < BW && t >= s) ? sc[t - s] : 0;
        __syncthreads();
        if (t < BW) sc[t] += v;
        __syncthreads();
    }
    if (t < BW) excl[t] = sc[t] - hist[t];
    if (t < nn) off[(size_t)r * N + node0 + t] = cbase + excl[t];
    __syncthreads();
    for (int k = t; k < c; k += 256) {
        uint2 pr = staging[(size_t)cbase + k];
        int l = (int)pr.y - node0;
        int pos = atomicAdd(&cur[l], 1);
        csr[(size_t)cbase + excl[l] + pos] = (int)pr.x;
    }
}

// ---- f32 -> bf16 [N,128] + fp8 [N,128] ----------------------------------
__global__ void cvt_kernel(const float* __restrict__ in,
                           unsigned short* __restrict__ o,
                           unsigned char* __restrict__ o8, int n4)
{
    int t = blockIdx.x * blockDim.x + threadIdx.x;
    if (t >= n4) return;
    float4 v = ((const float4*)in)[t];
    ushort4 r;
    r.x = f2bf(v.x); r.y = f2bf(v.y); r.z = f2bf(v.z); r.w = f2bf(v.w);
    ((ushort4*)o)[t] = r;
    ((unsigned*)o8)[t] = f32x4_fp8x4(v.x, v.y, v.z, v.w);
}

// ---- weight prep: combined-Wself / Wn -> bf16 W^T rows, biases ----------
__global__ void prep_kernel(const float* __restrict__ Ws1, const float* __restrict__ Wn1,
                            const float* __restrict__ b1,
                            const float* __restrict__ Ws2, const float* __restrict__ Wn2,
                            const float* __restrict__ b2,
                            unsigned short* __restrict__ WT1z, unsigned short* __restrict__ WT1a,
                            unsigned short* __restrict__ WT1b, float* __restrict__ bc1,
                            unsigned short* __restrict__ WT2z, unsigned short* __restrict__ WT2a,
                            unsigned short* __restrict__ WT2b, float* __restrict__ bc2)
{
    int t = blockIdx.x * blockDim.x + threadIdx.x;
    if (t < 16384) {                 // layer 1: [n][k] <- [k][n], n,k < 128
        int n = t >> 7, k = t & 127;
        int in = k * 128 + n;
        WT1z[t] = f2bf(Ws1[in] + Ws1[16384 + in]);
        WT1a[t] = f2bf(Wn1[in]);
        WT1b[t] = f2bf(Wn1[16384 + in]);
    }
    if (t < 8192) {                  // layer 2: n < 64, k < 128
        int n = t >> 7, k = t & 127;
        int in = k * 64 + n;
        WT2z[t] = f2bf(Ws2[in] + Ws2[8192 + in]);
        WT2a[t] = f2bf(Wn2[in]);
        WT2b[t] = f2bf(Wn2[8192 + in]);
    }
    if (t < 128) bc1[t] = b1[t] + b1[128 + t];
    if (t < 64)  bc2[t] = b2[t] + b2[64 + t];
}

// ---- agg L1: wave per node, fp8 gathers (128B/row), unroll x8 -----------
__global__ __launch_bounds__(256) void
agg1_kernel(const unsigned char* __restrict__ xb8,
            const int* __restrict__ csr, const int* __restrict__ off,
            unsigned short* __restrict__ m0, unsigned short* __restrict__ m1,
            int N, int twoE)
{
    int w = blockIdx.x * 4 + (threadIdx.x >> 6);
    int lane = threadIdx.x & 63;
    if (w >= N) return;
    const int col = lane * 2;
    const unsigned char* xc = xb8 + col;

    float sx0 = 0.f, sy0 = 0.f, sx1 = 0.f, sy1 = 0.f;

    // ---- relation 0 ----
    int o0 = RFL(off[w]);
    int o1 = RFL(off[w + 1]);
    int d0 = o1 - o0;
    int j = o0;
    for (; j + 7 < o1; j += 8) {
        int s0 = RFL(csr[j]);     int s1 = RFL(csr[j + 1]);
        int s2 = RFL(csr[j + 2]); int s3 = RFL(csr[j + 3]);
        int s4 = RFL(csr[j + 4]); int s5 = RFL(csr[j + 5]);
        int s6 = RFL(csr[j + 6]); int s7 = RFL(csr[j + 7]);
        unsigned a0 = *(const unsigned short*)(xc + (size_t)s0 * 128);
        unsigned a1 = *(const unsigned short*)(xc + (size_t)s1 * 128);
        unsigned a2 = *(const unsigned short*)(xc + (size_t)s2 * 128);
        unsigned a3 = *(const unsigned short*)(xc + (size_t)s3 * 128);
        unsigned a4 = *(const unsigned short*)(xc + (size_t)s4 * 128);
        unsigned a5 = *(const unsigned short*)(xc + (size_t)s5 * 128);
        unsigned a6 = *(const unsigned short*)(xc + (size_t)s6 * 128);
        unsigned a7 = *(const unsigned short*)(xc + (size_t)s7 * 128);
        floatx2 v0 = fp8x2_f32(a0); floatx2 v1 = fp8x2_f32(a1);
        floatx2 v2 = fp8x2_f32(a2); floatx2 v3 = fp8x2_f32(a3);
        floatx2 v4 = fp8x2_f32(a4); floatx2 v5 = fp8x2_f32(a5);
        floatx2 v6 = fp8x2_f32(a6); floatx2 v7 = fp8x2_f32(a7);
        sx0 += ((v0.x + v1.x) + (v2.x + v3.x)) + ((v4.x + v5.x) + (v6.x + v7.x));
        sy0 += ((v0.y + v1.y) + (v2.y + v3.y)) + ((v4.y + v5.y) + (v6.y + v7.y));
    }
    for (; j < o1; ++j) {
        int s0 = RFL(csr[j]);
        floatx2 v = fp8x2_f32(*(const unsigned short*)(xc + (size_t)s0 * 128));
        sx0 += v.x; sy0 += v.y;
    }

    // ---- relation 1 ----
    int p = N + w;
    o0 = RFL(off[p]);
    o1 = (p + 1 < 2 * N) ? RFL(off[p + 1]) : twoE;
    int d1 = o1 - o0;
    j = o0;
    for (; j + 7 < o1; j += 8) {
        int s0 = RFL(csr[j]);     int s1 = RFL(csr[j + 1]);
        int s2 = RFL(csr[j + 2]); int s3 = RFL(csr[j + 3]);
        int s4 = RFL(csr[j + 4]); int s5 = RFL(csr[j + 5]);
        int s6 = RFL(csr[j + 6]); int s7 = RFL(csr[j + 7]);
        unsigned a0 = *(const unsigned short*)(xc + (size_t)s0 * 128);
        unsigned a1 = *(const unsigned short*)(xc + (size_t)s1 * 128);
        unsigned a2 = *(const unsigned short*)(xc + (size_t)s2 * 128);
        unsigned a3 = *(const unsigned short*)(xc + (size_t)s3 * 128);
        unsigned a4 = *(const unsigned short*)(xc + (size_t)s4 * 128);
        unsigned a5 = *(const unsigned short*)(xc + (size_t)s5 * 128);
        unsigned a6 = *(const unsigned short*)(xc + (size_t)s6 * 128);
        unsigned a7 = *(const unsigned short*)(xc + (size_t)s7 * 128);
        floatx2 v0 = fp8x2_f32(a0); floatx2 v1 = fp8x2_f32(a1);
        floatx2 v2 = fp8x2_f32(a2); floatx2 v3 = fp8x2_f32(a3);
        floatx2 v4 = fp8x2_f32(a4); floatx2 v5 = fp8x2_f32(a5);
        floatx2 v6 = fp8x2_f32(a6); floatx2 v7 = fp8x2_f32(a7);
        sx1 += ((v0.x + v1.x) + (v2.x + v3.x)) + ((v4.x + v5.x) + (v6.x + v7.x));
        sy1 += ((v0.y + v1.y) + (v2.y + v3.y)) + ((v4.y + v5.y) + (v6.y + v7.y));
    }
    for (; j < o1; ++j) {
        int s0 = RFL(csr[j]);
        floatx2 v = fp8x2_f32(*(const unsigned short*)(xc + (size_t)s0 * 128));
        sx1 += v.x; sy1 += v.y;
    }

    float inv0 = 1.0f / fmaxf((float)d0, 1.0f);
    float inv1 = 1.0f / fmaxf((float)d1, 1.0f);
    *(unsigned*)(m0 + (size_t)w * 128 + col) = pack2(sx0 * inv0, sy0 * inv0);
    *(unsigned*)(m1 + (size_t)w * 128 + col) = pack2(sx1 * inv1, sy1 * inv1);
}

// ---- fused layer-1 GEMM: h1 = relu(x@WTz + m0@WTa + m1@WTb + bias) ------
__global__ __launch_bounds__(256) void
gemm1_fused_kernel(const unsigned short* __restrict__ xb,
                   const unsigned short* __restrict__ m0,
                   const unsigned short* __restrict__ m1,
                   const unsigned short* __restrict__ WTz,
                   const unsigned short* __restrict__ WTa,
                   const unsigned short* __restrict__ WTb,
                   const float* __restrict__ bias,
                   unsigned short* __restrict__ h1b, int N)
{
    __shared__ float eb[64][129];

    const int tid = threadIdx.x;
    const int wave = tid >> 6;
    const int lane = tid & 63;
    const int m = lane & 15;
    const int quad = lane >> 4;

    floatx4 acc[8];
    const floatx4 z4 = {0.f, 0.f, 0.f, 0.f};
#pragma unroll
    for (int t = 0; t < 8; ++t) acc[t] = z4;

    int arow = blockIdx.x * 64 + wave * 16 + m;
    if (arow >= N) arow = N - 1;
    const size_t abase = (size_t)arow * 128 + quad * 8;

#pragma unroll
    for (int s = 0; s < 4; ++s) {
        bf16x8 ax = *(const bf16x8*)(xb + abase + s * 32);
        bf16x8 a0 = *(const bf16x8*)(m0 + abase + s * 32);
        bf16x8 a1 = *(const bf16x8*)(m1 + abase + s * 32);
#pragma unroll
        for (int t = 0; t < 8; ++t) {
            const size_t bo = (size_t)(t * 16 + m) * 128 + s * 32 + quad * 8;
            acc[t] = __builtin_amdgcn_mfma_f32_16x16x32_bf16(
                ax, *(const bf16x8*)(WTz + bo), acc[t], 0, 0, 0);
            acc[t] = __builtin_amdgcn_mfma_f32_16x16x32_bf16(
                a0, *(const bf16x8*)(WTa + bo), acc[t], 0, 0, 0);
            acc[t] = __builtin_amdgcn_mfma_f32_16x16x32_bf16(
                a1, *(const bf16x8*)(WTb + bo), acc[t], 0, 0, 0);
        }
    }

    // C/D: col = lane&15, row = quad*4 + reg -> LDS transpose epilogue
#pragma unroll
    for (int t = 0; t < 8; ++t)
#pragma unroll
        for (int i = 0; i < 4; ++i)
            eb[wave * 16 + quad * 4 + i][t * 16 + m] = acc[t][i];
    __syncthreads();

#pragma unroll
    for (int j = 0; j < 4; ++j) {
        int lr = wave * 16 + j * 4 + quad;
        int grow = blockIdx.x * 64 + lr;
        if (grow < N) {
#pragma unroll
            for (int i = 0; i < 2; ++i) {
                int c0 = (i * 16 + m) * 4;
                float v0 = fmaxf(eb[lr][c0 + 0] + bias[c0 + 0], 0.0f);
                float v1 = fmaxf(eb[lr][c0 + 1] + bias[c0 + 1], 0.0f);
                float v2 = fmaxf(eb[lr][c0 + 2] + bias[c0 + 2], 0.0f);
                float v3 = fmaxf(eb[lr][c0 + 3] + bias[c0 + 3], 0.0f);
                ushort4 u;
                u.x = f2bf(v0); u.y = f2bf(v1); u.z = f2bf(v2); u.w = f2bf(v3);
                *(ushort4*)(h1b + (size_t)grow * 128 + c0) = u;
            }
        }
    }
}

// ---- fused layer-2 GEMM: h1b -> z2 (f32+bias), t0/t1 (fp8) --------------
__global__ __launch_bounds__(256) void
gemm2_fused_kernel(const unsigned short* __restrict__ Ab,
                   const unsigned short* __restrict__ WTz,
                   const unsigned short* __restrict__ WTa,
                   const unsigned short* __restrict__ WTb,
                   const float* __restrict__ bias,
                   float* __restrict__ zf,
                   unsigned char* __restrict__ t08, unsigned char* __restrict__ t18,
                   int N)
{
    __shared__ float eb[64][65];

    const int tid = threadIdx.x;
    const int wave = tid >> 6;
    const int lane = tid & 63;
    const int m = lane & 15;
    const int quad = lane >> 4;

    floatx4 accz[4], acca[4], accb[4];
    const floatx4 z4 = {0.f, 0.f, 0.f, 0.f};
#pragma unroll
    for (int t = 0; t < 4; ++t) { accz[t] = z4; acca[t] = z4; accb[t] = z4; }

    int arow = blockIdx.x * 64 + wave * 16 + m;
    if (arow >= N) arow = N - 1;
    const unsigned short* aptr = Ab + (size_t)arow * 128 + quad * 8;

#pragma unroll
    for (int s = 0; s < 4; ++s) {
        bf16x8 a = *(const bf16x8*)(aptr + s * 32);
#pragma unroll
        for (int t = 0; t < 4; ++t) {
            const size_t bo = (size_t)(t * 16 + m) * 128 + s * 32 + quad * 8;
            accz[t] = __builtin_amdgcn_mfma_f32_16x16x32_bf16(
                a, *(const bf16x8*)(WTz + bo), accz[t], 0, 0, 0);
            acca[t] = __builtin_amdgcn_mfma_f32_16x16x32_bf16(
                a, *(const bf16x8*)(WTa + bo), acca[t], 0, 0, 0);
            accb[t] = __builtin_amdgcn_mfma_f32_16x16x32_bf16(
                a, *(const bf16x8*)(WTb + bo), accb[t], 0, 0, 0);
        }
    }

    // ---- round z: f32 + bias ----
#pragma unroll
    for (int t = 0; t < 4; ++t)
#pragma unroll
        for (int i = 0; i < 4; ++i)
            eb[wave * 16 + quad * 4 + i][t * 16 + m] = accz[t][i];
    __syncthreads();
#pragma unroll
    for (int j = 0; j < 4; ++j) {
        int lr = wave * 16 + j * 4 + quad;
        int gr = blockIdx.x * 64 + lr;
        if (gr < N) {
            int c0 = m * 4;
            float4 o;
            o.x = eb[lr][c0 + 0] + bias[c0 + 0];
            o.y = eb[lr][c0 + 1] + bias[c0 + 1];
            o.z = eb[lr][c0 + 2] + bias[c0 + 2];
            o.w = eb[lr][c0 + 3] + bias[c0 + 3];
            *(float4*)(zf + (size_t)gr * 64 + c0) = o;
        }
    }
    __syncthreads();

    // ---- round a: fp8 ----
#pragma unroll
    for (int t = 0; t < 4; ++t)
#pragma unroll
        for (int i = 0; i < 4; ++i)
            eb[wave * 16 + quad * 4 + i][t * 16 + m] = acca[t][i];
    __syncthreads();
#pragma unroll
    for (int j = 0; j < 4; ++j) {
        int lr = wave * 16 + j * 4 + quad;
        int gr = blockIdx.x * 64 + lr;
        if (gr < N) {
            int c0 = m * 4;
            *(unsigned*)(t08 + (size_t)gr * 64 + c0) = f32x4_fp8x4(
                eb[lr][c0 + 0], eb[lr][c0 + 1], eb[lr][c0 + 2], eb[lr][c0 + 3]);
        }
    }
    __syncthreads();

    // ---- round b: fp8 ----
#pragma unroll
    for (int t = 0; t < 4; ++t)
#pragma unroll
        for (int i = 0; i < 4; ++i)
            eb[wave * 16 + quad * 4 + i][t * 16 + m] = accb[t][i];
    __syncthreads();
#pragma unroll
    for (int j = 0; j < 4; ++j) {
        int lr = wave * 16 + j * 4 + quad;
        int gr = blockIdx.x * 64 + lr;
        if (gr < N) {
            int c0 = m * 4;
            *(unsigned*)(t18 + (size_t)gr * 64 + c0) = f32x4_fp8x4(
                eb[lr][c0 + 0], eb[lr][c0 + 1], eb[lr][c0 + 2], eb[lr][c0 + 3]);
        }
    }
}

// ---- agg L2: wave per node, fp8 gathers (64B/row), half-wave stride-2 ---
__global__ __launch_bounds__(256) void
agg2_kernel(const unsigned char* __restrict__ t08,
            const unsigned char* __restrict__ t18,
            const float* __restrict__ z2,
            const int* __restrict__ csr, const int* __restrict__ off,
            unsigned short* __restrict__ h2b, int N, int twoE)
{
    int w = blockIdx.x * 4 + (threadIdx.x >> 6);
    int lane = threadIdx.x & 63;
    if (w >= N) return;
    const int half = lane >> 5;
    const int col = (lane & 31) * 2;
    const unsigned char* t0c = t08 + col;
    const unsigned char* t1c = t18 + col;

    float sx0 = 0.f, sy0 = 0.f, sx1 = 0.f, sy1 = 0.f;
    int o0 = RFL(off[w]);
    int o1 = RFL(off[w + 1]);
    int d0 = o1 - o0;
    int j = o0 + half;
    for (; j + 6 < o1; j += 8) {
        int s0 = csr[j], s1 = csr[j + 2], s2 = csr[j + 4], s3 = csr[j + 6];
        unsigned a0 = *(const unsigned short*)(t0c + (size_t)s0 * 64);
        unsigned a1 = *(const unsigned short*)(t0c + (size_t)s1 * 64);
        unsigned a2 = *(const unsigned short*)(t0c + (size_t)s2 * 64);
        unsigned a3 = *(const unsigned short*)(t0c + (size_t)s3 * 64);
        floatx2 v0 = fp8x2_f32(a0); floatx2 v1 = fp8x2_f32(a1);
        floatx2 v2 = fp8x2_f32(a2); floatx2 v3 = fp8x2_f32(a3);
        sx0 += (v0.x + v1.x) + (v2.x + v3.x);
        sy0 += (v0.y + v1.y) + (v2.y + v3.y);
    }
    for (; j < o1; j += 2) {
        floatx2 v = fp8x2_f32(*(const unsigned short*)(t0c + (size_t)csr[j] * 64));
        sx0 += v.x; sy0 += v.y;
    }
    int p = N + w;
    o0 = RFL(off[p]);
    o1 = (p + 1 < 2 * N) ? RFL(off[p + 1]) : twoE;
    int d1 = o1 - o0;
    j = o0 + half;
    for (; j + 6 < o1; j += 8) {
        int s0 = csr[j], s1 = csr[j + 2], s2 = csr[j + 4], s3 = csr[j + 6];
        unsigned a0 = *(const unsigned short*)(t1c + (size_t)s0 * 64);
        unsigned a1 = *(const unsigned short*)(t1c + (size_t)s1 * 64);
        unsigned a2 = *(const unsigned short*)(t1c + (size_t)s2 * 64);
        unsigned a3 = *(const unsigned short*)(t1c + (size_t)s3 * 64);
        floatx2 v0 = fp8x2_f32(a0); floatx2 v1 = fp8x2_f32(a1);
        floatx2 v2 = fp8x2_f32(a2); floatx2 v3 = fp8x2_f32(a3);
        sx1 += (v0.x + v1.x) + (v2.x + v3.x);
        sy1 += (v0.y + v1.y) + (v2.y + v3.y);
    }
    for (; j < o1; j += 2) {
        floatx2 v = fp8x2_f32(*(const unsigned short*)(t1c + (size_t)csr[j] * 64));
        sx1 += v.x; sy1 += v.y;
    }
    sx0 += __shfl_xor(sx0, 32);
    sy0 += __shfl_xor(sy0, 32);
    sx1 += __shfl_xor(sx1, 32);
    sy1 += __shfl_xor(sy1, 32);
    if (half == 0) {
        float inv0 = 1.0f / fmaxf((float)d0, 1.0f);
        float inv1 = 1.0f / fmaxf((float)d1, 1.0f);
        float2 z = *(const float2*)(z2 + (size_t)w * 64 + col);
        float hx = z.x + sx0 * inv0 + sx1 * inv1;
        float hy = z.y + sy0 * inv0 + sy1 * inv1;
        *(unsigned*)(h2b + (size_t)w * 64 + col) = pack2(hx, hy);
    }
}

// ---- score (merged pos+neg): 8 lanes/edge, 128B rows, shfl reduce --------
__global__ __launch_bounds__(256) void
score_kernel(const unsigned short* __restrict__ h, // [N,64] bf16
             const int* __restrict__ edges, const int* __restrict__ neg,
             float* __restrict__ out, int E, int En)
{
    int t = blockIdx.x * blockDim.x + threadIdx.x;
    int e = t >> 3;
    int c = t & 7;
    if (e >= E + En) return;
    int sI, dI, oI;
    if (e < E) { sI = edges[e]; dI = edges[E + e]; oI = e; }
    else { int en = e - E; sI = neg[en]; dI = neg[En + en]; oI = E + en; }
    uint4 va = *(const uint4*)(h + (size_t)sI * 64 + c * 8);
    uint4 vb = *(const uint4*)(h + (size_t)dI * 64 + c * 8);
    float s = 0.0f;
    s = fmaf(bflo(va.x), bflo(vb.x), s);
    s = fmaf(bfhi(va.x), bfhi(vb.x), s);
    s = fmaf(bflo(va.y), bflo(vb.y), s);
    s = fmaf(bfhi(va.y), bfhi(vb.y), s);
    s = fmaf(bflo(va.z), bflo(vb.z), s);
    s = fmaf(bfhi(va.z), bfhi(vb.z), s);
    s = fmaf(bflo(va.w), bflo(vb.w), s);
    s = fmaf(bfhi(va.w), bfhi(vb.w), s);
    s += __shfl_xor(s, 1);
    s += __shfl_xor(s, 2);
    s += __shfl_xor(s, 4);
    if (c == 0) out[oI] = s;
}

extern "C" void kernel_launch(void* const* d_in, const int* in_sizes, int n_in,
                              void* d_out, int out_size, void* d_ws, size_t ws_size,
                              hipStream_t stream)
{
    const float* x     = (const float*)d_in[0];
    const int*   edges = (const int*)d_in[1];
    const int*   neg   = (const int*)d_in[2];
    const float* Wn1   = (const float*)d_in[3];
    const float* Ws1   = (const float*)d_in[4];
    const float* b1    = (const float*)d_in[5];
    const float* Wn2   = (const float*)d_in[6];
    const float* Ws2   = (const float*)d_in[7];
    const float* b2    = (const float*)d_in[8];
    float* out = (float*)d_out;

    const int Fin = 128, R = 2;
    const int N  = in_sizes[0] / Fin;        // 50000
    const int E  = in_sizes[1] / (R * 2);    // 800000
    const int En = in_sizes[2] / 2;          // 800000
    const int twoE = 2 * E;
    const int NBK = (N + BW - 1) / BW;       // 391
    const int rbT = 2 * NBK;

    // ---- workspace layout (aliases noted) ----
    const size_t nb128 = (size_t)N * 128 * sizeof(unsigned short);   // 12.8MB
    char* p = (char*)d_ws;

    // region0: staging [2E] (CSR build) -> xb8 [N,128] fp8 (cvt..agg1)
    //          -> z2 [N,64] f32 (gemm2..agg2). Lifetimes strictly ordered.
    uint2* staging       = (uint2*)p;
    unsigned char* xb8   = (unsigned char*)p;
    float* z2            = (float*)p;
    {
        size_t r0 = (size_t)twoE * sizeof(uint2);          // 12.8MB
        size_t r1 = (size_t)N * 64 * sizeof(float);        // 12.8MB
        size_t r2 = (size_t)N * 128;                       // 6.4MB
        size_t rm = r0 > r1 ? r0 : r1;
        if (r2 > rm) rm = r2;
        p += rm;
    }
    unsigned short* m0  = (unsigned short*)p; p += nb128;  // [N,128] mean rel0 (t08/t18 reuse)
    unsigned short* m1  = (unsigned short*)p; p += nb128;  // [N,128] mean rel1 (h2b reuse)
    unsigned short* xb  = (unsigned short*)p; p += nb128;  // [N,128] bf16 x
    unsigned short* h1b = (unsigned short*)p; p += nb128;  // [N,128] bf16 h1
    unsigned short* WT1z = (unsigned short*)p; p += 16384 * 2;
    unsigned short* WT1a = (unsigned short*)p; p += 16384 * 2;
    unsigned short* WT1b = (unsigned short*)p; p += 16384 * 2;
    unsigned short* WT2z = (unsigned short*)p; p += 8192 * 2;
    unsigned short* WT2a = (unsigned short*)p; p += 8192 * 2;
    unsigned short* WT2b = (unsigned short*)p; p += 8192 * 2;
    float* bc1 = (float*)p; p += 128 * sizeof(float);
    float* bc2 = (float*)p; p += 64 * sizeof(float);
    int* bcnt = (int*)p; p += (size_t)2 * NBK_MAX * sizeof(int);
    int* gcur = (int*)p; p += (size_t)2 * NBK_MAX * sizeof(int);
    int* bko  = (int*)p; p += ((size_t)2 * NBK_MAX + 1) * sizeof(int);
    int* off  = (int*)p; p += (size_t)2 * N * sizeof(int);
    int* csr  = (int*)p;

    unsigned char*  t08 = (unsigned char*)m0;        // [N,64] fp8
    unsigned char*  t18 = t08 + (size_t)N * 64;      // [N,64] fp8
    unsigned short* h2b = m1;                        // [N,64] bf16

    const int BS = 256;
    const int edge_blocks = (twoE + EPB - 1) / EPB;
    const int gx = (N + 63) / 64;

    // ---- CSR build (radix by dst bucket) ----
    hipMemsetAsync(bcnt, 0, (size_t)4 * NBK_MAX * sizeof(int), stream);
    bucket_count_kernel<<<edge_blocks, BS, 0, stream>>>(edges, bcnt, NBK, E);
    bucket_scan_kernel<<<1, 1024, 0, stream>>>(bcnt, bko, rbT, twoE);
    partition_kernel<<<edge_blocks, BS, 0, stream>>>(edges, bko, gcur, staging, NBK, E);
    bucket_csr_kernel<<<rbT, BS, 0, stream>>>(staging, bko, csr, off, NBK, N);

    // ---- prep (cvt AFTER bucket_csr: xb8 aliases dead staging) ----
    cvt_kernel<<<(N * 32 + BS - 1) / BS, BS, 0, stream>>>(x, xb, xb8, N * 32);
    prep_kernel<<<(16384 + BS - 1) / BS, BS, 0, stream>>>(
        Ws1, Wn1, b1, Ws2, Wn2, b2,
        WT1z, WT1a, WT1b, bc1, WT2z, WT2a, WT2b, bc2);

    // ---- Layer 1: fp8 aggregate, then fused 3-matmul GEMM + bias + relu
    agg1_kernel<<<(N + 3) / 4, BS, 0, stream>>>(xb8, csr, off, m0, m1, N, twoE);
    gemm1_fused_kernel<<<gx, BS, 0, stream>>>(xb, m0, m1, WT1z, WT1a, WT1b,
                                              bc1, h1b, N);

    // ---- Layer 2: one fused transform (z2 f32, t0/t1 fp8), then aggregate
    gemm2_fused_kernel<<<gx, BS, 0, stream>>>(h1b, WT2z, WT2a, WT2b, bc2,
                                              z2, t08, t18, N);
    agg2_kernel<<<(N + 3) / 4, BS, 0, stream>>>(t08, t18, z2, csr, off, h2b, N, twoE);

    // ---- Scores (pos + neg in one launch) ----
    score_kernel<<<((E + En) * 8 + BS - 1) / BS, BS, 0, stream>>>(
        h2b, edges, neg, out, E, En);
}

// Round 7
// 373.379 us; speedup vs baseline: 1.2827x; 1.0080x over previous
//
#include <hip/hip_runtime.h>

// ---------------------------------------------------------------------------
// GraphSAGE 2-layer hetero (R=2) + edge dot scorer.  Round 15:
//  * agg kernels restructured to cut VMEM instructions/edge in half while
//    keeping round-14's fp8 payloads (agg2 was issue-bound: HBM 16%,
//    VALU 33%, nothing saturated):
//    - agg1: HALF-wave per edge. 32 lanes x 4B(uint) = one 128B fp8 row
//      per half -> 2 edges per gather instr (was 1). Indices via
//      csr[j+2k+half] (adjacent pair = 1 segment). Named scalars only.
//    - agg2: QUARTER-wave per edge. 16 lanes x 4B = one 64B fp8 row per
//      quarter -> 4 edges per gather instr. Indices csr[j+4k+q].
//      (Round-12 data: this exact shape did 1.6M x 64B in ~32us/pass.)
//  * Dequant via hw v_cvt_pk_f32_fp8 word-select (lo/hi of a uint).
//  * Everything else verbatim round 14 (CSR radix build, fused GEMMs,
//    fp8 t0/t1 epilogue, bf16 h2b + score, workspace aliasing).
// ---------------------------------------------------------------------------

#define BW 128            // nodes per radix bucket (pow2)
#define NBK_MAX 1024
#define EPB 8192          // edges per block in radix passes

typedef __attribute__((ext_vector_type(8))) short bf16x8;
typedef __attribute__((ext_vector_type(4))) float floatx4;
typedef __attribute__((ext_vector_type(2))) float floatx2;

__device__ __forceinline__ unsigned short f2bf(float f) {
    unsigned u = __float_as_uint(f);
    unsigned r = u + 0x7FFFu + ((u >> 16) & 1u);
    return (unsigned short)(r >> 16);
}
__device__ __forceinline__ unsigned pack2(float a, float b) {
    return (unsigned)f2bf(a) | ((unsigned)f2bf(b) << 16);
}
__device__ __forceinline__ float bflo(unsigned v) { return __uint_as_float(v << 16); }
__device__ __forceinline__ float bfhi(unsigned v) { return __uint_as_float(v & 0xFFFF0000u); }
#define RFL(x) __builtin_amdgcn_readfirstlane(x)

// ---- fp8 e4m3 helpers (hw cvt when available, bit-math fallback) --------
#if defined(__has_builtin) && __has_builtin(__builtin_amdgcn_cvt_pk_f32_fp8)
__device__ __forceinline__ floatx2 fp8lo(unsigned v) {
    return __builtin_amdgcn_cvt_pk_f32_fp8((int)v, false);
}
__device__ __forceinline__ floatx2 fp8hi(unsigned v) {
    return __builtin_amdgcn_cvt_pk_f32_fp8((int)v, true);
}
#else
__device__ __forceinline__ float fp8_1(unsigned b) {
    return __uint_as_float(((b & 0x80u) << 24) | ((b & 0x7Fu) << 20)) * 0x1.0p+120f;
}
__device__ __forceinline__ floatx2 fp8lo(unsigned v) {
    floatx2 r; r.x = fp8_1(v & 0xFFu); r.y = fp8_1((v >> 8) & 0xFFu); return r;
}
__device__ __forceinline__ floatx2 fp8hi(unsigned v) {
    floatx2 r; r.x = fp8_1((v >> 16) & 0xFFu); r.y = fp8_1((v >> 24) & 0xFFu); return r;
}
#endif

#if defined(__has_builtin) && __has_builtin(__builtin_amdgcn_cvt_pk_fp8_f32)
__device__ __forceinline__ unsigned f32x4_fp8x4(float a, float b, float c, float d) {
    unsigned lo = __builtin_amdgcn_cvt_pk_fp8_f32(a, b, 0, false);
    return __builtin_amdgcn_cvt_pk_fp8_f32(c, d, lo, true);
}
#else
__device__ __forceinline__ unsigned f2fp8(float x) {
    float m = fminf(fabsf(x), 448.0f);
    unsigned u = __float_as_uint(m * 0x1.0p-120f);
    unsigned r = (u + 0x7FFFFu + ((u >> 20) & 1u)) >> 20;
    if (r > 0x7Eu) r = 0x7Eu;
    return r | ((__float_as_uint(x) >> 24) & 0x80u);
}
__device__ __forceinline__ unsigned f32x4_fp8x4(float a, float b, float c, float d) {
    return f2fp8(a) | (f2fp8(b) << 8) | (f2fp8(c) << 16) | (f2fp8(d) << 24);
}
#endif

// ---- radix pass A: per-(r,bucket) counts --------------------------------
__global__ __launch_bounds__(256) void
bucket_count_kernel(const int* __restrict__ edges, int* __restrict__ bcnt,
                    int NBK, int E)
{
    __shared__ int cnt[2 * NBK_MAX];
    const int rbT = 2 * NBK;
    const int t = threadIdx.x;
    for (int k = t; k < rbT; k += 256) cnt[k] = 0;
    __syncthreads();
    long long start = (long long)blockIdx.x * EPB;
    long long twoE = 2LL * E;
    for (int u = 0; u < EPB / 256; ++u) {
        long long idx = start + u * 256 + t;
        if (idx < twoE) {
            int r = idx >= E;
            int e = (int)(idx - (long long)r * E);
            int d = edges[(size_t)r * 2 * E + E + e];
            atomicAdd(&cnt[r * NBK + (d >> 7)], 1);
        }
    }
    __syncthreads();
    for (int k = t; k < rbT; k += 256)
        if (cnt[k]) atomicAdd(&bcnt[k], cnt[k]);
}

// ---- radix pass B: exclusive scan of bucket counts ----------------------
__global__ __launch_bounds__(1024) void
bucket_scan_kernel(const int* __restrict__ bcnt, int* __restrict__ bko,
                   int rbT, int twoE)
{
    __shared__ int sm[1024];
    int t = threadIdx.x;
    int v = (t < rbT) ? bcnt[t] : 0;
    sm[t] = v;
    __syncthreads();
    for (int s = 1; s < 1024; s <<= 1) {
        int u = (t >= s) ? sm[t - s] : 0;
        __syncthreads();
        sm[t] += u;
        __syncthreads();
    }
    if (t < rbT) bko[t] = sm[t] - v;
    if (t == 0) bko[rbT] = twoE;
}

// ---- radix pass C: partition into bucket-grouped (src,dst) pairs --------
__global__ __launch_bounds__(256) void
partition_kernel(const int* __restrict__ edges, const int* __restrict__ bko,
                 int* __restrict__ gcur, uint2* __restrict__ staging,
                 int NBK, int E)
{
    __shared__ int cnt[2 * NBK_MAX];
    __shared__ int base[2 * NBK_MAX];
    const int rbT = 2 * NBK;
    const int t = threadIdx.x;
    for (int k = t; k < rbT; k += 256) cnt[k] = 0;
    __syncthreads();
    long long start = (long long)blockIdx.x * EPB;
    long long twoE = 2LL * E;
    for (int u = 0; u < EPB / 256; ++u) {
        long long idx = start + u * 256 + t;
        if (idx < twoE) {
            int r = idx >= E;
            int e = (int)(idx - (long long)r * E);
            int d = edges[(size_t)r * 2 * E + E + e];
            atomicAdd(&cnt[r * NBK + (d >> 7)], 1);
        }
    }
    __syncthreads();
    for (int k = t; k < rbT; k += 256) {
        int c0 = cnt[k];
        if (c0) base[k] = bko[k] + atomicAdd(&gcur[k], c0);
        cnt[k] = 0;
    }
    __syncthreads();
    for (int u = 0; u < EPB / 256; ++u) {
        long long idx = start + u * 256 + t;
        if (idx < twoE) {
            int r = idx >= E;
            int e = (int)(idx - (long long)r * E);
            int s = edges[(size_t)r * 2 * E + e];
            int d = edges[(size_t)r * 2 * E + E + e];
            int rb = r * NBK + (d >> 7);
            int pos = atomicAdd(&cnt[rb], 1);
            staging[(size_t)base[rb] + pos] = make_uint2((unsigned)s, (unsigned)d);
        }
    }
}

// ---- radix pass D: per-bucket node hist/scan -> off[] and csr[] ----------
__global__ __launch_bounds__(256) void
bucket_csr_kernel(const uint2* __restrict__ staging, const int* __restrict__ bko,
                  int* __restrict__ csr, int* __restrict__ off,
                  int NBK, int N)
{
    __shared__ int hist[BW], excl[BW], cur[BW], sc[BW];
    const int rb = blockIdx.x;
    const int r = rb / NBK;
    const int b = rb % NBK;
    const int node0 = b * BW;
    const int nn = min(BW, N - node0);
    const int cbase = bko[rb];
    const int c = bko[rb + 1] - cbase;
    const int t = threadIdx.x;

    if (t < BW) { hist[t] = 0; cur[t] = 0; }
    __syncthreads();
    for (int k = t; k < c; k += 256)
        atomicAdd(&hist[(int)staging[(size_t)cbase + k].y - node0], 1);
    __syncthreads();
    if (t < BW) sc[t] = hist[t];
    __syncthreads();
    for (int s = 1; s < BW; s <<= 1) {
        int v = (t < BW && t >= s) ? sc[t - s] : 0;
        __syncthreads();
        if (t < BW) sc[t] += v;
        __syncthreads();
    }
    if (t < BW) excl[t] = sc[t] - hist[t];
    if (t < nn) off[(size_t)r * N + node0 + t] = cbase + excl[t];
    __syncthreads();
    for (int k = t; k < c; k += 256) {
        uint2 pr = staging[(size_t)cbase + k];
        int l = (int)pr.y - node0;
        int pos = atomicAdd(&cur[l], 1);
        csr[(size_t)cbase + excl[l] + pos] = (int)pr.x;
    }
}

// ---- f32 -> bf16 [N,128] + fp8 [N,128] ----------------------------------
__global__ void cvt_kernel(const float* __restrict__ in,
                           unsigned short* __restrict__ o,
                           unsigned char* __restrict__ o8, int n4)
{
    int t = blockIdx.x * blockDim.x + threadIdx.x;
    if (t >= n4) return;
    float4 v = ((const float4*)in)[t];
    ushort4 r;
    r.x = f2bf(v.x); r.y = f2bf(v.y); r.z = f2bf(v.z); r.w = f2bf(v.w);
    ((ushort4*)o)[t] = r;
    ((unsigned*)o8)[t] = f32x4_fp8x4(v.x, v.y, v.z, v.w);
}

// ---- weight prep: combined-Wself / Wn -> bf16 W^T rows, biases ----------
__global__ void prep_kernel(const float* __restrict__ Ws1, const float* __restrict__ Wn1,
                            const float* __restrict__ b1,
                            const float* __restrict__ Ws2, const float* __restrict__ Wn2,
                            const float* __restrict__ b2,
                            unsigned short* __restrict__ WT1z, unsigned short* __restrict__ WT1a,
                            unsigned short* __restrict__ WT1b, float* __restrict__ bc1,
                            unsigned short* __restrict__ WT2z, unsigned short* __restrict__ WT2a,
                            unsigned short* __restrict__ WT2b, float* __restrict__ bc2)
{
    int t = blockIdx.x * blockDim.x + threadIdx.x;
    if (t < 16384) {                 // layer 1: [n][k] <- [k][n], n,k < 128
        int n = t >> 7, k = t & 127;
        int in = k * 128 + n;
        WT1z[t] = f2bf(Ws1[in] + Ws1[16384 + in]);
        WT1a[t] = f2bf(Wn1[in]);
        WT1b[t] = f2bf(Wn1[16384 + in]);
    }
    if (t < 8192) {                  // layer 2: n < 64, k < 128
        int n = t >> 7, k = t & 127;
        int in = k * 64 + n;
        WT2z[t] = f2bf(Ws2[in] + Ws2[8192 + in]);
        WT2a[t] = f2bf(Wn2[in]);
        WT2b[t] = f2bf(Wn2[8192 + in]);
    }
    if (t < 128) bc1[t] = b1[t] + b1[128 + t];
    if (t < 64)  bc2[t] = b2[t] + b2[64 + t];
}

// ---- agg L1: half-wave per edge, fp8 128B rows, 16 edges/iter -----------
// 32 lanes x 4B = one row per half -> 2 edges per gather instruction.
__global__ __launch_bounds__(256) void
agg1_kernel(const unsigned char* __restrict__ xb8,
            const int* __restrict__ csr, const int* __restrict__ off,
            unsigned short* __restrict__ m0, unsigned short* __restrict__ m1,
            int N, int twoE)
{
    int w = blockIdx.x * 4 + (threadIdx.x >> 6);
    int lane = threadIdx.x & 63;
    if (w >= N) return;
    const int half = lane >> 5;
    const int col = (lane & 31) * 4;          // 4 fp8 cols per lane
    const unsigned char* xc = xb8 + col;

    float a0 = 0.f, a1 = 0.f, a2 = 0.f, a3 = 0.f;   // rel0
    float b0 = 0.f, b1 = 0.f, b2 = 0.f, b3 = 0.f;   // rel1

    // ---- relation 0 ----
    int o0 = RFL(off[w]);
    int o1 = RFL(off[w + 1]);
    int d0 = o1 - o0;
    int j = o0;
    for (; j + 15 < o1; j += 16) {
        int r0 = csr[j + 0 + half];
        int r1 = csr[j + 2 + half];
        int r2 = csr[j + 4 + half];
        int r3 = csr[j + 6 + half];
        int r4 = csr[j + 8 + half];
        int r5 = csr[j + 10 + half];
        int r6 = csr[j + 12 + half];
        int r7 = csr[j + 14 + half];
        unsigned v0 = *(const unsigned*)(xc + (size_t)r0 * 128);
        unsigned v1 = *(const unsigned*)(xc + (size_t)r1 * 128);
        unsigned v2 = *(const unsigned*)(xc + (size_t)r2 * 128);
        unsigned v3 = *(const unsigned*)(xc + (size_t)r3 * 128);
        unsigned v4 = *(const unsigned*)(xc + (size_t)r4 * 128);
        unsigned v5 = *(const unsigned*)(xc + (size_t)r5 * 128);
        unsigned v6 = *(const unsigned*)(xc + (size_t)r6 * 128);
        unsigned v7 = *(const unsigned*)(xc + (size_t)r7 * 128);
        floatx2 l0 = fp8lo(v0), h0 = fp8hi(v0);
        floatx2 l1 = fp8lo(v1), h1 = fp8hi(v1);
        floatx2 l2 = fp8lo(v2), h2 = fp8hi(v2);
        floatx2 l3 = fp8lo(v3), h3 = fp8hi(v3);
        floatx2 l4 = fp8lo(v4), h4 = fp8hi(v4);
        floatx2 l5 = fp8lo(v5), h5 = fp8hi(v5);
        floatx2 l6 = fp8lo(v6), h6 = fp8hi(v6);
        floatx2 l7 = fp8lo(v7), h7 = fp8hi(v7);
        a0 += ((l0.x + l1.x) + (l2.x + l3.x)) + ((l4.x + l5.x) + (l6.x + l7.x));
        a1 += ((l0.y + l1.y) + (l2.y + l3.y)) + ((l4.y + l5.y) + (l6.y + l7.y));
        a2 += ((h0.x + h1.x) + (h2.x + h3.x)) + ((h4.x + h5.x) + (h6.x + h7.x));
        a3 += ((h0.y + h1.y) + (h2.y + h3.y)) + ((h4.y + h5.y) + (h6.y + h7.y));
    }
    for (; j + 1 < o1; j += 2) {
        int r = csr[j + half];
        unsigned v = *(const unsigned*)(xc + (size_t)r * 128);
        floatx2 l = fp8lo(v), h = fp8hi(v);
        a0 += l.x; a1 += l.y; a2 += h.x; a3 += h.y;
    }
    if (j < o1 && half == 0) {
        int r = csr[j];
        unsigned v = *(const unsigned*)(xc + (size_t)r * 128);
        floatx2 l = fp8lo(v), h = fp8hi(v);
        a0 += l.x; a1 += l.y; a2 += h.x; a3 += h.y;
    }

    // ---- relation 1 ----
    int p = N + w;
    o0 = RFL(off[p]);
    o1 = (p + 1 < 2 * N) ? RFL(off[p + 1]) : twoE;
    int d1 = o1 - o0;
    j = o0;
    for (; j + 15 < o1; j += 16) {
        int r0 = csr[j + 0 + half];
        int r1 = csr[j + 2 + half];
        int r2 = csr[j + 4 + half];
        int r3 = csr[j + 6 + half];
        int r4 = csr[j + 8 + half];
        int r5 = csr[j + 10 + half];
        int r6 = csr[j + 12 + half];
        int r7 = csr[j + 14 + half];
        unsigned v0 = *(const unsigned*)(xc + (size_t)r0 * 128);
        unsigned v1 = *(const unsigned*)(xc + (size_t)r1 * 128);
        unsigned v2 = *(const unsigned*)(xc + (size_t)r2 * 128);
        unsigned v3 = *(const unsigned*)(xc + (size_t)r3 * 128);
        unsigned v4 = *(const unsigned*)(xc + (size_t)r4 * 128);
        unsigned v5 = *(const unsigned*)(xc + (size_t)r5 * 128);
        unsigned v6 = *(const unsigned*)(xc + (size_t)r6 * 128);
        unsigned v7 = *(const unsigned*)(xc + (size_t)r7 * 128);
        floatx2 l0 = fp8lo(v0), h0 = fp8hi(v0);
        floatx2 l1 = fp8lo(v1), h1 = fp8hi(v1);
        floatx2 l2 = fp8lo(v2), h2 = fp8hi(v2);
        floatx2 l3 = fp8lo(v3), h3 = fp8hi(v3);
        floatx2 l4 = fp8lo(v4), h4 = fp8hi(v4);
        floatx2 l5 = fp8lo(v5), h5 = fp8hi(v5);
        floatx2 l6 = fp8lo(v6), h6 = fp8hi(v6);
        floatx2 l7 = fp8lo(v7), h7 = fp8hi(v7);
        b0 += ((l0.x + l1.x) + (l2.x + l3.x)) + ((l4.x + l5.x) + (l6.x + l7.x));
        b1 += ((l0.y + l1.y) + (l2.y + l3.y)) + ((l4.y + l5.y) + (l6.y + l7.y));
        b2 += ((h0.x + h1.x) + (h2.x + h3.x)) + ((h4.x + h5.x) + (h6.x + h7.x));
        b3 += ((h0.y + h1.y) + (h2.y + h3.y)) + ((h4.y + h5.y) + (h6.y + h7.y));
    }
    for (; j + 1 < o1; j += 2) {
        int r = csr[j + half];
        unsigned v = *(const unsigned*)(xc + (size_t)r * 128);
        floatx2 l = fp8lo(v), h = fp8hi(v);
        b0 += l.x; b1 += l.y; b2 += h.x; b3 += h.y;
    }
    if (j < o1 && half == 0) {
        int r = csr[j];
        unsigned v = *(const unsigned*)(xc + (size_t)r * 128);
        floatx2 l = fp8lo(v), h = fp8hi(v);
        b0 += l.x; b1 += l.y; b2 += h.x; b3 += h.y;
    }

    // cross-half reduce + write (lanes 0..31 write 8B each = 256B row)
    a0 += __shfl_xor(a0, 32); a1 += __shfl_xor(a1, 32);
    a2 += __shfl_xor(a2, 32); a3 += __shfl_xor(a3, 32);
    b0 += __shfl_xor(b0, 32); b1 += __shfl_xor(b1, 32);
    b2 += __shfl_xor(b2, 32); b3 += __shfl_xor(b3, 32);
    if (half == 0) {
        float inv0 = 1.0f / fmaxf((float)d0, 1.0f);
        float inv1 = 1.0f / fmaxf((float)d1, 1.0f);
        uint2 u0, u1;
        u0.x = pack2(a0 * inv0, a1 * inv0);
        u0.y = pack2(a2 * inv0, a3 * inv0);
        u1.x = pack2(b0 * inv1, b1 * inv1);
        u1.y = pack2(b2 * inv1, b3 * inv1);
        *(uint2*)(m0 + (size_t)w * 128 + col) = u0;
        *(uint2*)(m1 + (size_t)w * 128 + col) = u1;
    }
}

// ---- fused layer-1 GEMM: h1 = relu(x@WTz + m0@WTa + m1@WTb + bias) ------
__global__ __launch_bounds__(256) void
gemm1_fused_kernel(const unsigned short* __restrict__ xb,
                   const unsigned short* __restrict__ m0,
                   const unsigned short* __restrict__ m1,
                   const unsigned short* __restrict__ WTz,
                   const unsigned short* __restrict__ WTa,
                   const unsigned short* __restrict__ WTb,
                   const float* __restrict__ bias,
                   unsigned short* __restrict__ h1b, int N)
{
    __shared__ float eb[64][129];

    const int tid = threadIdx.x;
    const int wave = tid >> 6;
    const int lane = tid & 63;
    const int m = lane & 15;
    const int quad = lane >> 4;

    floatx4 acc[8];
    const floatx4 z4 = {0.f, 0.f, 0.f, 0.f};
#pragma unroll
    for (int t = 0; t < 8; ++t) acc[t] = z4;

    int arow = blockIdx.x * 64 + wave * 16 + m;
    if (arow >= N) arow = N - 1;
    const size_t abase = (size_t)arow * 128 + quad * 8;

#pragma unroll
    for (int s = 0; s < 4; ++s) {
        bf16x8 ax = *(const bf16x8*)(xb + abase + s * 32);
        bf16x8 a0 = *(const bf16x8*)(m0 + abase + s * 32);
        bf16x8 a1 = *(const bf16x8*)(m1 + abase + s * 32);
#pragma unroll
        for (int t = 0; t < 8; ++t) {
            const size_t bo = (size_t)(t * 16 + m) * 128 + s * 32 + quad * 8;
            acc[t] = __builtin_amdgcn_mfma_f32_16x16x32_bf16(
                ax, *(const bf16x8*)(WTz + bo), acc[t], 0, 0, 0);
            acc[t] = __builtin_amdgcn_mfma_f32_16x16x32_bf16(
                a0, *(const bf16x8*)(WTa + bo), acc[t], 0, 0, 0);
            acc[t] = __builtin_amdgcn_mfma_f32_16x16x32_bf16(
                a1, *(const bf16x8*)(WTb + bo), acc[t], 0, 0, 0);
        }
    }

    // C/D: col = lane&15, row = quad*4 + reg -> LDS transpose epilogue
#pragma unroll
    for (int t = 0; t < 8; ++t)
#pragma unroll
        for (int i = 0; i < 4; ++i)
            eb[wave * 16 + quad * 4 + i][t * 16 + m] = acc[t][i];
    __syncthreads();

#pragma unroll
    for (int j = 0; j < 4; ++j) {
        int lr = wave * 16 + j * 4 + quad;
        int grow = blockIdx.x * 64 + lr;
        if (grow < N) {
#pragma unroll
            for (int i = 0; i < 2; ++i) {
                int c0 = (i * 16 + m) * 4;
                float v0 = fmaxf(eb[lr][c0 + 0] + bias[c0 + 0], 0.0f);
                float v1 = fmaxf(eb[lr][c0 + 1] + bias[c0 + 1], 0.0f);
                float v2 = fmaxf(eb[lr][c0 + 2] + bias[c0 + 2], 0.0f);
                float v3 = fmaxf(eb[lr][c0 + 3] + bias[c0 + 3], 0.0f);
                ushort4 u;
                u.x = f2bf(v0); u.y = f2bf(v1); u.z = f2bf(v2); u.w = f2bf(v3);
                *(ushort4*)(h1b + (size_t)grow * 128 + c0) = u;
            }
        }
    }
}

// ---- fused layer-2 GEMM: h1b -> z2 (f32+bias), t0/t1 (fp8) --------------
__global__ __launch_bounds__(256) void
gemm2_fused_kernel(const unsigned short* __restrict__ Ab,
                   const unsigned short* __restrict__ WTz,
                   const unsigned short* __restrict__ WTa,
                   const unsigned short* __restrict__ WTb,
                   const float* __restrict__ bias,
                   float* __restrict__ zf,
                   unsigned char* __restrict__ t08, unsigned char* __restrict__ t18,
                   int N)
{
    __shared__ float eb[64][65];

    const int tid = threadIdx.x;
    const int wave = tid >> 6;
    const int lane = tid & 63;
    const int m = lane & 15;
    const int quad = lane >> 4;

    floatx4 accz[4], acca[4], accb[4];
    const floatx4 z4 = {0.f, 0.f, 0.f, 0.f};
#pragma unroll
    for (int t = 0; t < 4; ++t) { accz[t] = z4; acca[t] = z4; accb[t] = z4; }

    int arow = blockIdx.x * 64 + wave * 16 + m;
    if (arow >= N) arow = N - 1;
    const unsigned short* aptr = Ab + (size_t)arow * 128 + quad * 8;

#pragma unroll
    for (int s = 0; s < 4; ++s) {
        bf16x8 a = *(const bf16x8*)(aptr + s * 32);
#pragma unroll
        for (int t = 0; t < 4; ++t) {
            const size_t bo = (size_t)(t * 16 + m) * 128 + s * 32 + quad * 8;
            accz[t] = __builtin_amdgcn_mfma_f32_16x16x32_bf16(
                a, *(const bf16x8*)(WTz + bo), accz[t], 0, 0, 0);
            acca[t] = __builtin_amdgcn_mfma_f32_16x16x32_bf16(
                a, *(const bf16x8*)(WTa + bo), acca[t], 0, 0, 0);
            accb[t] = __builtin_amdgcn_mfma_f32_16x16x32_bf16(
                a, *(const bf16x8*)(WTb + bo), accb[t], 0, 0, 0);
        }
    }

    // ---- round z: f32 + bias ----
#pragma unroll
    for (int t = 0; t < 4; ++t)
#pragma unroll
        for (int i = 0; i < 4; ++i)
            eb[wave * 16 + quad * 4 + i][t * 16 + m] = accz[t][i];
    __syncthreads();
#pragma unroll
    for (int j = 0; j < 4; ++j) {
        int lr = wave * 16 + j * 4 + quad;
        int gr = blockIdx.x * 64 + lr;
        if (gr < N) {
            int c0 = m * 4;
            float4 o;
            o.x = eb[lr][c0 + 0] + bias[c0 + 0];
            o.y = eb[lr][c0 + 1] + bias[c0 + 1];
            o.z = eb[lr][c0 + 2] + bias[c0 + 2];
            o.w = eb[lr][c0 + 3] + bias[c0 + 3];
            *(float4*)(zf + (size_t)gr * 64 + c0) = o;
        }
    }
    __syncthreads();

    // ---- round a: fp8 ----
#pragma unroll
    for (int t = 0; t < 4; ++t)
#pragma unroll
        for (int i = 0; i < 4; ++i)
            eb[wave * 16 + quad * 4 + i][t * 16 + m] = acca[t][i];
    __syncthreads();
#pragma unroll
    for (int j = 0; j < 4; ++j) {
        int lr = wave * 16 + j * 4 + quad;
        int gr = blockIdx.x * 64 + lr;
        if (gr < N) {
            int c0 = m * 4;
            *(unsigned*)(t08 + (size_t)gr * 64 + c0) = f32x4_fp8x4(
                eb[lr][c0 + 0], eb[lr][c0 + 1], eb[lr][c0 + 2], eb[lr][c0 + 3]);
        }
    }
    __syncthreads();

    // ---- round b: fp8 ----
#pragma unroll
    for (int t = 0; t < 4; ++t)
#pragma unroll
        for (int i = 0; i < 4; ++i)
            eb[wave * 16 + quad * 4 + i][t * 16 + m] = accb[t][i];
    __syncthreads();
#pragma unroll
    for (int j = 0; j < 4; ++j) {
        int lr = wave * 16 + j * 4 + quad;
        int gr = blockIdx.x * 64 + lr;
        if (gr < N) {
            int c0 = m * 4;
            *(unsigned*)(t18 + (size_t)gr * 64 + c0) = f32x4_fp8x4(
                eb[lr][c0 + 0], eb[lr][c0 + 1], eb[lr][c0 + 2], eb[lr][c0 + 3]);
        }
    }
}

// ---- agg L2: quarter-wave per edge, fp8 64B rows, 16 edges/iter ---------
// 16 lanes x 4B = one row per quarter -> 4 edges per gather instruction.
__global__ __launch_bounds__(256) void
agg2_kernel(const unsigned char* __restrict__ t08,
            const unsigned char* __restrict__ t18,
            const float* __restrict__ z2,
            const int* __restrict__ csr, const int* __restrict__ off,
            unsigned short* __restrict__ h2b, int N, int twoE)
{
    int w = blockIdx.x * 4 + (threadIdx.x >> 6);
    int lane = threadIdx.x & 63;
    if (w >= N) return;
    const int q = lane >> 4;                 // edge slot 0..3
    const int col = (lane & 15) * 4;         // 4 fp8 cols per lane
    const unsigned char* t0c = t08 + col;
    const unsigned char* t1c = t18 + col;

    float a0 = 0.f, a1 = 0.f, a2 = 0.f, a3 = 0.f;   // rel0
    float b0 = 0.f, b1 = 0.f, b2 = 0.f, b3 = 0.f;   // rel1

    // ---- relation 0 ----
    int o0 = RFL(off[w]);
    int o1 = RFL(off[w + 1]);
    int d0 = o1 - o0;
    int j = o0;
    for (; j + 15 < o1; j += 16) {
        int r0 = csr[j + q];
        int r1 = csr[j + 4 + q];
        int r2 = csr[j + 8 + q];
        int r3 = csr[j + 12 + q];
        unsigned v0 = *(const unsigned*)(t0c + (size_t)r0 * 64);
        unsigned v1 = *(const unsigned*)(t0c + (size_t)r1 * 64);
        unsigned v2 = *(const unsigned*)(t0c + (size_t)r2 * 64);
        unsigned v3 = *(const unsigned*)(t0c + (size_t)r3 * 64);
        floatx2 l0 = fp8lo(v0), h0 = fp8hi(v0);
        floatx2 l1 = fp8lo(v1), h1 = fp8hi(v1);
        floatx2 l2 = fp8lo(v2), h2 = fp8hi(v2);
        floatx2 l3 = fp8lo(v3), h3 = fp8hi(v3);
        a0 += (l0.x + l1.x) + (l2.x + l3.x);
        a1 += (l0.y + l1.y) + (l2.y + l3.y);
        a2 += (h0.x + h1.x) + (h2.x + h3.x);
        a3 += (h0.y + h1.y) + (h2.y + h3.y);
    }
    for (; j + 3 < o1; j += 4) {
        int r = csr[j + q];
        unsigned v = *(const unsigned*)(t0c + (size_t)r * 64);
        floatx2 l = fp8lo(v), h = fp8hi(v);
        a0 += l.x; a1 += l.y; a2 += h.x; a3 += h.y;
    }
    if (j < o1 && q < o1 - j) {
        int r = csr[j + q];
        unsigned v = *(const unsigned*)(t0c + (size_t)r * 64);
        floatx2 l = fp8lo(v), h = fp8hi(v);
        a0 += l.x; a1 += l.y; a2 += h.x; a3 += h.y;
    }

    // ---- relation 1 ----
    int p = N + w;
    o0 = RFL(off[p]);
    o1 = (p + 1 < 2 * N) ? RFL(off[p + 1]) : twoE;
    int d1 = o1 - o0;
    j = o0;
    for (; j + 15 < o1; j += 16) {
        int r0 = csr[j + q];
        int r1 = csr[j + 4 + q];
        int r2 = csr[j + 8 + q];
        int r3 = csr[j + 12 + q];
        unsigned v0 = *(const unsigned*)(t1c + (size_t)r0 * 64);
        unsigned v1 = *(const unsigned*)(t1c + (size_t)r1 * 64);
        unsigned v2 = *(const unsigned*)(t1c + (size_t)r2 * 64);
        unsigned v3 = *(const unsigned*)(t1c + (size_t)r3 * 64);
        floatx2 l0 = fp8lo(v0), h0 = fp8hi(v0);
        floatx2 l1 = fp8lo(v1), h1 = fp8hi(v1);
        floatx2 l2 = fp8lo(v2), h2 = fp8hi(v2);
        floatx2 l3 = fp8lo(v3), h3 = fp8hi(v3);
        b0 += (l0.x + l1.x) + (l2.x + l3.x);
        b1 += (l0.y + l1.y) + (l2.y + l3.y);
        b2 += (h0.x + h1.x) + (h2.x + h3.x);
        b3 += (h0.y + h1.y) + (h2.y + h3.y);
    }
    for (; j + 3 < o1; j += 4) {
        int r = csr[j + q];
        unsigned v = *(const unsigned*)(t1c + (size_t)r * 64);
        floatx2 l = fp8lo(v), h = fp8hi(v);
        b0 += l.x; b1 += l.y; b2 += h.x; b3 += h.y;
    }
    if (j < o1 && q < o1 - j) {
        int r = csr[j + q];
        unsigned v = *(const unsigned*)(t1c + (size_t)r * 64);
        floatx2 l = fp8lo(v), h = fp8hi(v);
        b0 += l.x; b1 += l.y; b2 += h.x; b3 += h.y;
    }

    // cross-quarter reduce + write (lanes 0..15 write 8B each = 128B row)
    a0 += __shfl_xor(a0, 16); a1 += __shfl_xor(a1, 16);
    a2 += __shfl_xor(a2, 16); a3 += __shfl_xor(a3, 16);
    b0 += __shfl_xor(b0, 16); b1 += __shfl_xor(b1, 16);
    b2 += __shfl_xor(b2, 16); b3 += __shfl_xor(b3, 16);
    a0 += __shfl_xor(a0, 32); a1 += __shfl_xor(a1, 32);
    a2 += __shfl_xor(a2, 32); a3 += __shfl_xor(a3, 32);
    b0 += __shfl_xor(b0, 32); b1 += __shfl_xor(b1, 32);
    b2 += __shfl_xor(b2, 32); b3 += __shfl_xor(b3, 32);
    if (q == 0) {
        float inv0 = 1.0f / fmaxf((float)d0, 1.0f);
        float inv1 = 1.0f / fmaxf((float)d1, 1.0f);
        float4 z = *(const float4*)(z2 + (size_t)w * 64 + col);
        float h0v = z.x + a0 * inv0 + b0 * inv1;
        float h1v = z.y + a1 * inv0 + b1 * inv1;
        float h2v = z.z + a2 * inv0 + b2 * inv1;
        float h3v = z.w + a3 * inv0 + b3 * inv1;
        uint2 u;
        u.x = pack2(h0v, h1v);
        u.y = pack2(h2v, h3v);
        *(uint2*)(h2b + (size_t)w * 64 + col) = u;
    }
}

// ---- score (merged pos+neg): 8 lanes/edge, 128B rows, shfl reduce --------
__global__ __launch_bounds__(256) void
score_kernel(const unsigned short* __restrict__ h, // [N,64] bf16
             const int* __restrict__ edges, const int* __restrict__ neg,
             float* __restrict__ out, int E, int En)
{
    int t = blockIdx.x * blockDim.x + threadIdx.x;
    int e = t >> 3;
    int c = t & 7;
    if (e >= E + En) return;
    int sI, dI, oI;
    if (e < E) { sI = edges[e]; dI = edges[E + e]; oI = e; }
    else { int en = e - E; sI = neg[en]; dI = neg[En + en]; oI = E + en; }
    uint4 va = *(const uint4*)(h + (size_t)sI * 64 + c * 8);
    uint4 vb = *(const uint4*)(h + (size_t)dI * 64 + c * 8);
    float s = 0.0f;
    s = fmaf(bflo(va.x), bflo(vb.x), s);
    s = fmaf(bfhi(va.x), bfhi(vb.x), s);
    s = fmaf(bflo(va.y), bflo(vb.y), s);
    s = fmaf(bfhi(va.y), bfhi(vb.y), s);
    s = fmaf(bflo(va.z), bflo(vb.z), s);
    s = fmaf(bfhi(va.z), bfhi(vb.z), s);
    s = fmaf(bflo(va.w), bflo(vb.w), s);
    s = fmaf(bfhi(va.w), bfhi(vb.w), s);
    s += __shfl_xor(s, 1);
    s += __shfl_xor(s, 2);
    s += __shfl_xor(s, 4);
    if (c == 0) out[oI] = s;
}

extern "C" void kernel_launch(void* const* d_in, const int* in_sizes, int n_in,
                              void* d_out, int out_size, void* d_ws, size_t ws_size,
                              hipStream_t stream)
{
    const float* x     = (const float*)d_in[0];
    const int*   edges = (const int*)d_in[1];
    const int*   neg   = (const int*)d_in[2];
    const float* Wn1   = (const float*)d_in[3];
    const float* Ws1   = (const float*)d_in[4];
    const float* b1    = (const float*)d_in[5];
    const float* Wn2   = (const float*)d_in[6];
    const float* Ws2   = (const float*)d_in[7];
    const float* b2    = (const float*)d_in[8];
    float* out = (float*)d_out;

    const int Fin = 128, R = 2;
    const int N  = in_sizes[0] / Fin;        // 50000
    const int E  = in_sizes[1] / (R * 2);    // 800000
    const int En = in_sizes[2] / 2;          // 800000
    const int twoE = 2 * E;
    const int NBK = (N + BW - 1) / BW;       // 391
    const int rbT = 2 * NBK;

    // ---- workspace layout (aliases noted) ----
    const size_t nb128 = (size_t)N * 128 * sizeof(unsigned short);   // 12.8MB
    char* p = (char*)d_ws;

    // region0: staging [2E] (CSR build) -> xb8 [N,128] fp8 (cvt..agg1)
    //          -> z2 [N,64] f32 (gemm2..agg2). Lifetimes strictly ordered.
    uint2* staging       = (uint2*)p;
    unsigned char* xb8   = (unsigned char*)p;
    float* z2            = (float*)p;
    {
        size_t r0 = (size_t)twoE * sizeof(uint2);          // 12.8MB
        size_t r1 = (size_t)N * 64 * sizeof(float);        // 12.8MB
        size_t r2 = (size_t)N * 128;                       // 6.4MB
        size_t rm = r0 > r1 ? r0 : r1;
        if (r2 > rm) rm = r2;
        p += rm;
    }
    unsigned short* m0  = (unsigned short*)p; p += nb128;  // [N,128] mean rel0 (t08/t18 reuse)
    unsigned short* m1  = (unsigned short*)p; p += nb128;  // [N,128] mean rel1 (h2b reuse)
    unsigned short* xb  = (unsigned short*)p; p += nb128;  // [N,128] bf16 x
    unsigned short* h1b = (unsigned short*)p; p += nb128;  // [N,128] bf16 h1
    unsigned short* WT1z = (unsigned short*)p; p += 16384 * 2;
    unsigned short* WT1a = (unsigned short*)p; p += 16384 * 2;
    unsigned short* WT1b = (unsigned short*)p; p += 16384 * 2;
    unsigned short* WT2z = (unsigned short*)p; p += 8192 * 2;
    unsigned short* WT2a = (unsigned short*)p; p += 8192 * 2;
    unsigned short* WT2b = (unsigned short*)p; p += 8192 * 2;
    float* bc1 = (float*)p; p += 128 * sizeof(float);
    float* bc2 = (float*)p; p += 64 * sizeof(float);
    int* bcnt = (int*)p; p += (size_t)2 * NBK_MAX * sizeof(int);
    int* gcur = (int*)p; p += (size_t)2 * NBK_MAX * sizeof(int);
    int* bko  = (int*)p; p += ((size_t)2 * NBK_MAX + 1) * sizeof(int);
    int* off  = (int*)p; p += (size_t)2 * N * sizeof(int);
    int* csr  = (int*)p;

    unsigned char*  t08 = (unsigned char*)m0;        // [N,64] fp8
    unsigned char*  t18 = t08 + (size_t)N * 64;      // [N,64] fp8
    unsigned short* h2b = m1;                        // [N,64] bf16

    const int BS = 256;
    const int edge_blocks = (twoE + EPB - 1) / EPB;
    const int gx = (N + 63) / 64;

    // ---- CSR build (radix by dst bucket) ----
    hipMemsetAsync(bcnt, 0, (size_t)4 * NBK_MAX * sizeof(int), stream);
    bucket_count_kernel<<<edge_blocks, BS, 0, stream>>>(edges, bcnt, NBK, E);
    bucket_scan_kernel<<<1, 1024, 0, stream>>>(bcnt, bko, rbT, twoE);
    partition_kernel<<<edge_blocks, BS, 0, stream>>>(edges, bko, gcur, staging, NBK, E);
    bucket_csr_kernel<<<rbT, BS, 0, stream>>>(staging, bko, csr, off, NBK, N);

    // ---- prep (cvt AFTER bucket_csr: xb8 aliases dead staging) ----
    cvt_kernel<<<(N * 32 + BS - 1) / BS, BS, 0, stream>>>(x, xb, xb8, N * 32);
    prep_kernel<<<(16384 + BS - 1) / BS, BS, 0, stream>>>(
        Ws1, Wn1, b1, Ws2, Wn2, b2,
        WT1z, WT1a, WT1b, bc1, WT2z, WT2a, WT2b, bc2);

    // ---- Layer 1: fp8 aggregate (half-wave), then fused 3-matmul GEMM ---
    agg1_kernel<<<(N + 3) / 4, BS, 0, stream>>>(xb8, csr, off, m0, m1, N, twoE);
    gemm1_fused_kernel<<<gx, BS, 0, stream>>>(xb, m0, m1, WT1z, WT1a, WT1b,
                                              bc1, h1b, N);

    // ---- Layer 2: fused transform (z2 f32, t0/t1 fp8), quarter-wave agg -
    gemm2_fused_kernel<<<gx, BS, 0, stream>>>(h1b, WT2z, WT2a, WT2b, bc2,
                                              z2, t08, t18, N);
    agg2_kernel<<<(N + 3) / 4, BS, 0, stream>>>(t08, t18, z2, csr, off, h2b, N, twoE);

    // ---- Scores (pos + neg in one launch) ----
    score_kernel<<<((E + En) * 8 + BS - 1) / BS, BS, 0, stream>>>(
        h2b, edges, neg, out, E, En);
}

// Round 8
// 363.800 us; speedup vs baseline: 1.3164x; 1.0263x over previous
//
#include <hip/hip_runtime.h>

// ---------------------------------------------------------------------------
// GraphSAGE 2-layer hetero (R=2) + edge dot scorer.  Round 16:
//  * agg1: REVERTED to round-14 full-wave form (64 lanes x ushort = one
//    128B fp8 row per instr, RFL'd csr -> SGPR-base s+v addressing).
//    Round-15's half-wave made row index per-lane -> per-lane 64b addr
//    math + VMEM index loads -> 50->58.8us regression. Third data point
//    confirming: full-wave + scalar base is right for 128B rows.
//  * agg2: KEPT round-15 quarter-wave (16 lanes x 4B = 64B fp8 row, 4
//    edges/instr) - it dropped out of the top-5 (was 54.4us).
//  * Everything else verbatim round 15 (CSR radix build, fused GEMMs,
//    fp8 t0/t1 epilogue, bf16 h2b + score, workspace aliasing).
// ---------------------------------------------------------------------------

#define BW 128            // nodes per radix bucket (pow2)
#define NBK_MAX 1024
#define EPB 8192          // edges per block in radix passes

typedef __attribute__((ext_vector_type(8))) short bf16x8;
typedef __attribute__((ext_vector_type(4))) float floatx4;
typedef __attribute__((ext_vector_type(2))) float floatx2;

__device__ __forceinline__ unsigned short f2bf(float f) {
    unsigned u = __float_as_uint(f);
    unsigned r = u + 0x7FFFu + ((u >> 16) & 1u);
    return (unsigned short)(r >> 16);
}
__device__ __forceinline__ unsigned pack2(float a, float b) {
    return (unsigned)f2bf(a) | ((unsigned)f2bf(b) << 16);
}
__device__ __forceinline__ float bflo(unsigned v) { return __uint_as_float(v << 16); }
__device__ __forceinline__ float bfhi(unsigned v) { return __uint_as_float(v & 0xFFFF0000u); }
#define RFL(x) __builtin_amdgcn_readfirstlane(x)

// ---- fp8 e4m3 helpers (hw cvt when available, bit-math fallback) --------
#if defined(__has_builtin) && __has_builtin(__builtin_amdgcn_cvt_pk_f32_fp8)
__device__ __forceinline__ floatx2 fp8lo(unsigned v) {
    return __builtin_amdgcn_cvt_pk_f32_fp8((int)v, false);
}
__device__ __forceinline__ floatx2 fp8hi(unsigned v) {
    return __builtin_amdgcn_cvt_pk_f32_fp8((int)v, true);
}
#else
__device__ __forceinline__ float fp8_1(unsigned b) {
    return __uint_as_float(((b & 0x80u) << 24) | ((b & 0x7Fu) << 20)) * 0x1.0p+120f;
}
__device__ __forceinline__ floatx2 fp8lo(unsigned v) {
    floatx2 r; r.x = fp8_1(v & 0xFFu); r.y = fp8_1((v >> 8) & 0xFFu); return r;
}
__device__ __forceinline__ floatx2 fp8hi(unsigned v) {
    floatx2 r; r.x = fp8_1((v >> 16) & 0xFFu); r.y = fp8_1((v >> 24) & 0xFFu); return r;
}
#endif

#if defined(__has_builtin) && __has_builtin(__builtin_amdgcn_cvt_pk_fp8_f32)
__device__ __forceinline__ unsigned f32x4_fp8x4(float a, float b, float c, float d) {
    unsigned lo = __builtin_amdgcn_cvt_pk_fp8_f32(a, b, 0, false);
    return __builtin_amdgcn_cvt_pk_fp8_f32(c, d, lo, true);
}
#else
__device__ __forceinline__ unsigned f2fp8(float x) {
    float m = fminf(fabsf(x), 448.0f);
    unsigned u = __float_as_uint(m * 0x1.0p-120f);
    unsigned r = (u + 0x7FFFFu + ((u >> 20) & 1u)) >> 20;
    if (r > 0x7Eu) r = 0x7Eu;
    return r | ((__float_as_uint(x) >> 24) & 0x80u);
}
__device__ __forceinline__ unsigned f32x4_fp8x4(float a, float b, float c, float d) {
    return f2fp8(a) | (f2fp8(b) << 8) | (f2fp8(c) << 16) | (f2fp8(d) << 24);
}
#endif

// ---- radix pass A: per-(r,bucket) counts --------------------------------
__global__ __launch_bounds__(256) void
bucket_count_kernel(const int* __restrict__ edges, int* __restrict__ bcnt,
                    int NBK, int E)
{
    __shared__ int cnt[2 * NBK_MAX];
    const int rbT = 2 * NBK;
    const int t = threadIdx.x;
    for (int k = t; k < rbT; k += 256) cnt[k] = 0;
    __syncthreads();
    long long start = (long long)blockIdx.x * EPB;
    long long twoE = 2LL * E;
    for (int u = 0; u < EPB / 256; ++u) {
        long long idx = start + u * 256 + t;
        if (idx < twoE) {
            int r = idx >= E;
            int e = (int)(idx - (long long)r * E);
            int d = edges[(size_t)r * 2 * E + E + e];
            atomicAdd(&cnt[r * NBK + (d >> 7)], 1);
        }
    }
    __syncthreads();
    for (int k = t; k < rbT; k += 256)
        if (cnt[k]) atomicAdd(&bcnt[k], cnt[k]);
}

// ---- radix pass B: exclusive scan of bucket counts ----------------------
__global__ __launch_bounds__(1024) void
bucket_scan_kernel(const int* __restrict__ bcnt, int* __restrict__ bko,
                   int rbT, int twoE)
{
    __shared__ int sm[1024];
    int t = threadIdx.x;
    int v = (t < rbT) ? bcnt[t] : 0;
    sm[t] = v;
    __syncthreads();
    for (int s = 1; s < 1024; s <<= 1) {
        int u = (t >= s) ? sm[t - s] : 0;
        __syncthreads();
        sm[t] += u;
        __syncthreads();
    }
    if (t < rbT) bko[t] = sm[t] - v;
    if (t == 0) bko[rbT] = twoE;
}

// ---- radix pass C: partition into bucket-grouped (src,dst) pairs --------
__global__ __launch_bounds__(256) void
partition_kernel(const int* __restrict__ edges, const int* __restrict__ bko,
                 int* __restrict__ gcur, uint2* __restrict__ staging,
                 int NBK, int E)
{
    __shared__ int cnt[2 * NBK_MAX];
    __shared__ int base[2 * NBK_MAX];
    const int rbT = 2 * NBK;
    const int t = threadIdx.x;
    for (int k = t; k < rbT; k += 256) cnt[k] = 0;
    __syncthreads();
    long long start = (long long)blockIdx.x * EPB;
    long long twoE = 2LL * E;
    for (int u = 0; u < EPB / 256; ++u) {
        long long idx = start + u * 256 + t;
        if (idx < twoE) {
            int r = idx >= E;
            int e = (int)(idx - (long long)r * E);
            int d = edges[(size_t)r * 2 * E + E + e];
            atomicAdd(&cnt[r * NBK + (d >> 7)], 1);
        }
    }
    __syncthreads();
    for (int k = t; k < rbT; k += 256) {
        int c0 = cnt[k];
        if (c0) base[k] = bko[k] + atomicAdd(&gcur[k], c0);
        cnt[k] = 0;
    }
    __syncthreads();
    for (int u = 0; u < EPB / 256; ++u) {
        long long idx = start + u * 256 + t;
        if (idx < twoE) {
            int r = idx >= E;
            int e = (int)(idx - (long long)r * E);
            int s = edges[(size_t)r * 2 * E + e];
            int d = edges[(size_t)r * 2 * E + E + e];
            int rb = r * NBK + (d >> 7);
            int pos = atomicAdd(&cnt[rb], 1);
            staging[(size_t)base[rb] + pos] = make_uint2((unsigned)s, (unsigned)d);
        }
    }
}

// ---- radix pass D: per-bucket node hist/scan -> off[] and csr[] ----------
__global__ __launch_bounds__(256) void
bucket_csr_kernel(const uint2* __restrict__ staging, const int* __restrict__ bko,
                  int* __restrict__ csr, int* __restrict__ off,
                  int NBK, int N)
{
    __shared__ int hist[BW], excl[BW], cur[BW], sc[BW];
    const int rb = blockIdx.x;
    const int r = rb / NBK;
    const int b = rb % NBK;
    const int node0 = b * BW;
    const int nn = min(BW, N - node0);
    const int cbase = bko[rb];
    const int c = bko[rb + 1] - cbase;
    const int t = threadIdx.x;

    if (t < BW) { hist[t] = 0; cur[t] = 0; }
    __syncthreads();
    for (int k = t; k < c; k += 256)
        atomicAdd(&hist[(int)staging[(size_t)cbase + k].y - node0], 1);
    __syncthreads();
    if (t < BW) sc[t] = hist[t];
    __syncthreads();
    for (int s = 1; s < BW; s <<= 1) {
        int v = (t < BW && t >= s) ? sc[t - s] : 0;
        __syncthreads();
        if (t < BW) sc[t] += v;
        __syncthreads();
    }
    if (t < BW) excl[t] = sc[t] - hist[t];
    if (t < nn) off[(size_t)r * N + node0 + t] = cbase + excl[t];
    __syncthreads();
    for (int k = t; k < c; k += 256) {
        uint2 pr = staging[(size_t)cbase + k];
        int l = (int)pr.y - node0;
        int pos = atomicAdd(&cur[l], 1);
        csr[(size_t)cbase + excl[l] + pos] = (int)pr.x;
    }
}

// ---- f32 -> bf16 [N,128] + fp8 [N,128] ----------------------------------
__global__ void cvt_kernel(const float* __restrict__ in,
                           unsigned short* __restrict__ o,
                           unsigned char* __restrict__ o8, int n4)
{
    int t = blockIdx.x * blockDim.x + threadIdx.x;
    if (t >= n4) return;
    float4 v = ((const float4*)in)[t];
    ushort4 r;
    r.x = f2bf(v.x); r.y = f2bf(v.y); r.z = f2bf(v.z); r.w = f2bf(v.w);
    ((ushort4*)o)[t] = r;
    ((unsigned*)o8)[t] = f32x4_fp8x4(v.x, v.y, v.z, v.w);
}

// ---- weight prep: combined-Wself / Wn -> bf16 W^T rows, biases ----------
__global__ void prep_kernel(const float* __restrict__ Ws1, const float* __restrict__ Wn1,
                            const float* __restrict__ b1,
                            const float* __restrict__ Ws2, const float* __restrict__ Wn2,
                            const float* __restrict__ b2,
                            unsigned short* __restrict__ WT1z, unsigned short* __restrict__ WT1a,
                            unsigned short* __restrict__ WT1b, float* __restrict__ bc1,
                            unsigned short* __restrict__ WT2z, unsigned short* __restrict__ WT2a,
                            unsigned short* __restrict__ WT2b, float* __restrict__ bc2)
{
    int t = blockIdx.x * blockDim.x + threadIdx.x;
    if (t < 16384) {                 // layer 1: [n][k] <- [k][n], n,k < 128
        int n = t >> 7, k = t & 127;
        int in = k * 128 + n;
        WT1z[t] = f2bf(Ws1[in] + Ws1[16384 + in]);
        WT1a[t] = f2bf(Wn1[in]);
        WT1b[t] = f2bf(Wn1[16384 + in]);
    }
    if (t < 8192) {                  // layer 2: n < 64, k < 128
        int n = t >> 7, k = t & 127;
        int in = k * 64 + n;
        WT2z[t] = f2bf(Ws2[in] + Ws2[8192 + in]);
        WT2a[t] = f2bf(Wn2[in]);
        WT2b[t] = f2bf(Wn2[8192 + in]);
    }
    if (t < 128) bc1[t] = b1[t] + b1[128 + t];
    if (t < 64)  bc2[t] = b2[t] + b2[64 + t];
}

// ---- agg L1: wave per node, fp8 gathers (128B/row), RFL csr, unroll x8 --
// Full wave per row: 64 lanes x ushort (2 fp8) = one row per instruction;
// RFL'd indices -> SGPR row base, s+v addressing, minimal per-lane VALU.
__global__ __launch_bounds__(256) void
agg1_kernel(const unsigned char* __restrict__ xb8,
            const int* __restrict__ csr, const int* __restrict__ off,
            unsigned short* __restrict__ m0, unsigned short* __restrict__ m1,
            int N, int twoE)
{
    int w = blockIdx.x * 4 + (threadIdx.x >> 6);
    int lane = threadIdx.x & 63;
    if (w >= N) return;
    const int col = lane * 2;
    const unsigned char* xc = xb8 + col;

    float sx0 = 0.f, sy0 = 0.f, sx1 = 0.f, sy1 = 0.f;

    // ---- relation 0 ----
    int o0 = RFL(off[w]);
    int o1 = RFL(off[w + 1]);
    int d0 = o1 - o0;
    int j = o0;
    for (; j + 7 < o1; j += 8) {
        int s0 = RFL(csr[j]);     int s1 = RFL(csr[j + 1]);
        int s2 = RFL(csr[j + 2]); int s3 = RFL(csr[j + 3]);
        int s4 = RFL(csr[j + 4]); int s5 = RFL(csr[j + 5]);
        int s6 = RFL(csr[j + 6]); int s7 = RFL(csr[j + 7]);
        unsigned a0 = *(const unsigned short*)(xc + (size_t)s0 * 128);
        unsigned a1 = *(const unsigned short*)(xc + (size_t)s1 * 128);
        unsigned a2 = *(const unsigned short*)(xc + (size_t)s2 * 128);
        unsigned a3 = *(const unsigned short*)(xc + (size_t)s3 * 128);
        unsigned a4 = *(const unsigned short*)(xc + (size_t)s4 * 128);
        unsigned a5 = *(const unsigned short*)(xc + (size_t)s5 * 128);
        unsigned a6 = *(const unsigned short*)(xc + (size_t)s6 * 128);
        unsigned a7 = *(const unsigned short*)(xc + (size_t)s7 * 128);
        floatx2 v0 = fp8lo(a0); floatx2 v1 = fp8lo(a1);
        floatx2 v2 = fp8lo(a2); floatx2 v3 = fp8lo(a3);
        floatx2 v4 = fp8lo(a4); floatx2 v5 = fp8lo(a5);
        floatx2 v6 = fp8lo(a6); floatx2 v7 = fp8lo(a7);
        sx0 += ((v0.x + v1.x) + (v2.x + v3.x)) + ((v4.x + v5.x) + (v6.x + v7.x));
        sy0 += ((v0.y + v1.y) + (v2.y + v3.y)) + ((v4.y + v5.y) + (v6.y + v7.y));
    }
    for (; j < o1; ++j) {
        int s0 = RFL(csr[j]);
        floatx2 v = fp8lo(*(const unsigned short*)(xc + (size_t)s0 * 128));
        sx0 += v.x; sy0 += v.y;
    }

    // ---- relation 1 ----
    int p = N + w;
    o0 = RFL(off[p]);
    o1 = (p + 1 < 2 * N) ? RFL(off[p + 1]) : twoE;
    int d1 = o1 - o0;
    j = o0;
    for (; j + 7 < o1; j += 8) {
        int s0 = RFL(csr[j]);     int s1 = RFL(csr[j + 1]);
        int s2 = RFL(csr[j + 2]); int s3 = RFL(csr[j + 3]);
        int s4 = RFL(csr[j + 4]); int s5 = RFL(csr[j + 5]);
        int s6 = RFL(csr[j + 6]); int s7 = RFL(csr[j + 7]);
        unsigned a0 = *(const unsigned short*)(xc + (size_t)s0 * 128);
        unsigned a1 = *(const unsigned short*)(xc + (size_t)s1 * 128);
        unsigned a2 = *(const unsigned short*)(xc + (size_t)s2 * 128);
        unsigned a3 = *(const unsigned short*)(xc + (size_t)s3 * 128);
        unsigned a4 = *(const unsigned short*)(xc + (size_t)s4 * 128);
        unsigned a5 = *(const unsigned short*)(xc + (size_t)s5 * 128);
        unsigned a6 = *(const unsigned short*)(xc + (size_t)s6 * 128);
        unsigned a7 = *(const unsigned short*)(xc + (size_t)s7 * 128);
        floatx2 v0 = fp8lo(a0); floatx2 v1 = fp8lo(a1);
        floatx2 v2 = fp8lo(a2); floatx2 v3 = fp8lo(a3);
        floatx2 v4 = fp8lo(a4); floatx2 v5 = fp8lo(a5);
        floatx2 v6 = fp8lo(a6); floatx2 v7 = fp8lo(a7);
        sx1 += ((v0.x + v1.x) + (v2.x + v3.x)) + ((v4.x + v5.x) + (v6.x + v7.x));
        sy1 += ((v0.y + v1.y) + (v2.y + v3.y)) + ((v4.y + v5.y) + (v6.y + v7.y));
    }
    for (; j < o1; ++j) {
        int s0 = RFL(csr[j]);
        floatx2 v = fp8lo(*(const unsigned short*)(xc + (size_t)s0 * 128));
        sx1 += v.x; sy1 += v.y;
    }

    float inv0 = 1.0f / fmaxf((float)d0, 1.0f);
    float inv1 = 1.0f / fmaxf((float)d1, 1.0f);
    *(unsigned*)(m0 + (size_t)w * 128 + col) = pack2(sx0 * inv0, sy0 * inv0);
    *(unsigned*)(m1 + (size_t)w * 128 + col) = pack2(sx1 * inv1, sy1 * inv1);
}

// ---- fused layer-1 GEMM: h1 = relu(x@WTz + m0@WTa + m1@WTb + bias) ------
__global__ __launch_bounds__(256) void
gemm1_fused_kernel(const unsigned short* __restrict__ xb,
                   const unsigned short* __restrict__ m0,
                   const unsigned short* __restrict__ m1,
                   const unsigned short* __restrict__ WTz,
                   const unsigned short* __restrict__ WTa,
                   const unsigned short* __restrict__ WTb,
                   const float* __restrict__ bias,
                   unsigned short* __restrict__ h1b, int N)
{
    __shared__ float eb[64][129];

    const int tid = threadIdx.x;
    const int wave = tid >> 6;
    const int lane = tid & 63;
    const int m = lane & 15;
    const int quad = lane >> 4;

    floatx4 acc[8];
    const floatx4 z4 = {0.f, 0.f, 0.f, 0.f};
#pragma unroll
    for (int t = 0; t < 8; ++t) acc[t] = z4;

    int arow = blockIdx.x * 64 + wave * 16 + m;
    if (arow >= N) arow = N - 1;
    const size_t abase = (size_t)arow * 128 + quad * 8;

#pragma unroll
    for (int s = 0; s < 4; ++s) {
        bf16x8 ax = *(const bf16x8*)(xb + abase + s * 32);
        bf16x8 a0 = *(const bf16x8*)(m0 + abase + s * 32);
        bf16x8 a1 = *(const bf16x8*)(m1 + abase + s * 32);
#pragma unroll
        for (int t = 0; t < 8; ++t) {
            const size_t bo = (size_t)(t * 16 + m) * 128 + s * 32 + quad * 8;
            acc[t] = __builtin_amdgcn_mfma_f32_16x16x32_bf16(
                ax, *(const bf16x8*)(WTz + bo), acc[t], 0, 0, 0);
            acc[t] = __builtin_amdgcn_mfma_f32_16x16x32_bf16(
                a0, *(const bf16x8*)(WTa + bo), acc[t], 0, 0, 0);
            acc[t] = __builtin_amdgcn_mfma_f32_16x16x32_bf16(
                a1, *(const bf16x8*)(WTb + bo), acc[t], 0, 0, 0);
        }
    }

    // C/D: col = lane&15, row = quad*4 + reg -> LDS transpose epilogue
#pragma unroll
    for (int t = 0; t < 8; ++t)
#pragma unroll
        for (int i = 0; i < 4; ++i)
            eb[wave * 16 + quad * 4 + i][t * 16 + m] = acc[t][i];
    __syncthreads();

#pragma unroll
    for (int j = 0; j < 4; ++j) {
        int lr = wave * 16 + j * 4 + quad;
        int grow = blockIdx.x * 64 + lr;
        if (grow < N) {
#pragma unroll
            for (int i = 0; i < 2; ++i) {
                int c0 = (i * 16 + m) * 4;
                float v0 = fmaxf(eb[lr][c0 + 0] + bias[c0 + 0], 0.0f);
                float v1 = fmaxf(eb[lr][c0 + 1] + bias[c0 + 1], 0.0f);
                float v2 = fmaxf(eb[lr][c0 + 2] + bias[c0 + 2], 0.0f);
                float v3 = fmaxf(eb[lr][c0 + 3] + bias[c0 + 3], 0.0f);
                ushort4 u;
                u.x = f2bf(v0); u.y = f2bf(v1); u.z = f2bf(v2); u.w = f2bf(v3);
                *(ushort4*)(h1b + (size_t)grow * 128 + c0) = u;
            }
        }
    }
}

// ---- fused layer-2 GEMM: h1b -> z2 (f32+bias), t0/t1 (fp8) --------------
__global__ __launch_bounds__(256) void
gemm2_fused_kernel(const unsigned short* __restrict__ Ab,
                   const unsigned short* __restrict__ WTz,
                   const unsigned short* __restrict__ WTa,
                   const unsigned short* __restrict__ WTb,
                   const float* __restrict__ bias,
                   float* __restrict__ zf,
                   unsigned char* __restrict__ t08, unsigned char* __restrict__ t18,
                   int N)
{
    __shared__ float eb[64][65];

    const int tid = threadIdx.x;
    const int wave = tid >> 6;
    const int lane = tid & 63;
    const int m = lane & 15;
    const int quad = lane >> 4;

    floatx4 accz[4], acca[4], accb[4];
    const floatx4 z4 = {0.f, 0.f, 0.f, 0.f};
#pragma unroll
    for (int t = 0; t < 4; ++t) { accz[t] = z4; acca[t] = z4; accb[t] = z4; }

    int arow = blockIdx.x * 64 + wave * 16 + m;
    if (arow >= N) arow = N - 1;
    const unsigned short* aptr = Ab + (size_t)arow * 128 + quad * 8;

#pragma unroll
    for (int s = 0; s < 4; ++s) {
        bf16x8 a = *(const bf16x8*)(aptr + s * 32);
#pragma unroll
        for (int t = 0; t < 4; ++t) {
            const size_t bo = (size_t)(t * 16 + m) * 128 + s * 32 + quad * 8;
            accz[t] = __builtin_amdgcn_mfma_f32_16x16x32_bf16(
                a, *(const bf16x8*)(WTz + bo), accz[t], 0, 0, 0);
            acca[t] = __builtin_amdgcn_mfma_f32_16x16x32_bf16(
                a, *(const bf16x8*)(WTa + bo), acca[t], 0, 0, 0);
            accb[t] = __builtin_amdgcn_mfma_f32_16x16x32_bf16(
                a, *(const bf16x8*)(WTb + bo), accb[t], 0, 0, 0);
        }
    }

    // ---- round z: f32 + bias ----
#pragma unroll
    for (int t = 0; t < 4; ++t)
#pragma unroll
        for (int i = 0; i < 4; ++i)
            eb[wave * 16 + quad * 4 + i][t * 16 + m] = accz[t][i];
    __syncthreads();
#pragma unroll
    for (int j = 0; j < 4; ++j) {
        int lr = wave * 16 + j * 4 + quad;
        int gr = blockIdx.x * 64 + lr;
        if (gr < N) {
            int c0 = m * 4;
            float4 o;
            o.x = eb[lr][c0 + 0] + bias[c0 + 0];
            o.y = eb[lr][c0 + 1] + bias[c0 + 1];
            o.z = eb[lr][c0 + 2] + bias[c0 + 2];
            o.w = eb[lr][c0 + 3] + bias[c0 + 3];
            *(float4*)(zf + (size_t)gr * 64 + c0) = o;
        }
    }
    __syncthreads();

    // ---- round a: fp8 ----
#pragma unroll
    for (int t = 0; t < 4; ++t)
#pragma unroll
        for (int i = 0; i < 4; ++i)
            eb[wave * 16 + quad * 4 + i][t * 16 + m] = acca[t][i];
    __syncthreads();
#pragma unroll
    for (int j = 0; j < 4; ++j) {
        int lr = wave * 16 + j * 4 + quad;
        int gr = blockIdx.x * 64 + lr;
        if (gr < N) {
            int c0 = m * 4;
            *(unsigned*)(t08 + (size_t)gr * 64 + c0) = f32x4_fp8x4(
                eb[lr][c0 + 0], eb[lr][c0 + 1], eb[lr][c0 + 2], eb[lr][c0 + 3]);
        }
    }
    __syncthreads();

    // ---- round b: fp8 ----
#pragma unroll
    for (int t = 0; t < 4; ++t)
#pragma unroll
        for (int i = 0; i < 4; ++i)
            eb[wave * 16 + quad * 4 + i][t * 16 + m] = accb[t][i];
    __syncthreads();
#pragma unroll
    for (int j = 0; j < 4; ++j) {
        int lr = wave * 16 + j * 4 + quad;
        int gr = blockIdx.x * 64 + lr;
        if (gr < N) {
            int c0 = m * 4;
            *(unsigned*)(t18 + (size_t)gr * 64 + c0) = f32x4_fp8x4(
                eb[lr][c0 + 0], eb[lr][c0 + 1], eb[lr][c0 + 2], eb[lr][c0 + 3]);
        }
    }
}

// ---- agg L2: quarter-wave per edge, fp8 64B rows, 16 edges/iter ---------
__global__ __launch_bounds__(256) void
agg2_kernel(const unsigned char* __restrict__ t08,
            const unsigned char* __restrict__ t18,
            const float* __restrict__ z2,
            const int* __restrict__ csr, const int* __restrict__ off,
            unsigned short* __restrict__ h2b, int N, int twoE)
{
    int w = blockIdx.x * 4 + (threadIdx.x >> 6);
    int lane = threadIdx.x & 63;
    if (w >= N) return;
    const int q = lane >> 4;                 // edge slot 0..3
    const int col = (lane & 15) * 4;         // 4 fp8 cols per lane
    const unsigned char* t0c = t08 + col;
    const unsigned char* t1c = t18 + col;

    float a0 = 0.f, a1 = 0.f, a2 = 0.f, a3 = 0.f;   // rel0
    float b0 = 0.f, b1 = 0.f, b2 = 0.f, b3 = 0.f;   // rel1

    // ---- relation 0 ----
    int o0 = RFL(off[w]);
    int o1 = RFL(off[w + 1]);
    int d0 = o1 - o0;
    int j = o0;
    for (; j + 15 < o1; j += 16) {
        int r0 = csr[j + q];
        int r1 = csr[j + 4 + q];
        int r2 = csr[j + 8 + q];
        int r3 = csr[j + 12 + q];
        unsigned v0 = *(const unsigned*)(t0c + (size_t)r0 * 64);
        unsigned v1 = *(const unsigned*)(t0c + (size_t)r1 * 64);
        unsigned v2 = *(const unsigned*)(t0c + (size_t)r2 * 64);
        unsigned v3 = *(const unsigned*)(t0c + (size_t)r3 * 64);
        floatx2 l0 = fp8lo(v0), h0 = fp8hi(v0);
        floatx2 l1 = fp8lo(v1), h1 = fp8hi(v1);
        floatx2 l2 = fp8lo(v2), h2 = fp8hi(v2);
        floatx2 l3 = fp8lo(v3), h3 = fp8hi(v3);
        a0 += (l0.x + l1.x) + (l2.x + l3.x);
        a1 += (l0.y + l1.y) + (l2.y + l3.y);
        a2 += (h0.x + h1.x) + (h2.x + h3.x);
        a3 += (h0.y + h1.y) + (h2.y + h3.y);
    }
    for (; j + 3 < o1; j += 4) {
        int r = csr[j + q];
        unsigned v = *(const unsigned*)(t0c + (size_t)r * 64);
        floatx2 l = fp8lo(v), h = fp8hi(v);
        a0 += l.x; a1 += l.y; a2 += h.x; a3 += h.y;
    }
    if (j < o1 && q < o1 - j) {
        int r = csr[j + q];
        unsigned v = *(const unsigned*)(t0c + (size_t)r * 64);
        floatx2 l = fp8lo(v), h = fp8hi(v);
        a0 += l.x; a1 += l.y; a2 += h.x; a3 += h.y;
    }

    // ---- relation 1 ----
    int p = N + w;
    o0 = RFL(off[p]);
    o1 = (p + 1 < 2 * N) ? RFL(off[p + 1]) : twoE;
    int d1 = o1 - o0;
    j = o0;
    for (; j + 15 < o1; j += 16) {
        int r0 = csr[j + q];
        int r1 = csr[j + 4 + q];
        int r2 = csr[j + 8 + q];
        int r3 = csr[j + 12 + q];
        unsigned v0 = *(const unsigned*)(t1c + (size_t)r0 * 64);
        unsigned v1 = *(const unsigned*)(t1c + (size_t)r1 * 64);
        unsigned v2 = *(const unsigned*)(t1c + (size_t)r2 * 64);
        unsigned v3 = *(const unsigned*)(t1c + (size_t)r3 * 64);
        floatx2 l0 = fp8lo(v0), h0 = fp8hi(v0);
        floatx2 l1 = fp8lo(v1), h1 = fp8hi(v1);
        floatx2 l2 = fp8lo(v2), h2 = fp8hi(v2);
        floatx2 l3 = fp8lo(v3), h3 = fp8hi(v3);
        b0 += (l0.x + l1.x) + (l2.x + l3.x);
        b1 += (l0.y + l1.y) + (l2.y + l3.y);
        b2 += (h0.x + h1.x) + (h2.x + h3.x);
        b3 += (h0.y + h1.y) + (h2.y + h3.y);
    }
    for (; j + 3 < o1; j += 4) {
        int r = csr[j + q];
        unsigned v = *(const unsigned*)(t1c + (size_t)r * 64);
        floatx2 l = fp8lo(v), h = fp8hi(v);
        b0 += l.x; b1 += l.y; b2 += h.x; b3 += h.y;
    }
    if (j < o1 && q < o1 - j) {
        int r = csr[j + q];
        unsigned v = *(const unsigned*)(t1c + (size_t)r * 64);
        floatx2 l = fp8lo(v), h = fp8hi(v);
        b0 += l.x; b1 += l.y; b2 += h.x; b3 += h.y;
    }

    // cross-quarter reduce + write (lanes 0..15 write 8B each = 128B row)
    a0 += __shfl_xor(a0, 16); a1 += __shfl_xor(a1, 16);
    a2 += __shfl_xor(a2, 16); a3 += __shfl_xor(a3, 16);
    b0 += __shfl_xor(b0, 16); b1 += __shfl_xor(b1, 16);
    b2 += __shfl_xor(b2, 16); b3 += __shfl_xor(b3, 16);
    a0 += __shfl_xor(a0, 32); a1 += __shfl_xor(a1, 32);
    a2 += __shfl_xor(a2, 32); a3 += __shfl_xor(a3, 32);
    b0 += __shfl_xor(b0, 32); b1 += __shfl_xor(b1, 32);
    b2 += __shfl_xor(b2, 32); b3 += __shfl_xor(b3, 32);
    if (q == 0) {
        float inv0 = 1.0f / fmaxf((float)d0, 1.0f);
        float inv1 = 1.0f / fmaxf((float)d1, 1.0f);
        float4 z = *(const float4*)(z2 + (size_t)w * 64 + col);
        float h0v = z.x + a0 * inv0 + b0 * inv1;
        float h1v = z.y + a1 * inv0 + b1 * inv1;
        float h2v = z.z + a2 * inv0 + b2 * inv1;
        float h3v = z.w + a3 * inv0 + b3 * inv1;
        uint2 u;
        u.x = pack2(h0v, h1v);
        u.y = pack2(h2v, h3v);
        *(uint2*)(h2b + (size_t)w * 64 + col) = u;
    }
}

// ---- score (merged pos+neg): 8 lanes/edge, 128B rows, shfl reduce --------
__global__ __launch_bounds__(256) void
score_kernel(const unsigned short* __restrict__ h, // [N,64] bf16
             const int* __restrict__ edges, const int* __restrict__ neg,
             float* __restrict__ out, int E, int En)
{
    int t = blockIdx.x * blockDim.x + threadIdx.x;
    int e = t >> 3;
    int c = t & 7;
    if (e >= E + En) return;
    int sI, dI, oI;
    if (e < E) { sI = edges[e]; dI = edges[E + e]; oI = e; }
    else { int en = e - E; sI = neg[en]; dI = neg[En + en]; oI = E + en; }
    uint4 va = *(const uint4*)(h + (size_t)sI * 64 + c * 8);
    uint4 vb = *(const uint4*)(h + (size_t)dI * 64 + c * 8);
    float s = 0.0f;
    s = fmaf(bflo(va.x), bflo(vb.x), s);
    s = fmaf(bfhi(va.x), bfhi(vb.x), s);
    s = fmaf(bflo(va.y), bflo(vb.y), s);
    s = fmaf(bfhi(va.y), bfhi(vb.y), s);
    s = fmaf(bflo(va.z), bflo(vb.z), s);
    s = fmaf(bfhi(va.z), bfhi(vb.z), s);
    s = fmaf(bflo(va.w), bflo(vb.w), s);
    s = fmaf(bfhi(va.w), bfhi(vb.w), s);
    s += __shfl_xor(s, 1);
    s += __shfl_xor(s, 2);
    s += __shfl_xor(s, 4);
    if (c == 0) out[oI] = s;
}

extern "C" void kernel_launch(void* const* d_in, const int* in_sizes, int n_in,
                              void* d_out, int out_size, void* d_ws, size_t ws_size,
                              hipStream_t stream)
{
    const float* x     = (const float*)d_in[0];
    const int*   edges = (const int*)d_in[1];
    const int*   neg   = (const int*)d_in[2];
    const float* Wn1   = (const float*)d_in[3];
    const float* Ws1   = (const float*)d_in[4];
    const float* b1    = (const float*)d_in[5];
    const float* Wn2   = (const float*)d_in[6];
    const float* Ws2   = (const float*)d_in[7];
    const float* b2    = (const float*)d_in[8];
    float* out = (float*)d_out;

    const int Fin = 128, R = 2;
    const int N  = in_sizes[0] / Fin;        // 50000
    const int E  = in_sizes[1] / (R * 2);    // 800000
    const int En = in_sizes[2] / 2;          // 800000
    const int twoE = 2 * E;
    const int NBK = (N + BW - 1) / BW;       // 391
    const int rbT = 2 * NBK;

    // ---- workspace layout (aliases noted) ----
    const size_t nb128 = (size_t)N * 128 * sizeof(unsigned short);   // 12.8MB
    char* p = (char*)d_ws;

    // region0: staging [2E] (CSR build) -> xb8 [N,128] fp8 (cvt..agg1)
    //          -> z2 [N,64] f32 (gemm2..agg2). Lifetimes strictly ordered.
    uint2* staging       = (uint2*)p;
    unsigned char* xb8   = (unsigned char*)p;
    float* z2            = (float*)p;
    {
        size_t r0 = (size_t)twoE * sizeof(uint2);          // 12.8MB
        size_t r1 = (size_t)N * 64 * sizeof(float);        // 12.8MB
        size_t r2 = (size_t)N * 128;                       // 6.4MB
        size_t rm = r0 > r1 ? r0 : r1;
        if (r2 > rm) rm = r2;
        p += rm;
    }
    unsigned short* m0  = (unsigned short*)p; p += nb128;  // [N,128] mean rel0 (t08/t18 reuse)
    unsigned short* m1  = (unsigned short*)p; p += nb128;  // [N,128] mean rel1 (h2b reuse)
    unsigned short* xb  = (unsigned short*)p; p += nb128;  // [N,128] bf16 x
    unsigned short* h1b = (unsigned short*)p; p += nb128;  // [N,128] bf16 h1
    unsigned short* WT1z = (unsigned short*)p; p += 16384 * 2;
    unsigned short* WT1a = (unsigned short*)p; p += 16384 * 2;
    unsigned short* WT1b = (unsigned short*)p; p += 16384 * 2;
    unsigned short* WT2z = (unsigned short*)p; p += 8192 * 2;
    unsigned short* WT2a = (unsigned short*)p; p += 8192 * 2;
    unsigned short* WT2b = (unsigned short*)p; p += 8192 * 2;
    float* bc1 = (float*)p; p += 128 * sizeof(float);
    float* bc2 = (float*)p; p += 64 * sizeof(float);
    int* bcnt = (int*)p; p += (size_t)2 * NBK_MAX * sizeof(int);
    int* gcur = (int*)p; p += (size_t)2 * NBK_MAX * sizeof(int);
    int* bko  = (int*)p; p += ((size_t)2 * NBK_MAX + 1) * sizeof(int);
    int* off  = (int*)p; p += (size_t)2 * N * sizeof(int);
    int* csr  = (int*)p;

    unsigned char*  t08 = (unsigned char*)m0;        // [N,64] fp8
    unsigned char*  t18 = t08 + (size_t)N * 64;      // [N,64] fp8
    unsigned short* h2b = m1;                        // [N,64] bf16

    const int BS = 256;
    const int edge_blocks = (twoE + EPB - 1) / EPB;
    const int gx = (N + 63) / 64;

    // ---- CSR build (radix by dst bucket) ----
    hipMemsetAsync(bcnt, 0, (size_t)4 * NBK_MAX * sizeof(int), stream);
    bucket_count_kernel<<<edge_blocks, BS, 0, stream>>>(edges, bcnt, NBK, E);
    bucket_scan_kernel<<<1, 1024, 0, stream>>>(bcnt, bko, rbT, twoE);
    partition_kernel<<<edge_blocks, BS, 0, stream>>>(edges, bko, gcur, staging, NBK, E);
    bucket_csr_kernel<<<rbT, BS, 0, stream>>>(staging, bko, csr, off, NBK, N);

    // ---- prep (cvt AFTER bucket_csr: xb8 aliases dead staging) ----
    cvt_kernel<<<(N * 32 + BS - 1) / BS, BS, 0, stream>>>(x, xb, xb8, N * 32);
    prep_kernel<<<(16384 + BS - 1) / BS, BS, 0, stream>>>(
        Ws1, Wn1, b1, Ws2, Wn2, b2,
        WT1z, WT1a, WT1b, bc1, WT2z, WT2a, WT2b, bc2);

    // ---- Layer 1: fp8 aggregate (full-wave), then fused 3-matmul GEMM ---
    agg1_kernel<<<(N + 3) / 4, BS, 0, stream>>>(xb8, csr, off, m0, m1, N, twoE);
    gemm1_fused_kernel<<<gx, BS, 0, stream>>>(xb, m0, m1, WT1z, WT1a, WT1b,
                                              bc1, h1b, N);

    // ---- Layer 2: fused transform (z2 f32, t0/t1 fp8), quarter-wave agg -
    gemm2_fused_kernel<<<gx, BS, 0, stream>>>(h1b, WT2z, WT2a, WT2b, bc2,
                                              z2, t08, t18, N);
    agg2_kernel<<<(N + 3) / 4, BS, 0, stream>>>(t08, t18, z2, csr, off, h2b, N, twoE);

    // ---- Scores (pos + neg in one launch) ----
    score_kernel<<<((E + En) * 8 + BS - 1) / BS, BS, 0, stream>>>(
        h2b, edges, neg, out, E, En);
}

// Round 9
// 363.595 us; speedup vs baseline: 1.3172x; 1.0006x over previous
//
#include <hip/hip_runtime.h>

// ---------------------------------------------------------------------------
// GraphSAGE 2-layer hetero (R=2) + edge dot scorer.  Round 17:
//  * GEMM kernels rebuilt for latency hiding (r16 profile: gemm1 54us with
//    MfmaUtil 3%, VALU 3%, HBM 7%, Occ 21%, VGPR 52 -> serialized B-loads
//    at L2 latency + LDS-capped occupancy):
//    - LDS transpose epilogue REMOVED: direct stores from MFMA C layout
//      (per (t,i): quad writes 16 contiguous ushorts = 32B). LDS -> 0.
//    - All A-frags prefetched as NAMED registers (12 for gemm1, 4 for
//      gemm2) -> loads stay in flight, VGPR ~90-100.
//    - gemm1 split over grid.y=2 col-halves: 1564 blocks ~ 6/CU -> 20+
//      waves/CU TLP. A re-read is L3-resident (HBM at 7%, don't care).
//  * agg1 (full-wave fp8 128B rows, RFL csr), agg2 (quarter-wave fp8 64B
//    rows), CSR build, score: verbatim round 16.
// ---------------------------------------------------------------------------

#define BW 128            // nodes per radix bucket (pow2)
#define NBK_MAX 1024
#define EPB 8192          // edges per block in radix passes

typedef __attribute__((ext_vector_type(8))) short bf16x8;
typedef __attribute__((ext_vector_type(4))) float floatx4;
typedef __attribute__((ext_vector_type(2))) float floatx2;

__device__ __forceinline__ unsigned short f2bf(float f) {
    unsigned u = __float_as_uint(f);
    unsigned r = u + 0x7FFFu + ((u >> 16) & 1u);
    return (unsigned short)(r >> 16);
}
__device__ __forceinline__ unsigned pack2(float a, float b) {
    return (unsigned)f2bf(a) | ((unsigned)f2bf(b) << 16);
}
__device__ __forceinline__ float bflo(unsigned v) { return __uint_as_float(v << 16); }
__device__ __forceinline__ float bfhi(unsigned v) { return __uint_as_float(v & 0xFFFF0000u); }
#define RFL(x) __builtin_amdgcn_readfirstlane(x)

// ---- fp8 e4m3 helpers (hw cvt when available, bit-math fallback) --------
#if defined(__has_builtin) && __has_builtin(__builtin_amdgcn_cvt_pk_f32_fp8)
__device__ __forceinline__ floatx2 fp8lo(unsigned v) {
    return __builtin_amdgcn_cvt_pk_f32_fp8((int)v, false);
}
__device__ __forceinline__ floatx2 fp8hi(unsigned v) {
    return __builtin_amdgcn_cvt_pk_f32_fp8((int)v, true);
}
#else
__device__ __forceinline__ float fp8_1(unsigned b) {
    return __uint_as_float(((b & 0x80u) << 24) | ((b & 0x7Fu) << 20)) * 0x1.0p+120f;
}
__device__ __forceinline__ floatx2 fp8lo(unsigned v) {
    floatx2 r; r.x = fp8_1(v & 0xFFu); r.y = fp8_1((v >> 8) & 0xFFu); return r;
}
__device__ __forceinline__ floatx2 fp8hi(unsigned v) {
    floatx2 r; r.x = fp8_1((v >> 16) & 0xFFu); r.y = fp8_1((v >> 24) & 0xFFu); return r;
}
#endif

#if defined(__has_builtin) && __has_builtin(__builtin_amdgcn_cvt_pk_fp8_f32)
__device__ __forceinline__ unsigned f32x4_fp8x4(float a, float b, float c, float d) {
    unsigned lo = __builtin_amdgcn_cvt_pk_fp8_f32(a, b, 0, false);
    return __builtin_amdgcn_cvt_pk_fp8_f32(c, d, lo, true);
}
__device__ __forceinline__ unsigned char f2fp8_1(float x) {
    return (unsigned char)(__builtin_amdgcn_cvt_pk_fp8_f32(x, x, 0, false) & 0xFFu);
}
#else
__device__ __forceinline__ unsigned f2fp8(float x) {
    float m = fminf(fabsf(x), 448.0f);
    unsigned u = __float_as_uint(m * 0x1.0p-120f);
    unsigned r = (u + 0x7FFFFu + ((u >> 20) & 1u)) >> 20;
    if (r > 0x7Eu) r = 0x7Eu;
    return r | ((__float_as_uint(x) >> 24) & 0x80u);
}
__device__ __forceinline__ unsigned f32x4_fp8x4(float a, float b, float c, float d) {
    return f2fp8(a) | (f2fp8(b) << 8) | (f2fp8(c) << 16) | (f2fp8(d) << 24);
}
__device__ __forceinline__ unsigned char f2fp8_1(float x) {
    return (unsigned char)f2fp8(x);
}
#endif

// ---- radix pass A: per-(r,bucket) counts --------------------------------
__global__ __launch_bounds__(256) void
bucket_count_kernel(const int* __restrict__ edges, int* __restrict__ bcnt,
                    int NBK, int E)
{
    __shared__ int cnt[2 * NBK_MAX];
    const int rbT = 2 * NBK;
    const int t = threadIdx.x;
    for (int k = t; k < rbT; k += 256) cnt[k] = 0;
    __syncthreads();
    long long start = (long long)blockIdx.x * EPB;
    long long twoE = 2LL * E;
    for (int u = 0; u < EPB / 256; ++u) {
        long long idx = start + u * 256 + t;
        if (idx < twoE) {
            int r = idx >= E;
            int e = (int)(idx - (long long)r * E);
            int d = edges[(size_t)r * 2 * E + E + e];
            atomicAdd(&cnt[r * NBK + (d >> 7)], 1);
        }
    }
    __syncthreads();
    for (int k = t; k < rbT; k += 256)
        if (cnt[k]) atomicAdd(&bcnt[k], cnt[k]);
}

// ---- radix pass B: exclusive scan of bucket counts ----------------------
__global__ __launch_bounds__(1024) void
bucket_scan_kernel(const int* __restrict__ bcnt, int* __restrict__ bko,
                   int rbT, int twoE)
{
    __shared__ int sm[1024];
    int t = threadIdx.x;
    int v = (t < rbT) ? bcnt[t] : 0;
    sm[t] = v;
    __syncthreads();
    for (int s = 1; s < 1024; s <<= 1) {
        int u = (t >= s) ? sm[t - s] : 0;
        __syncthreads();
        sm[t] += u;
        __syncthreads();
    }
    if (t < rbT) bko[t] = sm[t] - v;
    if (t == 0) bko[rbT] = twoE;
}

// ---- radix pass C: partition into bucket-grouped (src,dst) pairs --------
__global__ __launch_bounds__(256) void
partition_kernel(const int* __restrict__ edges, const int* __restrict__ bko,
                 int* __restrict__ gcur, uint2* __restrict__ staging,
                 int NBK, int E)
{
    __shared__ int cnt[2 * NBK_MAX];
    __shared__ int base[2 * NBK_MAX];
    const int rbT = 2 * NBK;
    const int t = threadIdx.x;
    for (int k = t; k < rbT; k += 256) cnt[k] = 0;
    __syncthreads();
    long long start = (long long)blockIdx.x * EPB;
    long long twoE = 2LL * E;
    for (int u = 0; u < EPB / 256; ++u) {
        long long idx = start + u * 256 + t;
        if (idx < twoE) {
            int r = idx >= E;
            int e = (int)(idx - (long long)r * E);
            int d = edges[(size_t)r * 2 * E + E + e];
            atomicAdd(&cnt[r * NBK + (d >> 7)], 1);
        }
    }
    __syncthreads();
    for (int k = t; k < rbT; k += 256) {
        int c0 = cnt[k];
        if (c0) base[k] = bko[k] + atomicAdd(&gcur[k], c0);
        cnt[k] = 0;
    }
    __syncthreads();
    for (int u = 0; u < EPB / 256; ++u) {
        long long idx = start + u * 256 + t;
        if (idx < twoE) {
            int r = idx >= E;
            int e = (int)(idx - (long long)r * E);
            int s = edges[(size_t)r * 2 * E + e];
            int d = edges[(size_t)r * 2 * E + E + e];
            int rb = r * NBK + (d >> 7);
            int pos = atomicAdd(&cnt[rb], 1);
            staging[(size_t)base[rb] + pos] = make_uint2((unsigned)s, (unsigned)d);
        }
    }
}

// ---- radix pass D: per-bucket node hist/scan -> off[] and csr[] ----------
__global__ __launch_bounds__(256) void
bucket_csr_kernel(const uint2* __restrict__ staging, const int* __restrict__ bko,
                  int* __restrict__ csr, int* __restrict__ off,
                  int NBK, int N)
{
    __shared__ int hist[BW], excl[BW], cur[BW], sc[BW];
    const int rb = blockIdx.x;
    const int r = rb / NBK;
    const int b = rb % NBK;
    const int node0 = b * BW;
    const int nn = min(BW, N - node0);
    const int cbase = bko[rb];
    const int c = bko[rb + 1] - cbase;
    const int t = threadIdx.x;

    if (t < BW) { hist[t] = 0; cur[t] = 0; }
    __syncthreads();
    for (int k = t; k < c; k += 256)
        atomicAdd(&hist[(int)staging[(size_t)cbase + k].y - node0], 1);
    __syncthreads();
    if (t < BW) sc[t] = hist[t];
    __syncthreads();
    for (int s = 1; s < BW; s <<= 1) {
        int v = (t < BW && t >= s) ? sc[t - s] : 0;
        __syncthreads();
        if (t < BW) sc[t] += v;
        __syncthreads();
    }
    if (t < BW) excl[t] = sc[t] - hist[t];
    if (t < nn) off[(size_t)r * N + node0 + t] = cbase + excl[t];
    __syncthreads();
    for (int k = t; k < c; k += 256) {
        uint2 pr = staging[(size_t)cbase + k];
        int l = (int)pr.y - node0;
        int pos = atomicAdd(&cur[l], 1);
        csr[(size_t)cbase + excl[l] + pos] = (int)pr.x;
    }
}

// ---- f32 -> bf16 [N,128] + fp8 [N,128] ----------------------------------
__global__ void cvt_kernel(const float* __restrict__ in,
                           unsigned short* __restrict__ o,
                           unsigned char* __restrict__ o8, int n4)
{
    int t = blockIdx.x * blockDim.x + threadIdx.x;
    if (t >= n4) return;
    float4 v = ((const float4*)in)[t];
    ushort4 r;
    r.x = f2bf(v.x); r.y = f2bf(v.y); r.z = f2bf(v.z); r.w = f2bf(v.w);
    ((ushort4*)o)[t] = r;
    ((unsigned*)o8)[t] = f32x4_fp8x4(v.x, v.y, v.z, v.w);
}

// ---- weight prep: combined-Wself / Wn -> bf16 W^T rows, biases ----------
__global__ void prep_kernel(const float* __restrict__ Ws1, const float* __restrict__ Wn1,
                            const float* __restrict__ b1,
                            const float* __restrict__ Ws2, const float* __restrict__ Wn2,
                            const float* __restrict__ b2,
                            unsigned short* __restrict__ WT1z, unsigned short* __restrict__ WT1a,
                            unsigned short* __restrict__ WT1b, float* __restrict__ bc1,
                            unsigned short* __restrict__ WT2z, unsigned short* __restrict__ WT2a,
                            unsigned short* __restrict__ WT2b, float* __restrict__ bc2)
{
    int t = blockIdx.x * blockDim.x + threadIdx.x;
    if (t < 16384) {                 // layer 1: [n][k] <- [k][n], n,k < 128
        int n = t >> 7, k = t & 127;
        int in = k * 128 + n;
        WT1z[t] = f2bf(Ws1[in] + Ws1[16384 + in]);
        WT1a[t] = f2bf(Wn1[in]);
        WT1b[t] = f2bf(Wn1[16384 + in]);
    }
    if (t < 8192) {                  // layer 2: n < 64, k < 128
        int n = t >> 7, k = t & 127;
        int in = k * 64 + n;
        WT2z[t] = f2bf(Ws2[in] + Ws2[8192 + in]);
        WT2a[t] = f2bf(Wn2[in]);
        WT2b[t] = f2bf(Wn2[8192 + in]);
    }
    if (t < 128) bc1[t] = b1[t] + b1[128 + t];
    if (t < 64)  bc2[t] = b2[t] + b2[64 + t];
}

// ---- agg L1: wave per node, fp8 gathers (128B/row), RFL csr, unroll x8 --
__global__ __launch_bounds__(256) void
agg1_kernel(const unsigned char* __restrict__ xb8,
            const int* __restrict__ csr, const int* __restrict__ off,
            unsigned short* __restrict__ m0, unsigned short* __restrict__ m1,
            int N, int twoE)
{
    int w = blockIdx.x * 4 + (threadIdx.x >> 6);
    int lane = threadIdx.x & 63;
    if (w >= N) return;
    const int col = lane * 2;
    const unsigned char* xc = xb8 + col;

    float sx0 = 0.f, sy0 = 0.f, sx1 = 0.f, sy1 = 0.f;

    // ---- relation 0 ----
    int o0 = RFL(off[w]);
    int o1 = RFL(off[w + 1]);
    int d0 = o1 - o0;
    int j = o0;
    for (; j + 7 < o1; j += 8) {
        int s0 = RFL(csr[j]);     int s1 = RFL(csr[j + 1]);
        int s2 = RFL(csr[j + 2]); int s3 = RFL(csr[j + 3]);
        int s4 = RFL(csr[j + 4]); int s5 = RFL(csr[j + 5]);
        int s6 = RFL(csr[j + 6]); int s7 = RFL(csr[j + 7]);
        unsigned a0 = *(const unsigned short*)(xc + (size_t)s0 * 128);
        unsigned a1 = *(const unsigned short*)(xc + (size_t)s1 * 128);
        unsigned a2 = *(const unsigned short*)(xc + (size_t)s2 * 128);
        unsigned a3 = *(const unsigned short*)(xc + (size_t)s3 * 128);
        unsigned a4 = *(const unsigned short*)(xc + (size_t)s4 * 128);
        unsigned a5 = *(const unsigned short*)(xc + (size_t)s5 * 128);
        unsigned a6 = *(const unsigned short*)(xc + (size_t)s6 * 128);
        unsigned a7 = *(const unsigned short*)(xc + (size_t)s7 * 128);
        floatx2 v0 = fp8lo(a0); floatx2 v1 = fp8lo(a1);
        floatx2 v2 = fp8lo(a2); floatx2 v3 = fp8lo(a3);
        floatx2 v4 = fp8lo(a4); floatx2 v5 = fp8lo(a5);
        floatx2 v6 = fp8lo(a6); floatx2 v7 = fp8lo(a7);
        sx0 += ((v0.x + v1.x) + (v2.x + v3.x)) + ((v4.x + v5.x) + (v6.x + v7.x));
        sy0 += ((v0.y + v1.y) + (v2.y + v3.y)) + ((v4.y + v5.y) + (v6.y + v7.y));
    }
    for (; j < o1; ++j) {
        int s0 = RFL(csr[j]);
        floatx2 v = fp8lo(*(const unsigned short*)(xc + (size_t)s0 * 128));
        sx0 += v.x; sy0 += v.y;
    }

    // ---- relation 1 ----
    int p = N + w;
    o0 = RFL(off[p]);
    o1 = (p + 1 < 2 * N) ? RFL(off[p + 1]) : twoE;
    int d1 = o1 - o0;
    j = o0;
    for (; j + 7 < o1; j += 8) {
        int s0 = RFL(csr[j]);     int s1 = RFL(csr[j + 1]);
        int s2 = RFL(csr[j + 2]); int s3 = RFL(csr[j + 3]);
        int s4 = RFL(csr[j + 4]); int s5 = RFL(csr[j + 5]);
        int s6 = RFL(csr[j + 6]); int s7 = RFL(csr[j + 7]);
        unsigned a0 = *(const unsigned short*)(xc + (size_t)s0 * 128);
        unsigned a1 = *(const unsigned short*)(xc + (size_t)s1 * 128);
        unsigned a2 = *(const unsigned short*)(xc + (size_t)s2 * 128);
        unsigned a3 = *(const unsigned short*)(xc + (size_t)s3 * 128);
        unsigned a4 = *(const unsigned short*)(xc + (size_t)s4 * 128);
        unsigned a5 = *(const unsigned short*)(xc + (size_t)s5 * 128);
        unsigned a6 = *(const unsigned short*)(xc + (size_t)s6 * 128);
        unsigned a7 = *(const unsigned short*)(xc + (size_t)s7 * 128);
        floatx2 v0 = fp8lo(a0); floatx2 v1 = fp8lo(a1);
        floatx2 v2 = fp8lo(a2); floatx2 v3 = fp8lo(a3);
        floatx2 v4 = fp8lo(a4); floatx2 v5 = fp8lo(a5);
        floatx2 v6 = fp8lo(a6); floatx2 v7 = fp8lo(a7);
        sx1 += ((v0.x + v1.x) + (v2.x + v3.x)) + ((v4.x + v5.x) + (v6.x + v7.x));
        sy1 += ((v0.y + v1.y) + (v2.y + v3.y)) + ((v4.y + v5.y) + (v6.y + v7.y));
    }
    for (; j < o1; ++j) {
        int s0 = RFL(csr[j]);
        floatx2 v = fp8lo(*(const unsigned short*)(xc + (size_t)s0 * 128));
        sx1 += v.x; sy1 += v.y;
    }

    float inv0 = 1.0f / fmaxf((float)d0, 1.0f);
    float inv1 = 1.0f / fmaxf((float)d1, 1.0f);
    *(unsigned*)(m0 + (size_t)w * 128 + col) = pack2(sx0 * inv0, sy0 * inv0);
    *(unsigned*)(m1 + (size_t)w * 128 + col) = pack2(sx1 * inv1, sy1 * inv1);
}

// ---- fused layer-1 GEMM v2: no LDS, direct stores, col-half split -------
// grid (gx, 2): block = 64 rows x 64 cols (blockIdx.y col half).
// 12 A-frags prefetched as named registers; 48 B-loads + 48 MFMAs.
__global__ __launch_bounds__(256) void
gemm1_fused_kernel(const unsigned short* __restrict__ xb,
                   const unsigned short* __restrict__ m0,
                   const unsigned short* __restrict__ m1,
                   const unsigned short* __restrict__ WTz,
                   const unsigned short* __restrict__ WTa,
                   const unsigned short* __restrict__ WTb,
                   const float* __restrict__ bias,
                   unsigned short* __restrict__ h1b, int N)
{
    const int tid = threadIdx.x;
    const int wave = tid >> 6;
    const int lane = tid & 63;
    const int m = lane & 15;
    const int quad = lane >> 4;
    const int colbase = blockIdx.y * 64;

    floatx4 acc[4];
    const floatx4 z4 = {0.f, 0.f, 0.f, 0.f};
#pragma unroll
    for (int t = 0; t < 4; ++t) acc[t] = z4;

    int arow = blockIdx.x * 64 + wave * 16 + m;
    if (arow >= N) arow = N - 1;
    const size_t ab = (size_t)arow * 128 + quad * 8;

    // prefetch all 12 A-frags (named -> stay in flight)
    bf16x8 ax0 = *(const bf16x8*)(xb + ab);
    bf16x8 ax1 = *(const bf16x8*)(xb + ab + 32);
    bf16x8 ax2 = *(const bf16x8*)(xb + ab + 64);
    bf16x8 ax3 = *(const bf16x8*)(xb + ab + 96);
    bf16x8 a00 = *(const bf16x8*)(m0 + ab);
    bf16x8 a01 = *(const bf16x8*)(m0 + ab + 32);
    bf16x8 a02 = *(const bf16x8*)(m0 + ab + 64);
    bf16x8 a03 = *(const bf16x8*)(m0 + ab + 96);
    bf16x8 a10 = *(const bf16x8*)(m1 + ab);
    bf16x8 a11 = *(const bf16x8*)(m1 + ab + 32);
    bf16x8 a12 = *(const bf16x8*)(m1 + ab + 64);
    bf16x8 a13 = *(const bf16x8*)(m1 + ab + 96);

#pragma unroll
    for (int t = 0; t < 4; ++t) {
        const size_t bo = (size_t)(colbase + t * 16 + m) * 128 + quad * 8;
        acc[t] = __builtin_amdgcn_mfma_f32_16x16x32_bf16(
            ax0, *(const bf16x8*)(WTz + bo), acc[t], 0, 0, 0);
        acc[t] = __builtin_amdgcn_mfma_f32_16x16x32_bf16(
            a00, *(const bf16x8*)(WTa + bo), acc[t], 0, 0, 0);
        acc[t] = __builtin_amdgcn_mfma_f32_16x16x32_bf16(
            a10, *(const bf16x8*)(WTb + bo), acc[t], 0, 0, 0);
        acc[t] = __builtin_amdgcn_mfma_f32_16x16x32_bf16(
            ax1, *(const bf16x8*)(WTz + bo + 32), acc[t], 0, 0, 0);
        acc[t] = __builtin_amdgcn_mfma_f32_16x16x32_bf16(
            a01, *(const bf16x8*)(WTa + bo + 32), acc[t], 0, 0, 0);
        acc[t] = __builtin_amdgcn_mfma_f32_16x16x32_bf16(
            a11, *(const bf16x8*)(WTb + bo + 32), acc[t], 0, 0, 0);
        acc[t] = __builtin_amdgcn_mfma_f32_16x16x32_bf16(
            ax2, *(const bf16x8*)(WTz + bo + 64), acc[t], 0, 0, 0);
        acc[t] = __builtin_amdgcn_mfma_f32_16x16x32_bf16(
            a02, *(const bf16x8*)(WTa + bo + 64), acc[t], 0, 0, 0);
        acc[t] = __builtin_amdgcn_mfma_f32_16x16x32_bf16(
            a12, *(const bf16x8*)(WTb + bo + 64), acc[t], 0, 0, 0);
        acc[t] = __builtin_amdgcn_mfma_f32_16x16x32_bf16(
            ax3, *(const bf16x8*)(WTz + bo + 96), acc[t], 0, 0, 0);
        acc[t] = __builtin_amdgcn_mfma_f32_16x16x32_bf16(
            a03, *(const bf16x8*)(WTa + bo + 96), acc[t], 0, 0, 0);
        acc[t] = __builtin_amdgcn_mfma_f32_16x16x32_bf16(
            a13, *(const bf16x8*)(WTb + bo + 96), acc[t], 0, 0, 0);
    }

    // direct store from C layout: row = quad*4+i, col = colbase+t*16+m
    const int gr0 = blockIdx.x * 64 + wave * 16 + quad * 4;
#pragma unroll
    for (int t = 0; t < 4; ++t) {
        int colg = colbase + t * 16 + m;
        float bv = bias[colg];
#pragma unroll
        for (int i = 0; i < 4; ++i) {
            int gr = gr0 + i;
            if (gr < N)
                h1b[(size_t)gr * 128 + colg] = f2bf(fmaxf(acc[t][i] + bv, 0.0f));
        }
    }
}

// ---- fused layer-2 GEMM v2: no LDS, direct stores ------------------------
// 64 rows x 64 cols x 3 mats per block; 4 A-frags prefetched.
__global__ __launch_bounds__(256) void
gemm2_fused_kernel(const unsigned short* __restrict__ Ab,
                   const unsigned short* __restrict__ WTz,
                   const unsigned short* __restrict__ WTa,
                   const unsigned short* __restrict__ WTb,
                   const float* __restrict__ bias,
                   float* __restrict__ zf,
                   unsigned char* __restrict__ t08, unsigned char* __restrict__ t18,
                   int N)
{
    const int tid = threadIdx.x;
    const int wave = tid >> 6;
    const int lane = tid & 63;
    const int m = lane & 15;
    const int quad = lane >> 4;

    floatx4 accz[4], acca[4], accb[4];
    const floatx4 z4 = {0.f, 0.f, 0.f, 0.f};
#pragma unroll
    for (int t = 0; t < 4; ++t) { accz[t] = z4; acca[t] = z4; accb[t] = z4; }

    int arow = blockIdx.x * 64 + wave * 16 + m;
    if (arow >= N) arow = N - 1;
    const size_t ab = (size_t)arow * 128 + quad * 8;

    bf16x8 h0 = *(const bf16x8*)(Ab + ab);
    bf16x8 h1 = *(const bf16x8*)(Ab + ab + 32);
    bf16x8 h2 = *(const bf16x8*)(Ab + ab + 64);
    bf16x8 h3 = *(const bf16x8*)(Ab + ab + 96);

#pragma unroll
    for (int t = 0; t < 4; ++t) {
        const size_t bo = (size_t)(t * 16 + m) * 128 + quad * 8;
        accz[t] = __builtin_amdgcn_mfma_f32_16x16x32_bf16(
            h0, *(const bf16x8*)(WTz + bo), accz[t], 0, 0, 0);
        acca[t] = __builtin_amdgcn_mfma_f32_16x16x32_bf16(
            h0, *(const bf16x8*)(WTa + bo), acca[t], 0, 0, 0);
        accb[t] = __builtin_amdgcn_mfma_f32_16x16x32_bf16(
            h0, *(const bf16x8*)(WTb + bo), accb[t], 0, 0, 0);
        accz[t] = __builtin_amdgcn_mfma_f32_16x16x32_bf16(
            h1, *(const bf16x8*)(WTz + bo + 32), accz[t], 0, 0, 0);
        acca[t] = __builtin_amdgcn_mfma_f32_16x16x32_bf16(
            h1, *(const bf16x8*)(WTa + bo + 32), acca[t], 0, 0, 0);
        accb[t] = __builtin_amdgcn_mfma_f32_16x16x32_bf16(
            h1, *(const bf16x8*)(WTb + bo + 32), accb[t], 0, 0, 0);
        accz[t] = __builtin_amdgcn_mfma_f32_16x16x32_bf16(
            h2, *(const bf16x8*)(WTz + bo + 64), accz[t], 0, 0, 0);
        acca[t] = __builtin_amdgcn_mfma_f32_16x16x32_bf16(
            h2, *(const bf16x8*)(WTa + bo + 64), acca[t], 0, 0, 0);
        accb[t] = __builtin_amdgcn_mfma_f32_16x16x32_bf16(
            h2, *(const bf16x8*)(WTb + bo + 64), accb[t], 0, 0, 0);
        accz[t] = __builtin_amdgcn_mfma_f32_16x16x32_bf16(
            h3, *(const bf16x8*)(WTz + bo + 96), accz[t], 0, 0, 0);
        acca[t] = __builtin_amdgcn_mfma_f32_16x16x32_bf16(
            h3, *(const bf16x8*)(WTa + bo + 96), acca[t], 0, 0, 0);
        accb[t] = __builtin_amdgcn_mfma_f32_16x16x32_bf16(
            h3, *(const bf16x8*)(WTb + bo + 96), accb[t], 0, 0, 0);
    }

    const int gr0 = blockIdx.x * 64 + wave * 16 + quad * 4;
#pragma unroll
    for (int t = 0; t < 4; ++t) {
        int colg = t * 16 + m;
        float bv = bias[colg];
#pragma unroll
        for (int i = 0; i < 4; ++i) {
            int gr = gr0 + i;
            if (gr < N) {
                zf[(size_t)gr * 64 + colg] = accz[t][i] + bv;
                t08[(size_t)gr * 64 + colg] = f2fp8_1(acca[t][i]);
                t18[(size_t)gr * 64 + colg] = f2fp8_1(accb[t][i]);
            }
        }
    }
}

// ---- agg L2: quarter-wave per edge, fp8 64B rows, 16 edges/iter ---------
__global__ __launch_bounds__(256) void
agg2_kernel(const unsigned char* __restrict__ t08,
            const unsigned char* __restrict__ t18,
            const float* __restrict__ z2,
            const int* __restrict__ csr, const int* __restrict__ off,
            unsigned short* __restrict__ h2b, int N, int twoE)
{
    int w = blockIdx.x * 4 + (threadIdx.x >> 6);
    int lane = threadIdx.x & 63;
    if (w >= N) return;
    const int q = lane >> 4;                 // edge slot 0..3
    const int col = (lane & 15) * 4;         // 4 fp8 cols per lane
    const unsigned char* t0c = t08 + col;
    const unsigned char* t1c = t18 + col;

    float a0 = 0.f, a1 = 0.f, a2 = 0.f, a3 = 0.f;   // rel0
    float b0 = 0.f, b1 = 0.f, b2 = 0.f, b3 = 0.f;   // rel1

    // ---- relation 0 ----
    int o0 = RFL(off[w]);
    int o1 = RFL(off[w + 1]);
    int d0 = o1 - o0;
    int j = o0;
    for (; j + 15 < o1; j += 16) {
        int r0 = csr[j + q];
        int r1 = csr[j + 4 + q];
        int r2 = csr[j + 8 + q];
        int r3 = csr[j + 12 + q];
        unsigned v0 = *(const unsigned*)(t0c + (size_t)r0 * 64);
        unsigned v1 = *(const unsigned*)(t0c + (size_t)r1 * 64);
        unsigned v2 = *(const unsigned*)(t0c + (size_t)r2 * 64);
        unsigned v3 = *(const unsigned*)(t0c + (size_t)r3 * 64);
        floatx2 l0 = fp8lo(v0), h0 = fp8hi(v0);
        floatx2 l1 = fp8lo(v1), h1 = fp8hi(v1);
        floatx2 l2 = fp8lo(v2), h2 = fp8hi(v2);
        floatx2 l3 = fp8lo(v3), h3 = fp8hi(v3);
        a0 += (l0.x + l1.x) + (l2.x + l3.x);
        a1 += (l0.y + l1.y) + (l2.y + l3.y);
        a2 += (h0.x + h1.x) + (h2.x + h3.x);
        a3 += (h0.y + h1.y) + (h2.y + h3.y);
    }
    for (; j + 3 < o1; j += 4) {
        int r = csr[j + q];
        unsigned v = *(const unsigned*)(t0c + (size_t)r * 64);
        floatx2 l = fp8lo(v), h = fp8hi(v);
        a0 += l.x; a1 += l.y; a2 += h.x; a3 += h.y;
    }
    if (j < o1 && q < o1 - j) {
        int r = csr[j + q];
        unsigned v = *(const unsigned*)(t0c + (size_t)r * 64);
        floatx2 l = fp8lo(v), h = fp8hi(v);
        a0 += l.x; a1 += l.y; a2 += h.x; a3 += h.y;
    }

    // ---- relation 1 ----
    int p = N + w;
    o0 = RFL(off[p]);
    o1 = (p + 1 < 2 * N) ? RFL(off[p + 1]) : twoE;
    int d1 = o1 - o0;
    j = o0;
    for (; j + 15 < o1; j += 16) {
        int r0 = csr[j + q];
        int r1 = csr[j + 4 + q];
        int r2 = csr[j + 8 + q];
        int r3 = csr[j + 12 + q];
        unsigned v0 = *(const unsigned*)(t1c + (size_t)r0 * 64);
        unsigned v1 = *(const unsigned*)(t1c + (size_t)r1 * 64);
        unsigned v2 = *(const unsigned*)(t1c + (size_t)r2 * 64);
        unsigned v3 = *(const unsigned*)(t1c + (size_t)r3 * 64);
        floatx2 l0 = fp8lo(v0), h0 = fp8hi(v0);
        floatx2 l1 = fp8lo(v1), h1 = fp8hi(v1);
        floatx2 l2 = fp8lo(v2), h2 = fp8hi(v2);
        floatx2 l3 = fp8lo(v3), h3 = fp8hi(v3);
        b0 += (l0.x + l1.x) + (l2.x + l3.x);
        b1 += (l0.y + l1.y) + (l2.y + l3.y);
        b2 += (h0.x + h1.x) + (h2.x + h3.x);
        b3 += (h0.y + h1.y) + (h2.y + h3.y);
    }
    for (; j + 3 < o1; j += 4) {
        int r = csr[j + q];
        unsigned v = *(const unsigned*)(t1c + (size_t)r * 64);
        floatx2 l = fp8lo(v), h = fp8hi(v);
        b0 += l.x; b1 += l.y; b2 += h.x; b3 += h.y;
    }
    if (j < o1 && q < o1 - j) {
        int r = csr[j + q];
        unsigned v = *(const unsigned*)(t1c + (size_t)r * 64);
        floatx2 l = fp8lo(v), h = fp8hi(v);
        b0 += l.x; b1 += l.y; b2 += h.x; b3 += h.y;
    }

    // cross-quarter reduce + write
    a0 += __shfl_xor(a0, 16); a1 += __shfl_xor(a1, 16);
    a2 += __shfl_xor(a2, 16); a3 += __shfl_xor(a3, 16);
    b0 += __shfl_xor(b0, 16); b1 += __shfl_xor(b1, 16);
    b2 += __shfl_xor(b2, 16); b3 += __shfl_xor(b3, 16);
    a0 += __shfl_xor(a0, 32); a1 += __shfl_xor(a1, 32);
    a2 += __shfl_xor(a2, 32); a3 += __shfl_xor(a3, 32);
    b0 += __shfl_xor(b0, 32); b1 += __shfl_xor(b1, 32);
    b2 += __shfl_xor(b2, 32); b3 += __shfl_xor(b3, 32);
    if (q == 0) {
        float inv0 = 1.0f / fmaxf((float)d0, 1.0f);
        float inv1 = 1.0f / fmaxf((float)d1, 1.0f);
        float4 z = *(const float4*)(z2 + (size_t)w * 64 + col);
        float h0v = z.x + a0 * inv0 + b0 * inv1;
        float h1v = z.y + a1 * inv0 + b1 * inv1;
        float h2v = z.z + a2 * inv0 + b2 * inv1;
        float h3v = z.w + a3 * inv0 + b3 * inv1;
        uint2 u;
        u.x = pack2(h0v, h1v);
        u.y = pack2(h2v, h3v);
        *(uint2*)(h2b + (size_t)w * 64 + col) = u;
    }
}

// ---- score (merged pos+neg): 8 lanes/edge, 128B rows, shfl reduce --------
__global__ __launch_bounds__(256) void
score_kernel(const unsigned short* __restrict__ h, // [N,64] bf16
             const int* __restrict__ edges, const int* __restrict__ neg,
             float* __restrict__ out, int E, int En)
{
    int t = blockIdx.x * blockDim.x + threadIdx.x;
    int e = t >> 3;
    int c = t & 7;
    if (e >= E + En) return;
    int sI, dI, oI;
    if (e < E) { sI = edges[e]; dI = edges[E + e]; oI = e; }
    else { int en = e - E; sI = neg[en]; dI = neg[En + en]; oI = E + en; }
    uint4 va = *(const uint4*)(h + (size_t)sI * 64 + c * 8);
    uint4 vb = *(const uint4*)(h + (size_t)dI * 64 + c * 8);
    float s = 0.0f;
    s = fmaf(bflo(va.x), bflo(vb.x), s);
    s = fmaf(bfhi(va.x), bfhi(vb.x), s);
    s = fmaf(bflo(va.y), bflo(vb.y), s);
    s = fmaf(bfhi(va.y), bfhi(vb.y), s);
    s = fmaf(bflo(va.z), bflo(vb.z), s);
    s = fmaf(bfhi(va.z), bfhi(vb.z), s);
    s = fmaf(bflo(va.w), bflo(vb.w), s);
    s = fmaf(bfhi(va.w), bfhi(vb.w), s);
    s += __shfl_xor(s, 1);
    s += __shfl_xor(s, 2);
    s += __shfl_xor(s, 4);
    if (c == 0) out[oI] = s;
}

extern "C" void kernel_launch(void* const* d_in, const int* in_sizes, int n_in,
                              void* d_out, int out_size, void* d_ws, size_t ws_size,
                              hipStream_t stream)
{
    const float* x     = (const float*)d_in[0];
    const int*   edges = (const int*)d_in[1];
    const int*   neg   = (const int*)d_in[2];
    const float* Wn1   = (const float*)d_in[3];
    const float* Ws1   = (const float*)d_in[4];
    const float* b1    = (const float*)d_in[5];
    const float* Wn2   = (const float*)d_in[6];
    const float* Ws2   = (const float*)d_in[7];
    const float* b2    = (const float*)d_in[8];
    float* out = (float*)d_out;

    const int Fin = 128, R = 2;
    const int N  = in_sizes[0] / Fin;        // 50000
    const int E  = in_sizes[1] / (R * 2);    // 800000
    const int En = in_sizes[2] / 2;          // 800000
    const int twoE = 2 * E;
    const int NBK = (N + BW - 1) / BW;       // 391
    const int rbT = 2 * NBK;

    // ---- workspace layout (aliases noted) ----
    const size_t nb128 = (size_t)N * 128 * sizeof(unsigned short);   // 12.8MB
    char* p = (char*)d_ws;

    // region0: staging [2E] (CSR build) -> xb8 [N,128] fp8 (cvt..agg1)
    //          -> z2 [N,64] f32 (gemm2..agg2). Lifetimes strictly ordered.
    uint2* staging       = (uint2*)p;
    unsigned char* xb8   = (unsigned char*)p;
    float* z2            = (float*)p;
    {
        size_t r0 = (size_t)twoE * sizeof(uint2);          // 12.8MB
        size_t r1 = (size_t)N * 64 * sizeof(float);        // 12.8MB
        size_t r2 = (size_t)N * 128;                       // 6.4MB
        size_t rm = r0 > r1 ? r0 : r1;
        if (r2 > rm) rm = r2;
        p += rm;
    }
    unsigned short* m0  = (unsigned short*)p; p += nb128;  // [N,128] mean rel0 (t08/t18 reuse)
    unsigned short* m1  = (unsigned short*)p; p += nb128;  // [N,128] mean rel1 (h2b reuse)
    unsigned short* xb  = (unsigned short*)p; p += nb128;  // [N,128] bf16 x
    unsigned short* h1b = (unsigned short*)p; p += nb128;  // [N,128] bf16 h1
    unsigned short* WT1z = (unsigned short*)p; p += 16384 * 2;
    unsigned short* WT1a = (unsigned short*)p; p += 16384 * 2;
    unsigned short* WT1b = (unsigned short*)p; p += 16384 * 2;
    unsigned short* WT2z = (unsigned short*)p; p += 8192 * 2;
    unsigned short* WT2a = (unsigned short*)p; p += 8192 * 2;
    unsigned short* WT2b = (unsigned short*)p; p += 8192 * 2;
    float* bc1 = (float*)p; p += 128 * sizeof(float);
    float* bc2 = (float*)p; p += 64 * sizeof(float);
    int* bcnt = (int*)p; p += (size_t)2 * NBK_MAX * sizeof(int);
    int* gcur = (int*)p; p += (size_t)2 * NBK_MAX * sizeof(int);
    int* bko  = (int*)p; p += ((size_t)2 * NBK_MAX + 1) * sizeof(int);
    int* off  = (int*)p; p += (size_t)2 * N * sizeof(int);
    int* csr  = (int*)p;

    unsigned char*  t08 = (unsigned char*)m0;        // [N,64] fp8
    unsigned char*  t18 = t08 + (size_t)N * 64;      // [N,64] fp8
    unsigned short* h2b = m1;                        // [N,64] bf16

    const int BS = 256;
    const int edge_blocks = (twoE + EPB - 1) / EPB;
    const int gx = (N + 63) / 64;

    // ---- CSR build (radix by dst bucket) ----
    hipMemsetAsync(bcnt, 0, (size_t)4 * NBK_MAX * sizeof(int), stream);
    bucket_count_kernel<<<edge_blocks, BS, 0, stream>>>(edges, bcnt, NBK, E);
    bucket_scan_kernel<<<1, 1024, 0, stream>>>(bcnt, bko, rbT, twoE);
    partition_kernel<<<edge_blocks, BS, 0, stream>>>(edges, bko, gcur, staging, NBK, E);
    bucket_csr_kernel<<<rbT, BS, 0, stream>>>(staging, bko, csr, off, NBK, N);

    // ---- prep (cvt AFTER bucket_csr: xb8 aliases dead staging) ----
    cvt_kernel<<<(N * 32 + BS - 1) / BS, BS, 0, stream>>>(x, xb, xb8, N * 32);
    prep_kernel<<<(16384 + BS - 1) / BS, BS, 0, stream>>>(
        Ws1, Wn1, b1, Ws2, Wn2, b2,
        WT1z, WT1a, WT1b, bc1, WT2z, WT2a, WT2b, bc2);

    // ---- Layer 1: fp8 aggregate (full-wave), then fused 3-matmul GEMM ---
    agg1_kernel<<<(N + 3) / 4, BS, 0, stream>>>(xb8, csr, off, m0, m1, N, twoE);
    {
        dim3 g(gx, 2);
        gemm1_fused_kernel<<<g, BS, 0, stream>>>(xb, m0, m1, WT1z, WT1a, WT1b,
                                                 bc1, h1b, N);
    }

    // ---- Layer 2: fused transform (z2 f32, t0/t1 fp8), quarter-wave agg -
    gemm2_fused_kernel<<<gx, BS, 0, stream>>>(h1b, WT2z, WT2a, WT2b, bc2,
                                              z2, t08, t18, N);
    agg2_kernel<<<(N + 3) / 4, BS, 0, stream>>>(t08, t18, z2, csr, off, h2b, N, twoE);

    // ---- Scores (pos + neg in one launch) ----
    score_kernel<<<((E + En) * 8 + BS - 1) / BS, BS, 0, stream>>>(
        h2b, edges, neg, out, E, En);
}

// Round 10
// 318.298 us; speedup vs baseline: 1.5046x; 1.1423x over previous
//
#include <hip/hip_runtime.h>

// ---------------------------------------------------------------------------
// GraphSAGE 2-layer hetero (R=2) + edge dot scorer.  Round 18:
//  * GEMM diagnosis revised: r16 (LDS-epilogue) and r17 (no-LDS, more occ)
//    both sit ~54-60us with ALL counters idle -> address-divergence
//    memory-pipe bound: every B-frag load spans 16 cache lines (lane m
//    reads row t*16+m, rows 256B apart). Fix = canonical structure:
//    - B staged in LDS (48KB: 3 mats x 64 cols x 256B), loaded COALESCED
//      (6 x uint4 per thread), XOR-swizzled (byte ^= (col&7)<<4) to kill
//      the 16-way bank conflict of 256B-stride rows (G4).
//    - MFMA reads B via swizzled ds_read_b128; A stays per-lane global
//      (only 12 scattered instr/wave). 512-thread blocks, 128 rows.
//    - r17-verified direct-store epilogue kept verbatim.
//    - gemm1: grid (N/128, 2) col-halves; gemm2: grid (N/128), 64 cols.
//  * agg1 (full-wave fp8 128B rows), agg2 (quarter-wave fp8 64B rows),
//    CSR build, score, cvt/prep, workspace aliasing: verbatim round 17.
// ---------------------------------------------------------------------------

#define BW 128            // nodes per radix bucket (pow2)
#define NBK_MAX 1024
#define EPB 8192          // edges per block in radix passes

typedef __attribute__((ext_vector_type(8))) short bf16x8;
typedef __attribute__((ext_vector_type(4))) float floatx4;
typedef __attribute__((ext_vector_type(2))) float floatx2;

__device__ __forceinline__ unsigned short f2bf(float f) {
    unsigned u = __float_as_uint(f);
    unsigned r = u + 0x7FFFu + ((u >> 16) & 1u);
    return (unsigned short)(r >> 16);
}
__device__ __forceinline__ unsigned pack2(float a, float b) {
    return (unsigned)f2bf(a) | ((unsigned)f2bf(b) << 16);
}
__device__ __forceinline__ float bflo(unsigned v) { return __uint_as_float(v << 16); }
__device__ __forceinline__ float bfhi(unsigned v) { return __uint_as_float(v & 0xFFFF0000u); }
#define RFL(x) __builtin_amdgcn_readfirstlane(x)

// ---- fp8 e4m3 helpers (hw cvt when available, bit-math fallback) --------
#if defined(__has_builtin) && __has_builtin(__builtin_amdgcn_cvt_pk_f32_fp8)
__device__ __forceinline__ floatx2 fp8lo(unsigned v) {
    return __builtin_amdgcn_cvt_pk_f32_fp8((int)v, false);
}
__device__ __forceinline__ floatx2 fp8hi(unsigned v) {
    return __builtin_amdgcn_cvt_pk_f32_fp8((int)v, true);
}
#else
__device__ __forceinline__ float fp8_1(unsigned b) {
    return __uint_as_float(((b & 0x80u) << 24) | ((b & 0x7Fu) << 20)) * 0x1.0p+120f;
}
__device__ __forceinline__ floatx2 fp8lo(unsigned v) {
    floatx2 r; r.x = fp8_1(v & 0xFFu); r.y = fp8_1((v >> 8) & 0xFFu); return r;
}
__device__ __forceinline__ floatx2 fp8hi(unsigned v) {
    floatx2 r; r.x = fp8_1((v >> 16) & 0xFFu); r.y = fp8_1((v >> 24) & 0xFFu); return r;
}
#endif

#if defined(__has_builtin) && __has_builtin(__builtin_amdgcn_cvt_pk_fp8_f32)
__device__ __forceinline__ unsigned f32x4_fp8x4(float a, float b, float c, float d) {
    unsigned lo = __builtin_amdgcn_cvt_pk_fp8_f32(a, b, 0, false);
    return __builtin_amdgcn_cvt_pk_fp8_f32(c, d, lo, true);
}
__device__ __forceinline__ unsigned char f2fp8_1(float x) {
    return (unsigned char)(__builtin_amdgcn_cvt_pk_fp8_f32(x, x, 0, false) & 0xFFu);
}
#else
__device__ __forceinline__ unsigned f2fp8(float x) {
    float m = fminf(fabsf(x), 448.0f);
    unsigned u = __float_as_uint(m * 0x1.0p-120f);
    unsigned r = (u + 0x7FFFFu + ((u >> 20) & 1u)) >> 20;
    if (r > 0x7Eu) r = 0x7Eu;
    return r | ((__float_as_uint(x) >> 24) & 0x80u);
}
__device__ __forceinline__ unsigned f32x4_fp8x4(float a, float b, float c, float d) {
    return f2fp8(a) | (f2fp8(b) << 8) | (f2fp8(c) << 16) | (f2fp8(d) << 24);
}
__device__ __forceinline__ unsigned char f2fp8_1(float x) {
    return (unsigned char)f2fp8(x);
}
#endif

// ---- radix pass A: per-(r,bucket) counts --------------------------------
__global__ __launch_bounds__(256) void
bucket_count_kernel(const int* __restrict__ edges, int* __restrict__ bcnt,
                    int NBK, int E)
{
    __shared__ int cnt[2 * NBK_MAX];
    const int rbT = 2 * NBK;
    const int t = threadIdx.x;
    for (int k = t; k < rbT; k += 256) cnt[k] = 0;
    __syncthreads();
    long long start = (long long)blockIdx.x * EPB;
    long long twoE = 2LL * E;
    for (int u = 0; u < EPB / 256; ++u) {
        long long idx = start + u * 256 + t;
        if (idx < twoE) {
            int r = idx >= E;
            int e = (int)(idx - (long long)r * E);
            int d = edges[(size_t)r * 2 * E + E + e];
            atomicAdd(&cnt[r * NBK + (d >> 7)], 1);
        }
    }
    __syncthreads();
    for (int k = t; k < rbT; k += 256)
        if (cnt[k]) atomicAdd(&bcnt[k], cnt[k]);
}

// ---- radix pass B: exclusive scan of bucket counts ----------------------
__global__ __launch_bounds__(1024) void
bucket_scan_kernel(const int* __restrict__ bcnt, int* __restrict__ bko,
                   int rbT, int twoE)
{
    __shared__ int sm[1024];
    int t = threadIdx.x;
    int v = (t < rbT) ? bcnt[t] : 0;
    sm[t] = v;
    __syncthreads();
    for (int s = 1; s < 1024; s <<= 1) {
        int u = (t >= s) ? sm[t - s] : 0;
        __syncthreads();
        sm[t] += u;
        __syncthreads();
    }
    if (t < rbT) bko[t] = sm[t] - v;
    if (t == 0) bko[rbT] = twoE;
}

// ---- radix pass C: partition into bucket-grouped (src,dst) pairs --------
__global__ __launch_bounds__(256) void
partition_kernel(const int* __restrict__ edges, const int* __restrict__ bko,
                 int* __restrict__ gcur, uint2* __restrict__ staging,
                 int NBK, int E)
{
    __shared__ int cnt[2 * NBK_MAX];
    __shared__ int base[2 * NBK_MAX];
    const int rbT = 2 * NBK;
    const int t = threadIdx.x;
    for (int k = t; k < rbT; k += 256) cnt[k] = 0;
    __syncthreads();
    long long start = (long long)blockIdx.x * EPB;
    long long twoE = 2LL * E;
    for (int u = 0; u < EPB / 256; ++u) {
        long long idx = start + u * 256 + t;
        if (idx < twoE) {
            int r = idx >= E;
            int e = (int)(idx - (long long)r * E);
            int d = edges[(size_t)r * 2 * E + E + e];
            atomicAdd(&cnt[r * NBK + (d >> 7)], 1);
        }
    }
    __syncthreads();
    for (int k = t; k < rbT; k += 256) {
        int c0 = cnt[k];
        if (c0) base[k] = bko[k] + atomicAdd(&gcur[k], c0);
        cnt[k] = 0;
    }
    __syncthreads();
    for (int u = 0; u < EPB / 256; ++u) {
        long long idx = start + u * 256 + t;
        if (idx < twoE) {
            int r = idx >= E;
            int e = (int)(idx - (long long)r * E);
            int s = edges[(size_t)r * 2 * E + e];
            int d = edges[(size_t)r * 2 * E + E + e];
            int rb = r * NBK + (d >> 7);
            int pos = atomicAdd(&cnt[rb], 1);
            staging[(size_t)base[rb] + pos] = make_uint2((unsigned)s, (unsigned)d);
        }
    }
}

// ---- radix pass D: per-bucket node hist/scan -> off[] and csr[] ----------
__global__ __launch_bounds__(256) void
bucket_csr_kernel(const uint2* __restrict__ staging, const int* __restrict__ bko,
                  int* __restrict__ csr, int* __restrict__ off,
                  int NBK, int N)
{
    __shared__ int hist[BW], excl[BW], cur[BW], sc[BW];
    const int rb = blockIdx.x;
    const int r = rb / NBK;
    const int b = rb % NBK;
    const int node0 = b * BW;
    const int nn = min(BW, N - node0);
    const int cbase = bko[rb];
    const int c = bko[rb + 1] - cbase;
    const int t = threadIdx.x;

    if (t < BW) { hist[t] = 0; cur[t] = 0; }
    __syncthreads();
    for (int k = t; k < c; k += 256)
        atomicAdd(&hist[(int)staging[(size_t)cbase + k].y - node0], 1);
    __syncthreads();
    if (t < BW) sc[t] = hist[t];
    __syncthreads();
    for (int s = 1; s < BW; s <<= 1) {
        int v = (t < BW && t >= s) ? sc[t - s] : 0;
        __syncthreads();
        if (t < BW) sc[t] += v;
        __syncthreads();
    }
    if (t < BW) excl[t] = sc[t] - hist[t];
    if (t < nn) off[(size_t)r * N + node0 + t] = cbase + excl[t];
    __syncthreads();
    for (int k = t; k < c; k += 256) {
        uint2 pr = staging[(size_t)cbase + k];
        int l = (int)pr.y - node0;
        int pos = atomicAdd(&cur[l], 1);
        csr[(size_t)cbase + excl[l] + pos] = (int)pr.x;
    }
}

// ---- f32 -> bf16 [N,128] + fp8 [N,128] ----------------------------------
__global__ void cvt_kernel(const float* __restrict__ in,
                           unsigned short* __restrict__ o,
                           unsigned char* __restrict__ o8, int n4)
{
    int t = blockIdx.x * blockDim.x + threadIdx.x;
    if (t >= n4) return;
    float4 v = ((const float4*)in)[t];
    ushort4 r;
    r.x = f2bf(v.x); r.y = f2bf(v.y); r.z = f2bf(v.z); r.w = f2bf(v.w);
    ((ushort4*)o)[t] = r;
    ((unsigned*)o8)[t] = f32x4_fp8x4(v.x, v.y, v.z, v.w);
}

// ---- weight prep: combined-Wself / Wn -> bf16 W^T rows, biases ----------
__global__ void prep_kernel(const float* __restrict__ Ws1, const float* __restrict__ Wn1,
                            const float* __restrict__ b1,
                            const float* __restrict__ Ws2, const float* __restrict__ Wn2,
                            const float* __restrict__ b2,
                            unsigned short* __restrict__ WT1z, unsigned short* __restrict__ WT1a,
                            unsigned short* __restrict__ WT1b, float* __restrict__ bc1,
                            unsigned short* __restrict__ WT2z, unsigned short* __restrict__ WT2a,
                            unsigned short* __restrict__ WT2b, float* __restrict__ bc2)
{
    int t = blockIdx.x * blockDim.x + threadIdx.x;
    if (t < 16384) {                 // layer 1: [n][k] <- [k][n], n,k < 128
        int n = t >> 7, k = t & 127;
        int in = k * 128 + n;
        WT1z[t] = f2bf(Ws1[in] + Ws1[16384 + in]);
        WT1a[t] = f2bf(Wn1[in]);
        WT1b[t] = f2bf(Wn1[16384 + in]);
    }
    if (t < 8192) {                  // layer 2: n < 64, k < 128
        int n = t >> 7, k = t & 127;
        int in = k * 64 + n;
        WT2z[t] = f2bf(Ws2[in] + Ws2[8192 + in]);
        WT2a[t] = f2bf(Wn2[in]);
        WT2b[t] = f2bf(Wn2[8192 + in]);
    }
    if (t < 128) bc1[t] = b1[t] + b1[128 + t];
    if (t < 64)  bc2[t] = b2[t] + b2[64 + t];
}

// ---- agg L1: wave per node, fp8 gathers (128B/row), RFL csr, unroll x8 --
__global__ __launch_bounds__(256) void
agg1_kernel(const unsigned char* __restrict__ xb8,
            const int* __restrict__ csr, const int* __restrict__ off,
            unsigned short* __restrict__ m0, unsigned short* __restrict__ m1,
            int N, int twoE)
{
    int w = blockIdx.x * 4 + (threadIdx.x >> 6);
    int lane = threadIdx.x & 63;
    if (w >= N) return;
    const int col = lane * 2;
    const unsigned char* xc = xb8 + col;

    float sx0 = 0.f, sy0 = 0.f, sx1 = 0.f, sy1 = 0.f;

    // ---- relation 0 ----
    int o0 = RFL(off[w]);
    int o1 = RFL(off[w + 1]);
    int d0 = o1 - o0;
    int j = o0;
    for (; j + 7 < o1; j += 8) {
        int s0 = RFL(csr[j]);     int s1 = RFL(csr[j + 1]);
        int s2 = RFL(csr[j + 2]); int s3 = RFL(csr[j + 3]);
        int s4 = RFL(csr[j + 4]); int s5 = RFL(csr[j + 5]);
        int s6 = RFL(csr[j + 6]); int s7 = RFL(csr[j + 7]);
        unsigned a0 = *(const unsigned short*)(xc + (size_t)s0 * 128);
        unsigned a1 = *(const unsigned short*)(xc + (size_t)s1 * 128);
        unsigned a2 = *(const unsigned short*)(xc + (size_t)s2 * 128);
        unsigned a3 = *(const unsigned short*)(xc + (size_t)s3 * 128);
        unsigned a4 = *(const unsigned short*)(xc + (size_t)s4 * 128);
        unsigned a5 = *(const unsigned short*)(xc + (size_t)s5 * 128);
        unsigned a6 = *(const unsigned short*)(xc + (size_t)s6 * 128);
        unsigned a7 = *(const unsigned short*)(xc + (size_t)s7 * 128);
        floatx2 v0 = fp8lo(a0); floatx2 v1 = fp8lo(a1);
        floatx2 v2 = fp8lo(a2); floatx2 v3 = fp8lo(a3);
        floatx2 v4 = fp8lo(a4); floatx2 v5 = fp8lo(a5);
        floatx2 v6 = fp8lo(a6); floatx2 v7 = fp8lo(a7);
        sx0 += ((v0.x + v1.x) + (v2.x + v3.x)) + ((v4.x + v5.x) + (v6.x + v7.x));
        sy0 += ((v0.y + v1.y) + (v2.y + v3.y)) + ((v4.y + v5.y) + (v6.y + v7.y));
    }
    for (; j < o1; ++j) {
        int s0 = RFL(csr[j]);
        floatx2 v = fp8lo(*(const unsigned short*)(xc + (size_t)s0 * 128));
        sx0 += v.x; sy0 += v.y;
    }

    // ---- relation 1 ----
    int p = N + w;
    o0 = RFL(off[p]);
    o1 = (p + 1 < 2 * N) ? RFL(off[p + 1]) : twoE;
    int d1 = o1 - o0;
    j = o0;
    for (; j + 7 < o1; j += 8) {
        int s0 = RFL(csr[j]);     int s1 = RFL(csr[j + 1]);
        int s2 = RFL(csr[j + 2]); int s3 = RFL(csr[j + 3]);
        int s4 = RFL(csr[j + 4]); int s5 = RFL(csr[j + 5]);
        int s6 = RFL(csr[j + 6]); int s7 = RFL(csr[j + 7]);
        unsigned a0 = *(const unsigned short*)(xc + (size_t)s0 * 128);
        unsigned a1 = *(const unsigned short*)(xc + (size_t)s1 * 128);
        unsigned a2 = *(const unsigned short*)(xc + (size_t)s2 * 128);
        unsigned a3 = *(const unsigned short*)(xc + (size_t)s3 * 128);
        unsigned a4 = *(const unsigned short*)(xc + (size_t)s4 * 128);
        unsigned a5 = *(const unsigned short*)(xc + (size_t)s5 * 128);
        unsigned a6 = *(const unsigned short*)(xc + (size_t)s6 * 128);
        unsigned a7 = *(const unsigned short*)(xc + (size_t)s7 * 128);
        floatx2 v0 = fp8lo(a0); floatx2 v1 = fp8lo(a1);
        floatx2 v2 = fp8lo(a2); floatx2 v3 = fp8lo(a3);
        floatx2 v4 = fp8lo(a4); floatx2 v5 = fp8lo(a5);
        floatx2 v6 = fp8lo(a6); floatx2 v7 = fp8lo(a7);
        sx1 += ((v0.x + v1.x) + (v2.x + v3.x)) + ((v4.x + v5.x) + (v6.x + v7.x));
        sy1 += ((v0.y + v1.y) + (v2.y + v3.y)) + ((v4.y + v5.y) + (v6.y + v7.y));
    }
    for (; j < o1; ++j) {
        int s0 = RFL(csr[j]);
        floatx2 v = fp8lo(*(const unsigned short*)(xc + (size_t)s0 * 128));
        sx1 += v.x; sy1 += v.y;
    }

    float inv0 = 1.0f / fmaxf((float)d0, 1.0f);
    float inv1 = 1.0f / fmaxf((float)d1, 1.0f);
    *(unsigned*)(m0 + (size_t)w * 128 + col) = pack2(sx0 * inv0, sy0 * inv0);
    *(unsigned*)(m1 + (size_t)w * 128 + col) = pack2(sx1 * inv1, sy1 * inv1);
}

// ---- B-frag read from swizzled LDS --------------------------------------
__device__ __forceinline__ bf16x8 bs_read(const unsigned short* Bs, int mat,
                                          int c, int s, int quad) {
    unsigned byte = (unsigned)(mat * 16384 + c * 256 + s * 64 + quad * 16);
    byte ^= (unsigned)((c & 7) << 4);
    return *(const bf16x8*)((const char*)Bs + byte);
}

// ---- fused layer-1 GEMM v3: B in swizzled LDS, A per-lane, 512 thr ------
// grid (N/128, 2): block = 128 rows x 64 cols (blockIdx.y col half).
__global__ __launch_bounds__(512) void
gemm1_fused_kernel(const unsigned short* __restrict__ xb,
                   const unsigned short* __restrict__ m0,
                   const unsigned short* __restrict__ m1,
                   const unsigned short* __restrict__ WTz,
                   const unsigned short* __restrict__ WTa,
                   const unsigned short* __restrict__ WTb,
                   const float* __restrict__ bias,
                   unsigned short* __restrict__ h1b, int N)
{
    __shared__ unsigned short Bs[3 * 64 * 128];   // 48KB, XOR-swizzled

    const int tid = threadIdx.x;
    const int wave = tid >> 6;        // 0..7
    const int lane = tid & 63;
    const int m = lane & 15;
    const int quad = lane >> 4;
    const int colbase = blockIdx.y * 64;

    // stage B coalesced: 6 x uint4 per thread (48KB total)
#pragma unroll
    for (int i = 0; i < 6; ++i) {
        int o = (i * 512 + tid) * 8;          // ushort linear index
        int mat = o >> 13;
        int rem = o & 8191;
        int c = rem >> 7;
        int k = rem & 127;
        const unsigned short* src = (mat == 0) ? WTz : ((mat == 1) ? WTa : WTb);
        uint4 v = *(const uint4*)(src + (size_t)(colbase + c) * 128 + k);
        unsigned byte = (unsigned)(o * 2) ^ (unsigned)((c & 7) << 4);
        *(uint4*)((char*)Bs + byte) = v;
    }
    __syncthreads();

    floatx4 acc[4];
    const floatx4 z4 = {0.f, 0.f, 0.f, 0.f};
#pragma unroll
    for (int t = 0; t < 4; ++t) acc[t] = z4;

    int arow = blockIdx.x * 128 + wave * 16 + m;
    if (arow >= N) arow = N - 1;
    const size_t ab = (size_t)arow * 128 + quad * 8;

    bf16x8 ax0 = *(const bf16x8*)(xb + ab);
    bf16x8 ax1 = *(const bf16x8*)(xb + ab + 32);
    bf16x8 ax2 = *(const bf16x8*)(xb + ab + 64);
    bf16x8 ax3 = *(const bf16x8*)(xb + ab + 96);
    bf16x8 a00 = *(const bf16x8*)(m0 + ab);
    bf16x8 a01 = *(const bf16x8*)(m0 + ab + 32);
    bf16x8 a02 = *(const bf16x8*)(m0 + ab + 64);
    bf16x8 a03 = *(const bf16x8*)(m0 + ab + 96);
    bf16x8 a10 = *(const bf16x8*)(m1 + ab);
    bf16x8 a11 = *(const bf16x8*)(m1 + ab + 32);
    bf16x8 a12 = *(const bf16x8*)(m1 + ab + 64);
    bf16x8 a13 = *(const bf16x8*)(m1 + ab + 96);

#pragma unroll
    for (int t = 0; t < 4; ++t) {
        const int c = t * 16 + m;
        acc[t] = __builtin_amdgcn_mfma_f32_16x16x32_bf16(
            ax0, bs_read(Bs, 0, c, 0, quad), acc[t], 0, 0, 0);
        acc[t] = __builtin_amdgcn_mfma_f32_16x16x32_bf16(
            a00, bs_read(Bs, 1, c, 0, quad), acc[t], 0, 0, 0);
        acc[t] = __builtin_amdgcn_mfma_f32_16x16x32_bf16(
            a10, bs_read(Bs, 2, c, 0, quad), acc[t], 0, 0, 0);
        acc[t] = __builtin_amdgcn_mfma_f32_16x16x32_bf16(
            ax1, bs_read(Bs, 0, c, 1, quad), acc[t], 0, 0, 0);
        acc[t] = __builtin_amdgcn_mfma_f32_16x16x32_bf16(
            a01, bs_read(Bs, 1, c, 1, quad), acc[t], 0, 0, 0);
        acc[t] = __builtin_amdgcn_mfma_f32_16x16x32_bf16(
            a11, bs_read(Bs, 2, c, 1, quad), acc[t], 0, 0, 0);
        acc[t] = __builtin_amdgcn_mfma_f32_16x16x32_bf16(
            ax2, bs_read(Bs, 0, c, 2, quad), acc[t], 0, 0, 0);
        acc[t] = __builtin_amdgcn_mfma_f32_16x16x32_bf16(
            a02, bs_read(Bs, 1, c, 2, quad), acc[t], 0, 0, 0);
        acc[t] = __builtin_amdgcn_mfma_f32_16x16x32_bf16(
            a12, bs_read(Bs, 2, c, 2, quad), acc[t], 0, 0, 0);
        acc[t] = __builtin_amdgcn_mfma_f32_16x16x32_bf16(
            ax3, bs_read(Bs, 0, c, 3, quad), acc[t], 0, 0, 0);
        acc[t] = __builtin_amdgcn_mfma_f32_16x16x32_bf16(
            a03, bs_read(Bs, 1, c, 3, quad), acc[t], 0, 0, 0);
        acc[t] = __builtin_amdgcn_mfma_f32_16x16x32_bf16(
            a13, bs_read(Bs, 2, c, 3, quad), acc[t], 0, 0, 0);
    }

    // direct store (r17-verified): row = base + quad*4+i, col = colbase+t*16+m
    const int gr0 = blockIdx.x * 128 + wave * 16 + quad * 4;
#pragma unroll
    for (int t = 0; t < 4; ++t) {
        int colg = colbase + t * 16 + m;
        float bv = bias[colg];
#pragma unroll
        for (int i = 0; i < 4; ++i) {
            int gr = gr0 + i;
            if (gr < N)
                h1b[(size_t)gr * 128 + colg] = f2bf(fmaxf(acc[t][i] + bv, 0.0f));
        }
    }
}

// ---- fused layer-2 GEMM v3: B in swizzled LDS (48KB), 512 thr -----------
__global__ __launch_bounds__(512) void
gemm2_fused_kernel(const unsigned short* __restrict__ Ab,
                   const unsigned short* __restrict__ WTz,
                   const unsigned short* __restrict__ WTa,
                   const unsigned short* __restrict__ WTb,
                   const float* __restrict__ bias,
                   float* __restrict__ zf,
                   unsigned char* __restrict__ t08, unsigned char* __restrict__ t18,
                   int N)
{
    __shared__ unsigned short Bs[3 * 64 * 128];   // 48KB, XOR-swizzled

    const int tid = threadIdx.x;
    const int wave = tid >> 6;
    const int lane = tid & 63;
    const int m = lane & 15;
    const int quad = lane >> 4;

#pragma unroll
    for (int i = 0; i < 6; ++i) {
        int o = (i * 512 + tid) * 8;
        int mat = o >> 13;
        int rem = o & 8191;
        int c = rem >> 7;
        int k = rem & 127;
        const unsigned short* src = (mat == 0) ? WTz : ((mat == 1) ? WTa : WTb);
        uint4 v = *(const uint4*)(src + (size_t)c * 128 + k);
        unsigned byte = (unsigned)(o * 2) ^ (unsigned)((c & 7) << 4);
        *(uint4*)((char*)Bs + byte) = v;
    }
    __syncthreads();

    floatx4 accz[4], acca[4], accb[4];
    const floatx4 z4 = {0.f, 0.f, 0.f, 0.f};
#pragma unroll
    for (int t = 0; t < 4; ++t) { accz[t] = z4; acca[t] = z4; accb[t] = z4; }

    int arow = blockIdx.x * 128 + wave * 16 + m;
    if (arow >= N) arow = N - 1;
    const size_t ab = (size_t)arow * 128 + quad * 8;

    bf16x8 h0 = *(const bf16x8*)(Ab + ab);
    bf16x8 h1 = *(const bf16x8*)(Ab + ab + 32);
    bf16x8 h2 = *(const bf16x8*)(Ab + ab + 64);
    bf16x8 h3 = *(const bf16x8*)(Ab + ab + 96);

#pragma unroll
    for (int t = 0; t < 4; ++t) {
        const int c = t * 16 + m;
        accz[t] = __builtin_amdgcn_mfma_f32_16x16x32_bf16(
            h0, bs_read(Bs, 0, c, 0, quad), accz[t], 0, 0, 0);
        acca[t] = __builtin_amdgcn_mfma_f32_16x16x32_bf16(
            h0, bs_read(Bs, 1, c, 0, quad), acca[t], 0, 0, 0);
        accb[t] = __builtin_amdgcn_mfma_f32_16x16x32_bf16(
            h0, bs_read(Bs, 2, c, 0, quad), accb[t], 0, 0, 0);
        accz[t] = __builtin_amdgcn_mfma_f32_16x16x32_bf16(
            h1, bs_read(Bs, 0, c, 1, quad), accz[t], 0, 0, 0);
        acca[t] = __builtin_amdgcn_mfma_f32_16x16x32_bf16(
            h1, bs_read(Bs, 1, c, 1, quad), acca[t], 0, 0, 0);
        accb[t] = __builtin_amdgcn_mfma_f32_16x16x32_bf16(
            h1, bs_read(Bs, 2, c, 1, quad), accb[t], 0, 0, 0);
        accz[t] = __builtin_amdgcn_mfma_f32_16x16x32_bf16(
            h2, bs_read(Bs, 0, c, 2, quad), accz[t], 0, 0, 0);
        acca[t] = __builtin_amdgcn_mfma_f32_16x16x32_bf16(
            h2, bs_read(Bs, 1, c, 2, quad), acca[t], 0, 0, 0);
        accb[t] = __builtin_amdgcn_mfma_f32_16x16x32_bf16(
            h2, bs_read(Bs, 2, c, 2, quad), accb[t], 0, 0, 0);
        accz[t] = __builtin_amdgcn_mfma_f32_16x16x32_bf16(
            h3, bs_read(Bs, 0, c, 3, quad), accz[t], 0, 0, 0);
        acca[t] = __builtin_amdgcn_mfma_f32_16x16x32_bf16(
            h3, bs_read(Bs, 1, c, 3, quad), acca[t], 0, 0, 0);
        accb[t] = __builtin_amdgcn_mfma_f32_16x16x32_bf16(
            h3, bs_read(Bs, 2, c, 3, quad), accb[t], 0, 0, 0);
    }

    const int gr0 = blockIdx.x * 128 + wave * 16 + quad * 4;
#pragma unroll
    for (int t = 0; t < 4; ++t) {
        int colg = t * 16 + m;
        float bv = bias[colg];
#pragma unroll
        for (int i = 0; i < 4; ++i) {
            int gr = gr0 + i;
            if (gr < N) {
                zf[(size_t)gr * 64 + colg] = accz[t][i] + bv;
                t08[(size_t)gr * 64 + colg] = f2fp8_1(acca[t][i]);
                t18[(size_t)gr * 64 + colg] = f2fp8_1(accb[t][i]);
            }
        }
    }
}

// ---- agg L2: quarter-wave per edge, fp8 64B rows, 16 edges/iter ---------
__global__ __launch_bounds__(256) void
agg2_kernel(const unsigned char* __restrict__ t08,
            const unsigned char* __restrict__ t18,
            const float* __restrict__ z2,
            const int* __restrict__ csr, const int* __restrict__ off,
            unsigned short* __restrict__ h2b, int N, int twoE)
{
    int w = blockIdx.x * 4 + (threadIdx.x >> 6);
    int lane = threadIdx.x & 63;
    if (w >= N) return;
    const int q = lane >> 4;                 // edge slot 0..3
    const int col = (lane & 15) * 4;         // 4 fp8 cols per lane
    const unsigned char* t0c = t08 + col;
    const unsigned char* t1c = t18 + col;

    float a0 = 0.f, a1 = 0.f, a2 = 0.f, a3 = 0.f;   // rel0
    float b0 = 0.f, b1 = 0.f, b2 = 0.f, b3 = 0.f;   // rel1

    // ---- relation 0 ----
    int o0 = RFL(off[w]);
    int o1 = RFL(off[w + 1]);
    int d0 = o1 - o0;
    int j = o0;
    for (; j + 15 < o1; j += 16) {
        int r0 = csr[j + q];
        int r1 = csr[j + 4 + q];
        int r2 = csr[j + 8 + q];
        int r3 = csr[j + 12 + q];
        unsigned v0 = *(const unsigned*)(t0c + (size_t)r0 * 64);
        unsigned v1 = *(const unsigned*)(t0c + (size_t)r1 * 64);
        unsigned v2 = *(const unsigned*)(t0c + (size_t)r2 * 64);
        unsigned v3 = *(const unsigned*)(t0c + (size_t)r3 * 64);
        floatx2 l0 = fp8lo(v0), h0 = fp8hi(v0);
        floatx2 l1 = fp8lo(v1), h1 = fp8hi(v1);
        floatx2 l2 = fp8lo(v2), h2 = fp8hi(v2);
        floatx2 l3 = fp8lo(v3), h3 = fp8hi(v3);
        a0 += (l0.x + l1.x) + (l2.x + l3.x);
        a1 += (l0.y + l1.y) + (l2.y + l3.y);
        a2 += (h0.x + h1.x) + (h2.x + h3.x);
        a3 += (h0.y + h1.y) + (h2.y + h3.y);
    }
    for (; j + 3 < o1; j += 4) {
        int r = csr[j + q];
        unsigned v = *(const unsigned*)(t0c + (size_t)r * 64);
        floatx2 l = fp8lo(v), h = fp8hi(v);
        a0 += l.x; a1 += l.y; a2 += h.x; a3 += h.y;
    }
    if (j < o1 && q < o1 - j) {
        int r = csr[j + q];
        unsigned v = *(const unsigned*)(t0c + (size_t)r * 64);
        floatx2 l = fp8lo(v), h = fp8hi(v);
        a0 += l.x; a1 += l.y; a2 += h.x; a3 += h.y;
    }

    // ---- relation 1 ----
    int p = N + w;
    o0 = RFL(off[p]);
    o1 = (p + 1 < 2 * N) ? RFL(off[p + 1]) : twoE;
    int d1 = o1 - o0;
    j = o0;
    for (; j + 15 < o1; j += 16) {
        int r0 = csr[j + q];
        int r1 = csr[j + 4 + q];
        int r2 = csr[j + 8 + q];
        int r3 = csr[j + 12 + q];
        unsigned v0 = *(const unsigned*)(t1c + (size_t)r0 * 64);
        unsigned v1 = *(const unsigned*)(t1c + (size_t)r1 * 64);
        unsigned v2 = *(const unsigned*)(t1c + (size_t)r2 * 64);
        unsigned v3 = *(const unsigned*)(t1c + (size_t)r3 * 64);
        floatx2 l0 = fp8lo(v0), h0 = fp8hi(v0);
        floatx2 l1 = fp8lo(v1), h1 = fp8hi(v1);
        floatx2 l2 = fp8lo(v2), h2 = fp8hi(v2);
        floatx2 l3 = fp8lo(v3), h3 = fp8hi(v3);
        b0 += (l0.x + l1.x) + (l2.x + l3.x);
        b1 += (l0.y + l1.y) + (l2.y + l3.y);
        b2 += (h0.x + h1.x) + (h2.x + h3.x);
        b3 += (h0.y + h1.y) + (h2.y + h3.y);
    }
    for (; j + 3 < o1; j += 4) {
        int r = csr[j + q];
        unsigned v = *(const unsigned*)(t1c + (size_t)r * 64);
        floatx2 l = fp8lo(v), h = fp8hi(v);
        b0 += l.x; b1 += l.y; b2 += h.x; b3 += h.y;
    }
    if (j < o1 && q < o1 - j) {
        int r = csr[j + q];
        unsigned v = *(const unsigned*)(t1c + (size_t)r * 64);
        floatx2 l = fp8lo(v), h = fp8hi(v);
        b0 += l.x; b1 += l.y; b2 += h.x; b3 += h.y;
    }

    // cross-quarter reduce + write
    a0 += __shfl_xor(a0, 16); a1 += __shfl_xor(a1, 16);
    a2 += __shfl_xor(a2, 16); a3 += __shfl_xor(a3, 16);
    b0 += __shfl_xor(b0, 16); b1 += __shfl_xor(b1, 16);
    b2 += __shfl_xor(b2, 16); b3 += __shfl_xor(b3, 16);
    a0 += __shfl_xor(a0, 32); a1 += __shfl_xor(a1, 32);
    a2 += __shfl_xor(a2, 32); a3 += __shfl_xor(a3, 32);
    b0 += __shfl_xor(b0, 32); b1 += __shfl_xor(b1, 32);
    b2 += __shfl_xor(b2, 32); b3 += __shfl_xor(b3, 32);
    if (q == 0) {
        float inv0 = 1.0f / fmaxf((float)d0, 1.0f);
        float inv1 = 1.0f / fmaxf((float)d1, 1.0f);
        float4 z = *(const float4*)(z2 + (size_t)w * 64 + col);
        float h0v = z.x + a0 * inv0 + b0 * inv1;
        float h1v = z.y + a1 * inv0 + b1 * inv1;
        float h2v = z.z + a2 * inv0 + b2 * inv1;
        float h3v = z.w + a3 * inv0 + b3 * inv1;
        uint2 u;
        u.x = pack2(h0v, h1v);
        u.y = pack2(h2v, h3v);
        *(uint2*)(h2b + (size_t)w * 64 + col) = u;
    }
}

// ---- score (merged pos+neg): 8 lanes/edge, 128B rows, shfl reduce --------
__global__ __launch_bounds__(256) void
score_kernel(const unsigned short* __restrict__ h, // [N,64] bf16
             const int* __restrict__ edges, const int* __restrict__ neg,
             float* __restrict__ out, int E, int En)
{
    int t = blockIdx.x * blockDim.x + threadIdx.x;
    int e = t >> 3;
    int c = t & 7;
    if (e >= E + En) return;
    int sI, dI, oI;
    if (e < E) { sI = edges[e]; dI = edges[E + e]; oI = e; }
    else { int en = e - E; sI = neg[en]; dI = neg[En + en]; oI = E + en; }
    uint4 va = *(const uint4*)(h + (size_t)sI * 64 + c * 8);
    uint4 vb = *(const uint4*)(h + (size_t)dI * 64 + c * 8);
    float s = 0.0f;
    s = fmaf(bflo(va.x), bflo(vb.x), s);
    s = fmaf(bfhi(va.x), bfhi(vb.x), s);
    s = fmaf(bflo(va.y), bflo(vb.y), s);
    s = fmaf(bfhi(va.y), bfhi(vb.y), s);
    s = fmaf(bflo(va.z), bflo(vb.z), s);
    s = fmaf(bfhi(va.z), bfhi(vb.z), s);
    s = fmaf(bflo(va.w), bflo(vb.w), s);
    s = fmaf(bfhi(va.w), bfhi(vb.w), s);
    s += __shfl_xor(s, 1);
    s += __shfl_xor(s, 2);
    s += __shfl_xor(s, 4);
    if (c == 0) out[oI] = s;
}

extern "C" void kernel_launch(void* const* d_in, const int* in_sizes, int n_in,
                              void* d_out, int out_size, void* d_ws, size_t ws_size,
                              hipStream_t stream)
{
    const float* x     = (const float*)d_in[0];
    const int*   edges = (const int*)d_in[1];
    const int*   neg   = (const int*)d_in[2];
    const float* Wn1   = (const float*)d_in[3];
    const float* Ws1   = (const float*)d_in[4];
    const float* b1    = (const float*)d_in[5];
    const float* Wn2   = (const float*)d_in[6];
    const float* Ws2   = (const float*)d_in[7];
    const float* b2    = (const float*)d_in[8];
    float* out = (float*)d_out;

    const int Fin = 128, R = 2;
    const int N  = in_sizes[0] / Fin;        // 50000
    const int E  = in_sizes[1] / (R * 2);    // 800000
    const int En = in_sizes[2] / 2;          // 800000
    const int twoE = 2 * E;
    const int NBK = (N + BW - 1) / BW;       // 391
    const int rbT = 2 * NBK;

    // ---- workspace layout (aliases noted) ----
    const size_t nb128 = (size_t)N * 128 * sizeof(unsigned short);   // 12.8MB
    char* p = (char*)d_ws;

    // region0: staging [2E] (CSR build) -> xb8 [N,128] fp8 (cvt..agg1)
    //          -> z2 [N,64] f32 (gemm2..agg2). Lifetimes strictly ordered.
    uint2* staging       = (uint2*)p;
    unsigned char* xb8   = (unsigned char*)p;
    float* z2            = (float*)p;
    {
        size_t r0 = (size_t)twoE * sizeof(uint2);          // 12.8MB
        size_t r1 = (size_t)N * 64 * sizeof(float);        // 12.8MB
        size_t r2 = (size_t)N * 128;                       // 6.4MB
        size_t rm = r0 > r1 ? r0 : r1;
        if (r2 > rm) rm = r2;
        p += rm;
    }
    unsigned short* m0  = (unsigned short*)p; p += nb128;  // [N,128] mean rel0 (t08/t18 reuse)
    unsigned short* m1  = (unsigned short*)p; p += nb128;  // [N,128] mean rel1 (h2b reuse)
    unsigned short* xb  = (unsigned short*)p; p += nb128;  // [N,128] bf16 x
    unsigned short* h1b = (unsigned short*)p; p += nb128;  // [N,128] bf16 h1
    unsigned short* WT1z = (unsigned short*)p; p += 16384 * 2;
    unsigned short* WT1a = (unsigned short*)p; p += 16384 * 2;
    unsigned short* WT1b = (unsigned short*)p; p += 16384 * 2;
    unsigned short* WT2z = (unsigned short*)p; p += 8192 * 2;
    unsigned short* WT2a = (unsigned short*)p; p += 8192 * 2;
    unsigned short* WT2b = (unsigned short*)p; p += 8192 * 2;
    float* bc1 = (float*)p; p += 128 * sizeof(float);
    float* bc2 = (float*)p; p += 64 * sizeof(float);
    int* bcnt = (int*)p; p += (size_t)2 * NBK_MAX * sizeof(int);
    int* gcur = (int*)p; p += (size_t)2 * NBK_MAX * sizeof(int);
    int* bko  = (int*)p; p += ((size_t)2 * NBK_MAX + 1) * sizeof(int);
    int* off  = (int*)p; p += (size_t)2 * N * sizeof(int);
    int* csr  = (int*)p;

    unsigned char*  t08 = (unsigned char*)m0;        // [N,64] fp8
    unsigned char*  t18 = t08 + (size_t)N * 64;      // [N,64] fp8
    unsigned short* h2b = m1;                        // [N,64] bf16

    const int BS = 256;
    const int edge_blocks = (twoE + EPB - 1) / EPB;
    const int gx128 = (N + 127) / 128;

    // ---- CSR build (radix by dst bucket) ----
    hipMemsetAsync(bcnt, 0, (size_t)4 * NBK_MAX * sizeof(int), stream);
    bucket_count_kernel<<<edge_blocks, BS, 0, stream>>>(edges, bcnt, NBK, E);
    bucket_scan_kernel<<<1, 1024, 0, stream>>>(bcnt, bko, rbT, twoE);
    partition_kernel<<<edge_blocks, BS, 0, stream>>>(edges, bko, gcur, staging, NBK, E);
    bucket_csr_kernel<<<rbT, BS, 0, stream>>>(staging, bko, csr, off, NBK, N);

    // ---- prep (cvt AFTER bucket_csr: xb8 aliases dead staging) ----
    cvt_kernel<<<(N * 32 + BS - 1) / BS, BS, 0, stream>>>(x, xb, xb8, N * 32);
    prep_kernel<<<(16384 + BS - 1) / BS, BS, 0, stream>>>(
        Ws1, Wn1, b1, Ws2, Wn2, b2,
        WT1z, WT1a, WT1b, bc1, WT2z, WT2a, WT2b, bc2);

    // ---- Layer 1: fp8 aggregate (full-wave), then fused 3-matmul GEMM ---
    agg1_kernel<<<(N + 3) / 4, BS, 0, stream>>>(xb8, csr, off, m0, m1, N, twoE);
    {
        dim3 g(gx128, 2);
        gemm1_fused_kernel<<<g, 512, 0, stream>>>(xb, m0, m1, WT1z, WT1a, WT1b,
                                                  bc1, h1b, N);
    }

    // ---- Layer 2: fused transform (z2 f32, t0/t1 fp8), quarter-wave agg -
    gemm2_fused_kernel<<<gx128, 512, 0, stream>>>(h1b, WT2z, WT2a, WT2b, bc2,
                                                  z2, t08, t18, N);
    agg2_kernel<<<(N + 3) / 4, BS, 0, stream>>>(t08, t18, z2, csr, off, h2b, N, twoE);

    // ---- Scores (pos + neg in one launch) ----
    score_kernel<<<((E + En) * 8 + BS - 1) / BS, BS, 0, stream>>>(
        h2b, edges, neg, out, E, En);
}